// Round 8
// baseline (483.456 us; speedup 1.0000x reference)
//
#include <hip/hip_runtime.h>

#define HIDDEN 64
#define BETA 0.01f
#define GAMMA 0.01f

#define BUCKET_SHIFT 8                 // 256 users per bucket
#define BUCKET_W     (1 << BUCKET_SHIFT)
#define TILE_E       8192              // entries per partition tile
#define PTILE        8192              // pos pairs per partition tile

__device__ inline unsigned short f2bf(float f) {   // RNE float->bf16
    unsigned x = __float_as_uint(f);
    return (unsigned short)((x + 0x7fffu + ((x >> 16) & 1u)) >> 16);
}
__device__ inline float bf2f(unsigned short b) {
    return __uint_as_float(((unsigned)b) << 16);
}

// ---------------------------------------------------------------------------
// Encode phase A: H = features @ W_enc + b_enc   (thread per output element)
// ---------------------------------------------------------------------------
__global__ void h_kernel(const float* __restrict__ features,
                         const float* __restrict__ W_enc,
                         const float* __restrict__ b_enc,
                         float* __restrict__ H,
                         int num_movies, int in_feats) {
    const int tid = blockIdx.x * blockDim.x + threadIdx.x;
    const int j = tid & 63;
    const int m = tid >> 6;
    if (m >= num_movies) return;

    const float* frow = features + (size_t)m * in_feats;
    float a0 = 0.0f, a1 = 0.0f, a2 = 0.0f, a3 = 0.0f;
    #pragma unroll 8
    for (int f = 0; f < in_feats; f += 4) {
        const float4 fv = *(const float4*)(frow + f);
        a0 = fmaf(fv.x, W_enc[(f + 0) * HIDDEN + j], a0);
        a1 = fmaf(fv.y, W_enc[(f + 1) * HIDDEN + j], a1);
        a2 = fmaf(fv.z, W_enc[(f + 2) * HIDDEN + j], a2);
        a3 = fmaf(fv.w, W_enc[(f + 3) * HIDDEN + j], a3);
    }
    H[(size_t)m * HIDDEN + j] = (a0 + a1) + (a2 + a3) + b_enc[j];
}

// ---------------------------------------------------------------------------
// Encode phase B: P/Q in bf16 (L2-resident 2.56MB each) + BETA regularizer
// computed from fp32 registers.
// ---------------------------------------------------------------------------
__global__ void pq_kernel(const float* __restrict__ H,
                          const float* __restrict__ W_p,
                          const float* __restrict__ W_q,
                          unsigned short* __restrict__ Ph,
                          unsigned short* __restrict__ Qh,
                          float* __restrict__ out_loss,
                          int num_movies) {
    const int tid = blockIdx.x * blockDim.x + threadIdx.x;
    const int j = tid & 63;
    const int m = tid >> 6;
    float reg = 0.0f;

    if (m < num_movies) {
        const float* hrow = H + (size_t)m * HIDDEN;
        float p0 = 0.0f, p1 = 0.0f, p2 = 0.0f, p3 = 0.0f;
        float q0 = 0.0f, q1 = 0.0f, q2 = 0.0f, q3 = 0.0f;
        #pragma unroll 4
        for (int f = 0; f < HIDDEN; f += 4) {
            const float4 hv = *(const float4*)(hrow + f);
            p0 = fmaf(hv.x, W_p[(f + 0) * HIDDEN + j], p0);
            p1 = fmaf(hv.y, W_p[(f + 1) * HIDDEN + j], p1);
            p2 = fmaf(hv.z, W_p[(f + 2) * HIDDEN + j], p2);
            p3 = fmaf(hv.w, W_p[(f + 3) * HIDDEN + j], p3);
            q0 = fmaf(hv.x, W_q[(f + 0) * HIDDEN + j], q0);
            q1 = fmaf(hv.y, W_q[(f + 1) * HIDDEN + j], q1);
            q2 = fmaf(hv.z, W_q[(f + 2) * HIDDEN + j], q2);
            q3 = fmaf(hv.w, W_q[(f + 3) * HIDDEN + j], q3);
        }
        const float p = (p0 + p1) + (p2 + p3);
        const float q = (q0 + q1) + (q2 + q3);
        Ph[(size_t)m * HIDDEN + j] = f2bf(p);
        Qh[(size_t)m * HIDDEN + j] = f2bf(q);
        reg = p * p + q * q;
    }

    for (int off = 32; off; off >>= 1) reg += __shfl_down(reg, off);
    __shared__ float s_part[16];
    const int wave = threadIdx.x >> 6;
    const int lane = threadIdx.x & 63;
    if (lane == 0) s_part[wave] = reg;
    __syncthreads();
    if (threadIdx.x == 0) {
        float t = 0.0f;
        const int nw = blockDim.x >> 6;
        for (int w = 0; w < nw; ++w) t += s_part[w];
        atomicAdd(out_loss, 0.5f * BETA * t);
    }
}

// ---------------------------------------------------------------------------
// Per-tile LDS bucket histogram over nnz entries.
// ---------------------------------------------------------------------------
__global__ void tilehist_kernel(const int* __restrict__ rows, int nnz,
                                int nbuckets, int ntiles,
                                unsigned* __restrict__ tileHist) {
    extern __shared__ unsigned hist[];
    const int t = blockIdx.x;
    const int tid = threadIdx.x;
    for (int i = tid; i < nbuckets; i += blockDim.x) hist[i] = 0;
    __syncthreads();

    const int base = t * TILE_E;
    const int kmax = TILE_E / 256;
    for (int k = 0; k < kmax; ++k) {
        const int e = base + k * 256 + tid;
        if (e < nnz) atomicAdd(&hist[rows[e] >> BUCKET_SHIFT], 1u);
    }
    __syncthreads();
    for (int i = tid; i < nbuckets; i += blockDim.x)
        tileHist[(size_t)i * ntiles + t] = hist[i];
}

// ---------------------------------------------------------------------------
// Generic 2-level scan building blocks (n <= 256*256).
// ---------------------------------------------------------------------------
__global__ void chunksum_kernel(const unsigned* __restrict__ src, int n,
                                unsigned* __restrict__ sums) {
    __shared__ unsigned s[256];
    const int t = threadIdx.x;
    const int i = blockIdx.x * 256 + t;
    s[t] = (i < n) ? src[i] : 0u;
    __syncthreads();
    for (int off = 128; off; off >>= 1) {
        if (t < off) s[t] += s[t + off];
        __syncthreads();
    }
    if (t == 0) sums[blockIdx.x] = s[0];
}

__global__ void scantop_kernel(const unsigned* __restrict__ sums, int nchunks,
                               unsigned* __restrict__ chunk_off,
                               unsigned* __restrict__ offs, int n, int total) {
    __shared__ unsigned s[256];
    const int t = threadIdx.x;
    unsigned x = (t < nchunks) ? sums[t] : 0u;
    s[t] = x;
    __syncthreads();
    for (int off = 1; off < 256; off <<= 1) {
        unsigned v = (t >= off) ? s[t - off] : 0u;
        __syncthreads();
        s[t] += v;
        __syncthreads();
    }
    if (t < nchunks) chunk_off[t] = s[t] - x;   // exclusive
    if (t == 0) offs[n] = (unsigned)total;
}

__global__ void exscan_kernel(const unsigned* __restrict__ src, int n,
                              const unsigned* __restrict__ chunk_off,
                              unsigned* __restrict__ dst) {
    __shared__ unsigned s[256];
    const int t = threadIdx.x;
    const int i = blockIdx.x * 256 + t;
    unsigned x = (i < n) ? src[i] : 0u;
    s[t] = x;
    __syncthreads();
    for (int off = 1; off < 256; off <<= 1) {
        unsigned v = (t >= off) ? s[t - off] : 0u;
        __syncthreads();
        s[t] += v;
        __syncthreads();
    }
    if (i < n) dst[i] = chunk_off[blockIdx.x] + s[t] - x;
}

// ---------------------------------------------------------------------------
// Partition level 1: scatter nnz entries into bucket-major temp order.
// key = (user << 15) | col
// ---------------------------------------------------------------------------
__global__ void partition_kernel(const int* __restrict__ rows,
                                 const int* __restrict__ cols,
                                 const float* __restrict__ vals, int nnz,
                                 int nbuckets, int ntiles,
                                 const unsigned* __restrict__ offsB,
                                 uint2* __restrict__ temp) {
    extern __shared__ unsigned smem[];          // hist[nb] then lofs[nb]
    unsigned* hist = smem;
    unsigned* lofs = smem + nbuckets;
    const int t = blockIdx.x;
    const int tid = threadIdx.x;
    for (int i = tid; i < nbuckets; i += blockDim.x) {
        hist[i] = 0;
        lofs[i] = offsB[(size_t)i * ntiles + t];
    }
    __syncthreads();

    const int base = t * TILE_E;
    const int kmax = TILE_E / 256;
    for (int k = 0; k < kmax; ++k) {
        const int e = base + k * 256 + tid;
        if (e < nnz) {
            const int r = rows[e];
            const int b = r >> BUCKET_SHIFT;
            const unsigned lrank = atomicAdd(&hist[b], 1u);
            const unsigned dst = lofs[b] + lrank;
            const unsigned key = ((unsigned)r << 15) | (unsigned)cols[e];
            temp[dst] = make_uint2(key, __float_as_uint(vals[e]));
        }
    }
}

// ---------------------------------------------------------------------------
// Partition level 2 (fused per-user counting): bucket-major temp -> exact CSR.
// ---------------------------------------------------------------------------
__global__ void csr_scatter_kernel(const uint2* __restrict__ temp,
                                   const unsigned* __restrict__ offsB,
                                   int* __restrict__ row_start,
                                   uint2* __restrict__ pairs,
                                   int ntiles, int num_users, int nbB) {
    __shared__ int cnt[BUCKET_W];
    __shared__ int scan_s[BUCKET_W];
    __shared__ int cur[BUCKET_W];
    const int b = blockIdx.x;
    const int tid = threadIdx.x;
    const int ubase = b << BUCKET_SHIFT;
    const int s0 = (int)offsB[(size_t)b * ntiles];
    const int s1 = (int)offsB[(size_t)(b + 1) * ntiles];

    cnt[tid] = 0;
    __syncthreads();
    for (int s = s0 + tid; s < s1; s += 256)
        atomicAdd(&cnt[(int)(temp[s].x >> 15) - ubase], 1);
    __syncthreads();

    const int x = cnt[tid];
    scan_s[tid] = x;
    __syncthreads();
    for (int off = 1; off < 256; off <<= 1) {
        int v = (tid >= off) ? scan_s[tid - off] : 0;
        __syncthreads();
        scan_s[tid] += v;
        __syncthreads();
    }
    const int start = s0 + scan_s[tid] - x;
    cur[tid] = start;
    if (ubase + tid < num_users) row_start[ubase + tid] = start;
    if (b == nbB - 1 && tid == 0) row_start[num_users] = s1;
    __syncthreads();

    for (int s = s0 + tid; s < s1; s += 256) {
        const uint2 e = temp[s];
        const int lu = (int)(e.x >> 15) - ubase;
        const int dst = atomicAdd(&cur[lu], 1);
        pairs[dst] = make_uint2(e.x & 0x7fffu, e.y);
    }
}

// ---------------------------------------------------------------------------
// Segment sum: one wave per user, register accumulation, 4x MLP.
// P read as bf16 (2.56MB, per-XCD L2-resident).
// ---------------------------------------------------------------------------
__global__ void gather_kernel(const int* __restrict__ row_start,
                              const uint2* __restrict__ pairs,
                              const unsigned short* __restrict__ Ph,
                              float* __restrict__ user_emb,
                              float* __restrict__ user_deg, int nu) {
    const int lane = threadIdx.x & 63;
    const int u = (blockIdx.x * blockDim.x + threadIdx.x) >> 6;
    if (u >= nu) return;

    const int s0 = row_start[u];
    const int s1 = row_start[u + 1];
    float acc0 = 0.0f, acc1 = 0.0f, acc2 = 0.0f, acc3 = 0.0f, deg = 0.0f;
    int s = s0;
    for (; s + 3 < s1; s += 4) {
        const uint2 pr0 = pairs[s];
        const uint2 pr1 = pairs[s + 1];
        const uint2 pr2 = pairs[s + 2];
        const uint2 pr3 = pairs[s + 3];
        const float v0 = __uint_as_float(pr0.y);
        const float v1 = __uint_as_float(pr1.y);
        const float v2 = __uint_as_float(pr2.y);
        const float v3 = __uint_as_float(pr3.y);
        acc0 = fmaf(v0, bf2f(Ph[(size_t)pr0.x * HIDDEN + lane]), acc0);
        acc1 = fmaf(v1, bf2f(Ph[(size_t)pr1.x * HIDDEN + lane]), acc1);
        acc2 = fmaf(v2, bf2f(Ph[(size_t)pr2.x * HIDDEN + lane]), acc2);
        acc3 = fmaf(v3, bf2f(Ph[(size_t)pr3.x * HIDDEN + lane]), acc3);
        deg += (v0 + v1) + (v2 + v3);
    }
    for (; s < s1; ++s) {
        const uint2 pr = pairs[s];
        const float v = __uint_as_float(pr.y);
        acc0 = fmaf(v, bf2f(Ph[(size_t)pr.x * HIDDEN + lane]), acc0);
        deg += v;
    }
    user_emb[(size_t)u * HIDDEN + lane] = (acc0 + acc1) + (acc2 + acc3);
    if (lane == 0) user_deg[u] = deg;
}

// ---------------------------------------------------------------------------
// Pos-pair sort phase A: per-tile bucket histogram of users, and materialize
// u_of/i_of (pays the random rows[pos_idx]/cols[pos_idx] gather ONCE).
// ---------------------------------------------------------------------------
__global__ void pos_hist_kernel(const int* __restrict__ pos_idx,
                                const int* __restrict__ rows,
                                const int* __restrict__ cols, int np,
                                int nbuckets, int ntiles,
                                unsigned* __restrict__ posHist,
                                int* __restrict__ u_of,
                                int* __restrict__ i_of) {
    extern __shared__ unsigned hist[];
    const int t = blockIdx.x;
    const int tid = threadIdx.x;
    for (int i = tid; i < nbuckets; i += blockDim.x) hist[i] = 0;
    __syncthreads();

    const int base = t * PTILE;
    const int kmax = PTILE / 256;
    for (int k = 0; k < kmax; ++k) {
        const int p = base + k * 256 + tid;
        if (p < np) {
            const int e = pos_idx[p];
            const int u = rows[e];
            u_of[p] = u;
            i_of[p] = cols[e];
            atomicAdd(&hist[u >> BUCKET_SHIFT], 1u);
        }
    }
    __syncthreads();
    for (int i = tid; i < nbuckets; i += blockDim.x)
        posHist[(size_t)i * ntiles + t] = hist[i];
}

// ---------------------------------------------------------------------------
// Pos-pair sort phase B: scatter full records {u,i,j0..j4} into bucket-major
// order. All reads sequential; writes land in ~32KB bucket windows.
// ---------------------------------------------------------------------------
__global__ void pos_partition_kernel(const int* __restrict__ u_of,
                                     const int* __restrict__ i_of,
                                     const int* __restrict__ neg_item_idx,
                                     int np, int nbuckets, int ntiles,
                                     const unsigned* __restrict__ posOffs,
                                     uint4* __restrict__ recs) {
    extern __shared__ unsigned smem[];
    unsigned* hist = smem;
    unsigned* lofs = smem + nbuckets;
    const int t = blockIdx.x;
    const int tid = threadIdx.x;
    for (int i = tid; i < nbuckets; i += blockDim.x) {
        hist[i] = 0;
        lofs[i] = posOffs[(size_t)i * ntiles + t];
    }
    __syncthreads();

    const int base = t * PTILE;
    const int kmax = PTILE / 256;
    for (int k = 0; k < kmax; ++k) {
        const int p = base + k * 256 + tid;
        if (p < np) {
            const int u = u_of[p];
            const int b = u >> BUCKET_SHIFT;
            const unsigned lrank = atomicAdd(&hist[b], 1u);
            const unsigned dst = lofs[b] + lrank;
            const int j0 = neg_item_idx[5 * p + 0];
            const int j1 = neg_item_idx[5 * p + 1];
            const int j2 = neg_item_idx[5 * p + 2];
            const int j3 = neg_item_idx[5 * p + 3];
            const int j4 = neg_item_idx[5 * p + 4];
            recs[2 * (size_t)dst + 0] = make_uint4(u, i_of[p], j0, j1);
            recs[2 * (size_t)dst + 1] = make_uint4(j2, j3, j4, 0u);
        }
    }
}

// ---------------------------------------------------------------------------
// Pair loss over user-sorted records. 16-lane group per pair; Q in bf16
// (L2-resident); XCD-chunk bijective swizzle so each XCD owns a contiguous
// user range (user_emb L2-local).
// ---------------------------------------------------------------------------
__global__ void loss_sorted_kernel(const float* __restrict__ user_emb,
                                   const float* __restrict__ user_deg,
                                   const unsigned short* __restrict__ Qh,
                                   const float* __restrict__ b_u,
                                   const float* __restrict__ b_i,
                                   const uint4* __restrict__ recs,
                                   int num_pos,
                                   float* __restrict__ out_loss) {
    // bijective XCD swizzle (m204 variant)
    const int nwg = gridDim.x;
    const int orig = blockIdx.x;
    const int xcd = orig & 7;
    const int k = orig >> 3;
    const int q = nwg >> 3, r = nwg & 7;
    const int blk = (xcd < r ? xcd * (q + 1) : r * (q + 1) + (xcd - r) * q) + k;

    const int tid = blk * (int)blockDim.x + (int)threadIdx.x;
    const int g = tid >> 4;
    const int l = tid & 15;
    float acc = 0.0f;

    if (g < num_pos) {
        const uint4 r0 = recs[2 * (size_t)g + 0];
        const uint4 r1 = recs[2 * (size_t)g + 1];
        const int u = (int)r0.x;
        const int ii = (int)r0.y;
        int jarr[5] = {(int)r0.z, (int)r0.w, (int)r1.x, (int)r1.y, (int)r1.z};

        const float invdeg = 1.0f / user_deg[u];
        float4 ue = ((const float4*)(user_emb + (size_t)u * HIDDEN))[l];
        ue.x *= invdeg; ue.y *= invdeg; ue.z *= invdeg; ue.w *= invdeg;

        float part[6];
        {
            const ushort4 qv = ((const ushort4*)(Qh + (size_t)ii * HIDDEN))[l];
            part[0] = fmaf(ue.x, bf2f(qv.x), fmaf(ue.y, bf2f(qv.y),
                      fmaf(ue.z, bf2f(qv.z), ue.w * bf2f(qv.w))));
        }
        #pragma unroll
        for (int s = 0; s < 5; ++s) {
            const ushort4 qv =
                ((const ushort4*)(Qh + (size_t)jarr[s] * HIDDEN))[l];
            part[1 + s] = fmaf(ue.x, bf2f(qv.x), fmaf(ue.y, bf2f(qv.y),
                          fmaf(ue.z, bf2f(qv.z), ue.w * bf2f(qv.w))));
        }
        #pragma unroll
        for (int m = 1; m < 16; m <<= 1) {
            #pragma unroll
            for (int kk = 0; kk < 6; ++kk)
                part[kk] += __shfl_xor(part[kk], m, 16);
        }

        if (l == 0) {
            const float bu = b_u[u];
            const float rr = bu + b_i[ii] + part[0];
            #pragma unroll
            for (int s = 0; s < 5; ++s) {
                const float nr = bu + b_i[jarr[s]] + part[1 + s];
                const float diff = 1.0f - (rr - nr);
                acc += 0.5f * diff * diff;
            }
        }
    }

    for (int off = 32; off; off >>= 1) acc += __shfl_down(acc, off);
    __shared__ float s_part[16];
    const int wave = threadIdx.x >> 6;
    const int lane = threadIdx.x & 63;
    if (lane == 0) s_part[wave] = acc;
    __syncthreads();
    if (threadIdx.x == 0) {
        float t = 0.0f;
        const int nw = blockDim.x >> 6;
        for (int w = 0; w < nw; ++w) t += s_part[w];
        atomicAdd(out_loss, t);
    }
}

// generic fallback (thread per pair, unsorted), only used if S != 5
__global__ void loss_generic_kernel(const float* __restrict__ user_emb,
                                    const float* __restrict__ user_deg,
                                    const unsigned short* __restrict__ Qh,
                                    const float* __restrict__ b_u,
                                    const float* __restrict__ b_i,
                                    const int* __restrict__ rows,
                                    const int* __restrict__ cols,
                                    const int* __restrict__ pos_idx,
                                    const int* __restrict__ neg_item_idx,
                                    int num_pos, int S,
                                    float* __restrict__ out_loss) {
    const int p = blockIdx.x * blockDim.x + threadIdx.x;
    float acc = 0.0f;
    if (p < num_pos) {
        const int e = pos_idx[p];
        const int u = rows[e];
        const int ii = cols[e];
        const float invdeg = 1.0f / user_deg[u];
        float ue[HIDDEN];
        #pragma unroll
        for (int kk = 0; kk < HIDDEN; ++kk)
            ue[kk] = user_emb[(size_t)u * HIDDEN + kk] * invdeg;
        const float bu = b_u[u];
        float dot = 0.0f;
        #pragma unroll
        for (int kk = 0; kk < HIDDEN; ++kk)
            dot = fmaf(ue[kk], bf2f(Qh[(size_t)ii * HIDDEN + kk]), dot);
        const float rr = bu + b_i[ii] + dot;
        for (int s = 0; s < S; ++s) {
            const int j = neg_item_idx[(size_t)p * S + s];
            float dn = 0.0f;
            #pragma unroll
            for (int kk = 0; kk < HIDDEN; ++kk)
                dn = fmaf(ue[kk], bf2f(Qh[(size_t)j * HIDDEN + kk]), dn);
            const float nr = bu + b_i[j] + dn;
            const float diff = 1.0f - (rr - nr);
            acc += 0.5f * diff * diff;
        }
    }
    for (int off = 32; off; off >>= 1) acc += __shfl_down(acc, off);
    __shared__ float s_part[16];
    const int wave = threadIdx.x >> 6;
    const int lane = threadIdx.x & 63;
    if (lane == 0) s_part[wave] = acc;
    __syncthreads();
    if (threadIdx.x == 0) {
        float t = 0.0f;
        const int nw = blockDim.x >> 6;
        for (int w = 0; w < nw; ++w) t += s_part[w];
        atomicAdd(out_loss, t);
    }
}

// ---------------------------------------------------------------------------
// Bias regularizer 0.5*GAMMA*(sum b_u^2 + sum b_i^2)
// ---------------------------------------------------------------------------
__global__ void bias_reg_kernel(const float* __restrict__ b_u, int nu,
                                const float* __restrict__ b_i, int ni,
                                float* __restrict__ out_loss) {
    const int tid = blockIdx.x * blockDim.x + threadIdx.x;
    const int stride = gridDim.x * blockDim.x;
    const int n = nu + ni;
    float acc = 0.0f;
    for (int x = tid; x < n; x += stride) {
        float v = (x < nu) ? b_u[x] : b_i[x - nu];
        acc += v * v;
    }
    for (int off = 32; off; off >>= 1) acc += __shfl_down(acc, off);
    __shared__ float s_part[16];
    const int wave = threadIdx.x >> 6;
    const int lane = threadIdx.x & 63;
    if (lane == 0) s_part[wave] = acc;
    __syncthreads();
    if (threadIdx.x == 0) {
        float t = 0.0f;
        const int nw = blockDim.x >> 6;
        for (int w = 0; w < nw; ++w) t += s_part[w];
        atomicAdd(out_loss, 0.5f * GAMMA * t);
    }
}

// ---------------------------------------------------------------------------
extern "C" void kernel_launch(void* const* d_in, const int* in_sizes, int n_in,
                              void* d_out, int out_size, void* d_ws, size_t ws_size,
                              hipStream_t stream) {
    const float* features     = (const float*)d_in[0];
    const float* W_enc        = (const float*)d_in[1];
    const float* b_enc        = (const float*)d_in[2];
    const float* W_p          = (const float*)d_in[3];
    const float* W_q          = (const float*)d_in[4];
    const float* b_u          = (const float*)d_in[5];
    const float* b_i          = (const float*)d_in[6];
    const float* vals         = (const float*)d_in[7];
    const int*   rows         = (const int*)d_in[8];
    const int*   cols         = (const int*)d_in[9];
    const int*   pos_idx      = (const int*)d_in[10];
    const int*   neg_item_idx = (const int*)d_in[11];

    const int num_users  = in_sizes[5];                 // 50000
    const int num_movies = in_sizes[6];                 // 20000
    const int in_feats   = in_sizes[0] / num_movies;    // 128
    const int nnz        = in_sizes[7];                 // 2000000
    const int num_pos    = in_sizes[10];                // 200000
    const int S          = in_sizes[11] / num_pos;      // 5

    const int nbB    = (num_users + BUCKET_W - 1) >> BUCKET_SHIFT;  // 196
    const int ntiles = (nnz + TILE_E - 1) / TILE_E;                 // 245
    const int scanNB = nbB * ntiles;                                // 48020
    const int n1b    = (scanNB + 255) / 256;                        // 188
    const int nt2    = (num_pos + PTILE - 1) / PTILE;               // 25
    const int scanNP = nbB * nt2;                                   // 4900
    const int n1p    = (scanNP + 255) / 256;                        // 20

    // workspace layout (256B-aligned). Time-shared region U:
    //   H (encode) | temp (partition) | user_emb (gather+loss)
    auto align256 = [](size_t x) { return (x + 255) & ~(size_t)255; };
    char* ws = (char*)d_ws;
    size_t off = 0;
    unsigned short* Ph = (unsigned short*)(ws + off);
    off += align256((size_t)num_movies * HIDDEN * 2);
    unsigned short* Qh = (unsigned short*)(ws + off);
    off += align256((size_t)num_movies * HIDDEN * 2);
    char* U = ws + off;
    const size_t h_bytes   = align256((size_t)num_movies * HIDDEN * 4);
    const size_t emb_bytes = align256((size_t)num_users * HIDDEN * 4);
    const size_t tmp_bytes = align256((size_t)nnz * 8);
    float* H        = (float*)U;
    float* user_emb = (float*)(U + h_bytes);
    uint2* temp     = (uint2*)U;
    off += (h_bytes + emb_bytes > tmp_bytes) ? (h_bytes + emb_bytes) : tmp_bytes;
    float* user_deg = (float*)(ws + off); off += align256((size_t)num_users * 4);
    int*   row_start= (int*)(ws + off);   off += align256((size_t)(num_users + 1) * 4);
    unsigned* tileHistB = (unsigned*)(ws + off); off += align256((size_t)scanNB * 4);
    unsigned* offsB     = (unsigned*)(ws + off); off += align256((size_t)(scanNB + 1) * 4);
    unsigned* sums_b    = (unsigned*)(ws + off); off += align256(256 * 4);
    unsigned* top_b     = (unsigned*)(ws + off); off += align256(256 * 4);
    uint2* pairs        = (uint2*)(ws + off);    off += align256((size_t)nnz * 8);
    int*   u_of         = (int*)(ws + off);      off += align256((size_t)num_pos * 4);
    int*   i_of         = (int*)(ws + off);      off += align256((size_t)num_pos * 4);
    unsigned* posHist   = (unsigned*)(ws + off); off += align256((size_t)scanNP * 4);
    unsigned* posOffs   = (unsigned*)(ws + off); off += align256((size_t)(scanNP + 1) * 4);
    unsigned* sums_p    = (unsigned*)(ws + off); off += align256(256 * 4);
    unsigned* top_p     = (unsigned*)(ws + off); off += align256(256 * 4);
    uint4* recs         = (uint4*)(ws + off);    off += align256((size_t)num_pos * 32);

    float* out = (float*)d_out;
    hipMemsetAsync(out, 0, sizeof(float), stream);

    // encode
    const int enc_blocks = (num_movies * 64 + 255) / 256;
    h_kernel<<<enc_blocks, 256, 0, stream>>>(features, W_enc, b_enc, H,
                                             num_movies, in_feats);
    pq_kernel<<<enc_blocks, 256, 0, stream>>>(H, W_p, W_q, Ph, Qh, out,
                                              num_movies);

    // nnz bucket histogram + scan -> offsB
    tilehist_kernel<<<ntiles, 256, (size_t)nbB * 4, stream>>>(
        rows, nnz, nbB, ntiles, tileHistB);
    chunksum_kernel<<<n1b, 256, 0, stream>>>(tileHistB, scanNB, sums_b);
    scantop_kernel<<<1, 256, 0, stream>>>(sums_b, n1b, top_b, offsB, scanNB, nnz);
    exscan_kernel<<<n1b, 256, 0, stream>>>(tileHistB, scanNB, top_b, offsB);

    // two-level partition -> exact CSR pairs (+ row_start fused)
    partition_kernel<<<ntiles, 256, (size_t)nbB * 8, stream>>>(
        rows, cols, vals, nnz, nbB, ntiles, offsB, temp);
    csr_scatter_kernel<<<nbB, 256, 0, stream>>>(temp, offsB, row_start, pairs,
                                                ntiles, num_users, nbB);

    // segment sum (register gather, bf16 P)
    gather_kernel<<<(num_users * 64 + 255) / 256, 256, 0, stream>>>(
        row_start, pairs, Ph, user_emb, user_deg, num_users);

    if (S == 5) {
        // pos-pair sort by user bucket
        pos_hist_kernel<<<nt2, 256, (size_t)nbB * 4, stream>>>(
            pos_idx, rows, cols, num_pos, nbB, nt2, posHist, u_of, i_of);
        chunksum_kernel<<<n1p, 256, 0, stream>>>(posHist, scanNP, sums_p);
        scantop_kernel<<<1, 256, 0, stream>>>(sums_p, n1p, top_p, posOffs,
                                              scanNP, num_pos);
        exscan_kernel<<<n1p, 256, 0, stream>>>(posHist, scanNP, top_p, posOffs);
        pos_partition_kernel<<<nt2, 256, (size_t)nbB * 8, stream>>>(
            u_of, i_of, neg_item_idx, num_pos, nbB, nt2, posOffs, recs);

        const int nblk = ((size_t)num_pos * 16 + 255) / 256;
        loss_sorted_kernel<<<nblk, 256, 0, stream>>>(
            user_emb, user_deg, Qh, b_u, b_i, recs, num_pos, out);
    } else {
        loss_generic_kernel<<<(num_pos + 255) / 256, 256, 0, stream>>>(
            user_emb, user_deg, Qh, b_u, b_i, rows, cols, pos_idx,
            neg_item_idx, num_pos, S, out);
    }

    bias_reg_kernel<<<128, 256, 0, stream>>>(b_u, num_users, b_i, num_movies, out);
}

// Round 9
// 251.016 us; speedup vs baseline: 1.9260x; 1.9260x over previous
//
#include <hip/hip_runtime.h>

#define HIDDEN 64
#define BETA 0.01f
#define GAMMA 0.01f

#define BUCKET_SHIFT 8                 // 256 users per bucket
#define BUCKET_W     (1 << BUCKET_SHIFT)
#define TILE_E       8192              // entries per partition tile

__device__ inline unsigned short f2bf(float f) {   // RNE float->bf16
    unsigned x = __float_as_uint(f);
    return (unsigned short)((x + 0x7fffu + ((x >> 16) & 1u)) >> 16);
}
__device__ inline float bf2f(unsigned short b) {
    return __uint_as_float(((unsigned)b) << 16);
}

// ---------------------------------------------------------------------------
// Encode phase A: H = features @ W_enc + b_enc
// ---------------------------------------------------------------------------
__global__ void h_kernel(const float* __restrict__ features,
                         const float* __restrict__ W_enc,
                         const float* __restrict__ b_enc,
                         float* __restrict__ H,
                         int num_movies, int in_feats) {
    const int tid = blockIdx.x * blockDim.x + threadIdx.x;
    const int j = tid & 63;
    const int m = tid >> 6;
    if (m >= num_movies) return;

    const float* frow = features + (size_t)m * in_feats;
    float a0 = 0.0f, a1 = 0.0f, a2 = 0.0f, a3 = 0.0f;
    #pragma unroll 8
    for (int f = 0; f < in_feats; f += 4) {
        const float4 fv = *(const float4*)(frow + f);
        a0 = fmaf(fv.x, W_enc[(f + 0) * HIDDEN + j], a0);
        a1 = fmaf(fv.y, W_enc[(f + 1) * HIDDEN + j], a1);
        a2 = fmaf(fv.z, W_enc[(f + 2) * HIDDEN + j], a2);
        a3 = fmaf(fv.w, W_enc[(f + 3) * HIDDEN + j], a3);
    }
    H[(size_t)m * HIDDEN + j] = (a0 + a1) + (a2 + a3) + b_enc[j];
}

// ---------------------------------------------------------------------------
// Encode phase B: P/Q in bf16; BETA regularizer partial per block ->
// partials[slot_base + blockIdx.x] (plain store, no atomics).
// ---------------------------------------------------------------------------
__global__ void pq_kernel(const float* __restrict__ H,
                          const float* __restrict__ W_p,
                          const float* __restrict__ W_q,
                          unsigned short* __restrict__ Ph,
                          unsigned short* __restrict__ Qh,
                          float* __restrict__ partials, int slot_base,
                          int num_movies) {
    const int tid = blockIdx.x * blockDim.x + threadIdx.x;
    const int j = tid & 63;
    const int m = tid >> 6;
    float reg = 0.0f;

    if (m < num_movies) {
        const float* hrow = H + (size_t)m * HIDDEN;
        float p0 = 0.0f, p1 = 0.0f, p2 = 0.0f, p3 = 0.0f;
        float q0 = 0.0f, q1 = 0.0f, q2 = 0.0f, q3 = 0.0f;
        #pragma unroll 4
        for (int f = 0; f < HIDDEN; f += 4) {
            const float4 hv = *(const float4*)(hrow + f);
            p0 = fmaf(hv.x, W_p[(f + 0) * HIDDEN + j], p0);
            p1 = fmaf(hv.y, W_p[(f + 1) * HIDDEN + j], p1);
            p2 = fmaf(hv.z, W_p[(f + 2) * HIDDEN + j], p2);
            p3 = fmaf(hv.w, W_p[(f + 3) * HIDDEN + j], p3);
            q0 = fmaf(hv.x, W_q[(f + 0) * HIDDEN + j], q0);
            q1 = fmaf(hv.y, W_q[(f + 1) * HIDDEN + j], q1);
            q2 = fmaf(hv.z, W_q[(f + 2) * HIDDEN + j], q2);
            q3 = fmaf(hv.w, W_q[(f + 3) * HIDDEN + j], q3);
        }
        const float p = (p0 + p1) + (p2 + p3);
        const float q = (q0 + q1) + (q2 + q3);
        Ph[(size_t)m * HIDDEN + j] = f2bf(p);
        Qh[(size_t)m * HIDDEN + j] = f2bf(q);
        reg = p * p + q * q;
    }

    for (int off = 32; off; off >>= 1) reg += __shfl_down(reg, off);
    __shared__ float s_part[16];
    const int wave = threadIdx.x >> 6;
    const int lane = threadIdx.x & 63;
    if (lane == 0) s_part[wave] = reg;
    __syncthreads();
    if (threadIdx.x == 0) {
        float t = 0.0f;
        const int nw = blockDim.x >> 6;
        for (int w = 0; w < nw; ++w) t += s_part[w];
        partials[slot_base + blockIdx.x] = 0.5f * BETA * t;
    }
}

// ---------------------------------------------------------------------------
// Per-tile LDS bucket histogram over nnz entries.
// ---------------------------------------------------------------------------
__global__ void tilehist_kernel(const int* __restrict__ rows, int nnz,
                                int nbuckets, int ntiles,
                                unsigned* __restrict__ tileHist) {
    extern __shared__ unsigned hist[];
    const int t = blockIdx.x;
    const int tid = threadIdx.x;
    for (int i = tid; i < nbuckets; i += blockDim.x) hist[i] = 0;
    __syncthreads();

    const int base = t * TILE_E;
    const int kmax = TILE_E / 256;
    for (int k = 0; k < kmax; ++k) {
        const int e = base + k * 256 + tid;
        if (e < nnz) atomicAdd(&hist[rows[e] >> BUCKET_SHIFT], 1u);
    }
    __syncthreads();
    for (int i = tid; i < nbuckets; i += blockDim.x)
        tileHist[(size_t)i * ntiles + t] = hist[i];
}

// ---------------------------------------------------------------------------
// Generic 2-level scan building blocks (n <= 256*256).
// ---------------------------------------------------------------------------
__global__ void chunksum_kernel(const unsigned* __restrict__ src, int n,
                                unsigned* __restrict__ sums) {
    __shared__ unsigned s[256];
    const int t = threadIdx.x;
    const int i = blockIdx.x * 256 + t;
    s[t] = (i < n) ? src[i] : 0u;
    __syncthreads();
    for (int off = 128; off; off >>= 1) {
        if (t < off) s[t] += s[t + off];
        __syncthreads();
    }
    if (t == 0) sums[blockIdx.x] = s[0];
}

__global__ void scantop_kernel(const unsigned* __restrict__ sums, int nchunks,
                               unsigned* __restrict__ chunk_off,
                               unsigned* __restrict__ offs, int n, int total) {
    __shared__ unsigned s[256];
    const int t = threadIdx.x;
    unsigned x = (t < nchunks) ? sums[t] : 0u;
    s[t] = x;
    __syncthreads();
    for (int off = 1; off < 256; off <<= 1) {
        unsigned v = (t >= off) ? s[t - off] : 0u;
        __syncthreads();
        s[t] += v;
        __syncthreads();
    }
    if (t < nchunks) chunk_off[t] = s[t] - x;   // exclusive
    if (t == 0) offs[n] = (unsigned)total;
}

__global__ void exscan_kernel(const unsigned* __restrict__ src, int n,
                              const unsigned* __restrict__ chunk_off,
                              unsigned* __restrict__ dst) {
    __shared__ unsigned s[256];
    const int t = threadIdx.x;
    const int i = blockIdx.x * 256 + t;
    unsigned x = (i < n) ? src[i] : 0u;
    s[t] = x;
    __syncthreads();
    for (int off = 1; off < 256; off <<= 1) {
        unsigned v = (t >= off) ? s[t - off] : 0u;
        __syncthreads();
        s[t] += v;
        __syncthreads();
    }
    if (i < n) dst[i] = chunk_off[blockIdx.x] + s[t] - x;
}

// ---------------------------------------------------------------------------
// Partition level 1: scatter nnz entries into bucket-major temp order.
// key = (user << 15) | col
// ---------------------------------------------------------------------------
__global__ void partition_kernel(const int* __restrict__ rows,
                                 const int* __restrict__ cols,
                                 const float* __restrict__ vals, int nnz,
                                 int nbuckets, int ntiles,
                                 const unsigned* __restrict__ offsB,
                                 uint2* __restrict__ temp) {
    extern __shared__ unsigned smem[];          // hist[nb] then lofs[nb]
    unsigned* hist = smem;
    unsigned* lofs = smem + nbuckets;
    const int t = blockIdx.x;
    const int tid = threadIdx.x;
    for (int i = tid; i < nbuckets; i += blockDim.x) {
        hist[i] = 0;
        lofs[i] = offsB[(size_t)i * ntiles + t];
    }
    __syncthreads();

    const int base = t * TILE_E;
    const int kmax = TILE_E / 256;
    for (int k = 0; k < kmax; ++k) {
        const int e = base + k * 256 + tid;
        if (e < nnz) {
            const int r = rows[e];
            const int b = r >> BUCKET_SHIFT;
            const unsigned lrank = atomicAdd(&hist[b], 1u);
            const unsigned dst = lofs[b] + lrank;
            const unsigned key = ((unsigned)r << 15) | (unsigned)cols[e];
            temp[dst] = make_uint2(key, __float_as_uint(vals[e]));
        }
    }
}

// ---------------------------------------------------------------------------
// Partition level 2 (fused per-user counting): bucket-major temp -> exact CSR.
// ---------------------------------------------------------------------------
__global__ void csr_scatter_kernel(const uint2* __restrict__ temp,
                                   const unsigned* __restrict__ offsB,
                                   int* __restrict__ row_start,
                                   uint2* __restrict__ pairs,
                                   int ntiles, int num_users, int nbB) {
    __shared__ int cnt[BUCKET_W];
    __shared__ int scan_s[BUCKET_W];
    __shared__ int cur[BUCKET_W];
    const int b = blockIdx.x;
    const int tid = threadIdx.x;
    const int ubase = b << BUCKET_SHIFT;
    const int s0 = (int)offsB[(size_t)b * ntiles];
    const int s1 = (int)offsB[(size_t)(b + 1) * ntiles];

    cnt[tid] = 0;
    __syncthreads();
    for (int s = s0 + tid; s < s1; s += 256)
        atomicAdd(&cnt[(int)(temp[s].x >> 15) - ubase], 1);
    __syncthreads();

    const int x = cnt[tid];
    scan_s[tid] = x;
    __syncthreads();
    for (int off = 1; off < 256; off <<= 1) {
        int v = (tid >= off) ? scan_s[tid - off] : 0;
        __syncthreads();
        scan_s[tid] += v;
        __syncthreads();
    }
    const int start = s0 + scan_s[tid] - x;
    cur[tid] = start;
    if (ubase + tid < num_users) row_start[ubase + tid] = start;
    if (b == nbB - 1 && tid == 0) row_start[num_users] = s1;
    __syncthreads();

    for (int s = s0 + tid; s < s1; s += 256) {
        const uint2 e = temp[s];
        const int lu = (int)(e.x >> 15) - ubase;
        const int dst = atomicAdd(&cur[lu], 1);
        pairs[dst] = make_uint2(e.x & 0x7fffu, e.y);
    }
}

// ---------------------------------------------------------------------------
// Segment sum: one wave per user, register accumulation, 4x MLP, bf16 P.
// ---------------------------------------------------------------------------
__global__ void gather_kernel(const int* __restrict__ row_start,
                              const uint2* __restrict__ pairs,
                              const unsigned short* __restrict__ Ph,
                              float* __restrict__ user_emb,
                              float* __restrict__ user_deg, int nu) {
    const int lane = threadIdx.x & 63;
    const int u = (blockIdx.x * blockDim.x + threadIdx.x) >> 6;
    if (u >= nu) return;

    const int s0 = row_start[u];
    const int s1 = row_start[u + 1];
    float acc0 = 0.0f, acc1 = 0.0f, acc2 = 0.0f, acc3 = 0.0f, deg = 0.0f;
    int s = s0;
    for (; s + 3 < s1; s += 4) {
        const uint2 pr0 = pairs[s];
        const uint2 pr1 = pairs[s + 1];
        const uint2 pr2 = pairs[s + 2];
        const uint2 pr3 = pairs[s + 3];
        const float v0 = __uint_as_float(pr0.y);
        const float v1 = __uint_as_float(pr1.y);
        const float v2 = __uint_as_float(pr2.y);
        const float v3 = __uint_as_float(pr3.y);
        acc0 = fmaf(v0, bf2f(Ph[(size_t)pr0.x * HIDDEN + lane]), acc0);
        acc1 = fmaf(v1, bf2f(Ph[(size_t)pr1.x * HIDDEN + lane]), acc1);
        acc2 = fmaf(v2, bf2f(Ph[(size_t)pr2.x * HIDDEN + lane]), acc2);
        acc3 = fmaf(v3, bf2f(Ph[(size_t)pr3.x * HIDDEN + lane]), acc3);
        deg += (v0 + v1) + (v2 + v3);
    }
    for (; s < s1; ++s) {
        const uint2 pr = pairs[s];
        const float v = __uint_as_float(pr.y);
        acc0 = fmaf(v, bf2f(Ph[(size_t)pr.x * HIDDEN + lane]), acc0);
        deg += v;
    }
    user_emb[(size_t)u * HIDDEN + lane] = (acc0 + acc1) + (acc2 + acc3);
    if (lane == 0) user_deg[u] = deg;
}

// ---------------------------------------------------------------------------
// 16 bf16 x 16 fp32 dot for one lane: q points at 32B (2 x uint4).
// Unpack trick: lo = w<<16, hi = w & 0xffff0000 (1 VALU each).
// ---------------------------------------------------------------------------
__device__ inline float dot16(const uint4* __restrict__ q,
                              const float* __restrict__ ue) {
    float d = 0.0f;
    #pragma unroll
    for (int h = 0; h < 2; ++h) {
        const uint4 v = q[h];
        const unsigned w0 = v.x, w1 = v.y, w2 = v.z, w3 = v.w;
        d = fmaf(ue[h * 8 + 0], __uint_as_float(w0 << 16), d);
        d = fmaf(ue[h * 8 + 1], __uint_as_float(w0 & 0xffff0000u), d);
        d = fmaf(ue[h * 8 + 2], __uint_as_float(w1 << 16), d);
        d = fmaf(ue[h * 8 + 3], __uint_as_float(w1 & 0xffff0000u), d);
        d = fmaf(ue[h * 8 + 4], __uint_as_float(w2 << 16), d);
        d = fmaf(ue[h * 8 + 5], __uint_as_float(w2 & 0xffff0000u), d);
        d = fmaf(ue[h * 8 + 6], __uint_as_float(w3 << 16), d);
        d = fmaf(ue[h * 8 + 7], __uint_as_float(w3 & 0xffff0000u), d);
    }
    return d;
}

// ---------------------------------------------------------------------------
// Pair loss, 4-lane group per pair (lane = 16 components). Only 12 shfl_xor
// per wave-iteration (serving 16 pairs), no global atomics (partial store).
// ---------------------------------------------------------------------------
template <int S>
__global__ void loss4_kernel(const float* __restrict__ user_emb,
                             const float* __restrict__ user_deg,
                             const unsigned short* __restrict__ Qh,
                             const float* __restrict__ b_u,
                             const float* __restrict__ b_i,
                             const int* __restrict__ rows,
                             const int* __restrict__ cols,
                             const int* __restrict__ pos_idx,
                             const int* __restrict__ neg_item_idx,
                             int num_pos,
                             float* __restrict__ partials, int slot_base) {
    const int tid = blockIdx.x * blockDim.x + threadIdx.x;
    const int g = tid >> 2;            // pair index
    const int l = tid & 3;             // lane-in-group: components [16l,16l+16)
    float acc = 0.0f;

    if (g < num_pos) {
        const int e = pos_idx[g];
        const int u = rows[e];
        const int ii = cols[e];
        const float invdeg = 1.0f / user_deg[u];

        float ue[16];
        {
            const float4* uep =
                (const float4*)(user_emb + (size_t)u * HIDDEN + l * 16);
            #pragma unroll
            for (int k = 0; k < 4; ++k) {
                const float4 t4 = uep[k];
                ue[4 * k + 0] = t4.x * invdeg;
                ue[4 * k + 1] = t4.y * invdeg;
                ue[4 * k + 2] = t4.z * invdeg;
                ue[4 * k + 3] = t4.w * invdeg;
            }
        }

        int jarr[S];
        float part[1 + S];
        part[0] = dot16((const uint4*)(Qh + (size_t)ii * HIDDEN + l * 16), ue);
        #pragma unroll
        for (int s = 0; s < S; ++s) {
            const int j = neg_item_idx[(size_t)g * S + s];
            jarr[s] = j;
            part[1 + s] =
                dot16((const uint4*)(Qh + (size_t)j * HIDDEN + l * 16), ue);
        }

        // 2-step quad reduction (xor 1, 2 stay within the aligned 4-group)
        #pragma unroll
        for (int k = 0; k < 1 + S; ++k) {
            part[k] += __shfl_xor(part[k], 1);
            part[k] += __shfl_xor(part[k], 2);
        }

        if (l == 0) {
            const float bu = b_u[u];
            const float r = bu + b_i[ii] + part[0];
            #pragma unroll
            for (int s = 0; s < S; ++s) {
                const float nr = bu + b_i[jarr[s]] + part[1 + s];
                const float diff = 1.0f - (r - nr);
                acc += 0.5f * diff * diff;
            }
        }
    }

    // wave + block reduction -> plain store to this block's slot
    for (int off = 32; off; off >>= 1) acc += __shfl_down(acc, off);
    __shared__ float s_part[16];
    const int wave = threadIdx.x >> 6;
    const int lane = threadIdx.x & 63;
    if (lane == 0) s_part[wave] = acc;
    __syncthreads();
    if (threadIdx.x == 0) {
        float t = 0.0f;
        const int nw = blockDim.x >> 6;
        for (int w = 0; w < nw; ++w) t += s_part[w];
        partials[slot_base + blockIdx.x] = t;
    }
}

// generic fallback (thread per pair), only used if S != 5
__global__ void loss_generic_kernel(const float* __restrict__ user_emb,
                                    const float* __restrict__ user_deg,
                                    const unsigned short* __restrict__ Qh,
                                    const float* __restrict__ b_u,
                                    const float* __restrict__ b_i,
                                    const int* __restrict__ rows,
                                    const int* __restrict__ cols,
                                    const int* __restrict__ pos_idx,
                                    const int* __restrict__ neg_item_idx,
                                    int num_pos, int S,
                                    float* __restrict__ partials,
                                    int slot_base) {
    const int p = blockIdx.x * blockDim.x + threadIdx.x;
    float acc = 0.0f;
    if (p < num_pos) {
        const int e = pos_idx[p];
        const int u = rows[e];
        const int ii = cols[e];
        const float invdeg = 1.0f / user_deg[u];
        float ue[HIDDEN];
        #pragma unroll
        for (int kk = 0; kk < HIDDEN; ++kk)
            ue[kk] = user_emb[(size_t)u * HIDDEN + kk] * invdeg;
        const float bu = b_u[u];
        float dot = 0.0f;
        #pragma unroll
        for (int kk = 0; kk < HIDDEN; ++kk)
            dot = fmaf(ue[kk], bf2f(Qh[(size_t)ii * HIDDEN + kk]), dot);
        const float rr = bu + b_i[ii] + dot;
        for (int s = 0; s < S; ++s) {
            const int j = neg_item_idx[(size_t)p * S + s];
            float dn = 0.0f;
            #pragma unroll
            for (int kk = 0; kk < HIDDEN; ++kk)
                dn = fmaf(ue[kk], bf2f(Qh[(size_t)j * HIDDEN + kk]), dn);
            const float nr = bu + b_i[j] + dn;
            const float diff = 1.0f - (rr - nr);
            acc += 0.5f * diff * diff;
        }
    }
    for (int off = 32; off; off >>= 1) acc += __shfl_down(acc, off);
    __shared__ float s_part[16];
    const int wave = threadIdx.x >> 6;
    const int lane = threadIdx.x & 63;
    if (lane == 0) s_part[wave] = acc;
    __syncthreads();
    if (threadIdx.x == 0) {
        float t = 0.0f;
        const int nw = blockDim.x >> 6;
        for (int w = 0; w < nw; ++w) t += s_part[w];
        partials[slot_base + blockIdx.x] = t;
    }
}

// ---------------------------------------------------------------------------
// Bias regularizer partials: 0.5*GAMMA*(sum b_u^2 + sum b_i^2)
// ---------------------------------------------------------------------------
__global__ void bias_reg_kernel(const float* __restrict__ b_u, int nu,
                                const float* __restrict__ b_i, int ni,
                                float* __restrict__ partials, int slot_base) {
    const int tid = blockIdx.x * blockDim.x + threadIdx.x;
    const int stride = gridDim.x * blockDim.x;
    const int n = nu + ni;
    float acc = 0.0f;
    for (int x = tid; x < n; x += stride) {
        float v = (x < nu) ? b_u[x] : b_i[x - nu];
        acc += v * v;
    }
    for (int off = 32; off; off >>= 1) acc += __shfl_down(acc, off);
    __shared__ float s_part[16];
    const int wave = threadIdx.x >> 6;
    const int lane = threadIdx.x & 63;
    if (lane == 0) s_part[wave] = acc;
    __syncthreads();
    if (threadIdx.x == 0) {
        float t = 0.0f;
        const int nw = blockDim.x >> 6;
        for (int w = 0; w < nw; ++w) t += s_part[w];
        partials[slot_base + blockIdx.x] = 0.5f * GAMMA * t;
    }
}

// ---------------------------------------------------------------------------
// Deterministic final reduction of all partial slots -> out[0].
// ---------------------------------------------------------------------------
__global__ void final_reduce_kernel(const float* __restrict__ partials, int n,
                                    float* __restrict__ out) {
    __shared__ float s[256];
    float a = 0.0f;
    for (int i = threadIdx.x; i < n; i += 256) a += partials[i];
    s[threadIdx.x] = a;
    __syncthreads();
    for (int off = 128; off; off >>= 1) {
        if (threadIdx.x < off) s[threadIdx.x] += s[threadIdx.x + off];
        __syncthreads();
    }
    if (threadIdx.x == 0) out[0] = s[0];
}

// ---------------------------------------------------------------------------
extern "C" void kernel_launch(void* const* d_in, const int* in_sizes, int n_in,
                              void* d_out, int out_size, void* d_ws, size_t ws_size,
                              hipStream_t stream) {
    const float* features     = (const float*)d_in[0];
    const float* W_enc        = (const float*)d_in[1];
    const float* b_enc        = (const float*)d_in[2];
    const float* W_p          = (const float*)d_in[3];
    const float* W_q          = (const float*)d_in[4];
    const float* b_u          = (const float*)d_in[5];
    const float* b_i          = (const float*)d_in[6];
    const float* vals         = (const float*)d_in[7];
    const int*   rows         = (const int*)d_in[8];
    const int*   cols         = (const int*)d_in[9];
    const int*   pos_idx      = (const int*)d_in[10];
    const int*   neg_item_idx = (const int*)d_in[11];

    const int num_users  = in_sizes[5];                 // 50000
    const int num_movies = in_sizes[6];                 // 20000
    const int in_feats   = in_sizes[0] / num_movies;    // 128
    const int nnz        = in_sizes[7];                 // 2000000
    const int num_pos    = in_sizes[10];                // 200000
    const int S          = in_sizes[11] / num_pos;      // 5

    const int nbB    = (num_users + BUCKET_W - 1) >> BUCKET_SHIFT;  // 196
    const int ntiles = (nnz + TILE_E - 1) / TILE_E;                 // 245
    const int scanNB = nbB * ntiles;                                // 48020
    const int n1b    = (scanNB + 255) / 256;                        // 188

    const int enc_blocks  = (num_movies * 64 + 255) / 256;          // 5000
    const int loss_blocks = (S == 5) ? (int)(((size_t)num_pos * 4 + 255) / 256)
                                     : (num_pos + 255) / 256;
    const int bias_blocks = 128;
    const int slot_pq   = 0;
    const int slot_loss = enc_blocks;
    const int slot_bias = enc_blocks + loss_blocks;
    const int n_slots   = slot_bias + bias_blocks;

    // workspace layout (256B-aligned). Time-shared region U:
    //   H (encode) | temp (partition) | user_emb (gather+loss)
    auto align256 = [](size_t x) { return (x + 255) & ~(size_t)255; };
    char* ws = (char*)d_ws;
    size_t off = 0;
    unsigned short* Ph = (unsigned short*)(ws + off);
    off += align256((size_t)num_movies * HIDDEN * 2);
    unsigned short* Qh = (unsigned short*)(ws + off);
    off += align256((size_t)num_movies * HIDDEN * 2);
    char* U = ws + off;
    const size_t h_bytes   = align256((size_t)num_movies * HIDDEN * 4);
    const size_t emb_bytes = align256((size_t)num_users * HIDDEN * 4);
    const size_t tmp_bytes = align256((size_t)nnz * 8);
    float* H        = (float*)U;
    float* user_emb = (float*)(U + h_bytes);
    uint2* temp     = (uint2*)U;
    off += (h_bytes + emb_bytes > tmp_bytes) ? (h_bytes + emb_bytes) : tmp_bytes;
    float* user_deg = (float*)(ws + off); off += align256((size_t)num_users * 4);
    int*   row_start= (int*)(ws + off);   off += align256((size_t)(num_users + 1) * 4);
    unsigned* tileHistB = (unsigned*)(ws + off); off += align256((size_t)scanNB * 4);
    unsigned* offsB     = (unsigned*)(ws + off); off += align256((size_t)(scanNB + 1) * 4);
    unsigned* sums_b    = (unsigned*)(ws + off); off += align256(256 * 4);
    unsigned* top_b     = (unsigned*)(ws + off); off += align256(256 * 4);
    uint2* pairs        = (uint2*)(ws + off);    off += align256((size_t)nnz * 8);
    float* partials     = (float*)(ws + off);    off += align256((size_t)n_slots * 4);

    float* out = (float*)d_out;

    // encode
    h_kernel<<<enc_blocks, 256, 0, stream>>>(features, W_enc, b_enc, H,
                                             num_movies, in_feats);
    pq_kernel<<<enc_blocks, 256, 0, stream>>>(H, W_p, W_q, Ph, Qh,
                                              partials, slot_pq, num_movies);

    // nnz bucket histogram + scan -> offsB
    tilehist_kernel<<<ntiles, 256, (size_t)nbB * 4, stream>>>(
        rows, nnz, nbB, ntiles, tileHistB);
    chunksum_kernel<<<n1b, 256, 0, stream>>>(tileHistB, scanNB, sums_b);
    scantop_kernel<<<1, 256, 0, stream>>>(sums_b, n1b, top_b, offsB, scanNB, nnz);
    exscan_kernel<<<n1b, 256, 0, stream>>>(tileHistB, scanNB, top_b, offsB);

    // two-level partition -> exact CSR pairs (+ row_start fused)
    partition_kernel<<<ntiles, 256, (size_t)nbB * 8, stream>>>(
        rows, cols, vals, nnz, nbB, ntiles, offsB, temp);
    csr_scatter_kernel<<<nbB, 256, 0, stream>>>(temp, offsB, row_start, pairs,
                                                ntiles, num_users, nbB);

    // segment sum (register gather, bf16 P)
    gather_kernel<<<(num_users * 64 + 255) / 256, 256, 0, stream>>>(
        row_start, pairs, Ph, user_emb, user_deg, num_users);

    // pair loss -> per-block partials
    if (S == 5) {
        loss4_kernel<5><<<loss_blocks, 256, 0, stream>>>(
            user_emb, user_deg, Qh, b_u, b_i, rows, cols, pos_idx,
            neg_item_idx, num_pos, partials, slot_loss);
    } else {
        loss_generic_kernel<<<loss_blocks, 256, 0, stream>>>(
            user_emb, user_deg, Qh, b_u, b_i, rows, cols, pos_idx,
            neg_item_idx, num_pos, S, partials, slot_loss);
    }

    bias_reg_kernel<<<bias_blocks, 256, 0, stream>>>(b_u, num_users,
                                                     b_i, num_movies,
                                                     partials, slot_bias);

    final_reduce_kernel<<<1, 256, 0, stream>>>(partials, n_slots, out);
}

// Round 10
// 234.852 us; speedup vs baseline: 2.0586x; 1.0688x over previous
//
#include <hip/hip_runtime.h>

#define HIDDEN 64
#define BETA 0.01f
#define GAMMA 0.01f

#define BUCKET_SHIFT 8                 // 256 users per bucket
#define BUCKET_W     (1 << BUCKET_SHIFT)
#define TILE_E       8192              // entries per partition tile

__device__ inline unsigned short f2bf(float f) {   // RNE float->bf16
    unsigned x = __float_as_uint(f);
    return (unsigned short)((x + 0x7fffu + ((x >> 16) & 1u)) >> 16);
}
__device__ inline float bf2f(unsigned short b) {
    return __uint_as_float(((unsigned)b) << 16);
}

// ---------------------------------------------------------------------------
// Encode phase A: H = features @ W_enc + b_enc
// ---------------------------------------------------------------------------
__global__ void h_kernel(const float* __restrict__ features,
                         const float* __restrict__ W_enc,
                         const float* __restrict__ b_enc,
                         float* __restrict__ H,
                         int num_movies, int in_feats) {
    const int tid = blockIdx.x * blockDim.x + threadIdx.x;
    const int j = tid & 63;
    const int m = tid >> 6;
    if (m >= num_movies) return;

    const float* frow = features + (size_t)m * in_feats;
    float a0 = 0.0f, a1 = 0.0f, a2 = 0.0f, a3 = 0.0f;
    #pragma unroll 8
    for (int f = 0; f < in_feats; f += 4) {
        const float4 fv = *(const float4*)(frow + f);
        a0 = fmaf(fv.x, W_enc[(f + 0) * HIDDEN + j], a0);
        a1 = fmaf(fv.y, W_enc[(f + 1) * HIDDEN + j], a1);
        a2 = fmaf(fv.z, W_enc[(f + 2) * HIDDEN + j], a2);
        a3 = fmaf(fv.w, W_enc[(f + 3) * HIDDEN + j], a3);
    }
    H[(size_t)m * HIDDEN + j] = (a0 + a1) + (a2 + a3) + b_enc[j];
}

// ---------------------------------------------------------------------------
// Encode phase B: P/Q in bf16; BETA regularizer partial per block ->
// partials[slot_base + blockIdx.x] (plain store, no atomics).
// ---------------------------------------------------------------------------
__global__ void pq_kernel(const float* __restrict__ H,
                          const float* __restrict__ W_p,
                          const float* __restrict__ W_q,
                          unsigned short* __restrict__ Ph,
                          unsigned short* __restrict__ Qh,
                          float* __restrict__ partials, int slot_base,
                          int num_movies) {
    const int tid = blockIdx.x * blockDim.x + threadIdx.x;
    const int j = tid & 63;
    const int m = tid >> 6;
    float reg = 0.0f;

    if (m < num_movies) {
        const float* hrow = H + (size_t)m * HIDDEN;
        float p0 = 0.0f, p1 = 0.0f, p2 = 0.0f, p3 = 0.0f;
        float q0 = 0.0f, q1 = 0.0f, q2 = 0.0f, q3 = 0.0f;
        #pragma unroll 4
        for (int f = 0; f < HIDDEN; f += 4) {
            const float4 hv = *(const float4*)(hrow + f);
            p0 = fmaf(hv.x, W_p[(f + 0) * HIDDEN + j], p0);
            p1 = fmaf(hv.y, W_p[(f + 1) * HIDDEN + j], p1);
            p2 = fmaf(hv.z, W_p[(f + 2) * HIDDEN + j], p2);
            p3 = fmaf(hv.w, W_p[(f + 3) * HIDDEN + j], p3);
            q0 = fmaf(hv.x, W_q[(f + 0) * HIDDEN + j], q0);
            q1 = fmaf(hv.y, W_q[(f + 1) * HIDDEN + j], q1);
            q2 = fmaf(hv.z, W_q[(f + 2) * HIDDEN + j], q2);
            q3 = fmaf(hv.w, W_q[(f + 3) * HIDDEN + j], q3);
        }
        const float p = (p0 + p1) + (p2 + p3);
        const float q = (q0 + q1) + (q2 + q3);
        Ph[(size_t)m * HIDDEN + j] = f2bf(p);
        Qh[(size_t)m * HIDDEN + j] = f2bf(q);
        reg = p * p + q * q;
    }

    for (int off = 32; off; off >>= 1) reg += __shfl_down(reg, off);
    __shared__ float s_part[16];
    const int wave = threadIdx.x >> 6;
    const int lane = threadIdx.x & 63;
    if (lane == 0) s_part[wave] = reg;
    __syncthreads();
    if (threadIdx.x == 0) {
        float t = 0.0f;
        const int nw = blockDim.x >> 6;
        for (int w = 0; w < nw; ++w) t += s_part[w];
        partials[slot_base + blockIdx.x] = 0.5f * BETA * t;
    }
}

// ---------------------------------------------------------------------------
// Per-tile LDS bucket histogram over nnz entries.
// ---------------------------------------------------------------------------
__global__ void tilehist_kernel(const int* __restrict__ rows, int nnz,
                                int nbuckets, int ntiles,
                                unsigned* __restrict__ tileHist) {
    extern __shared__ unsigned hist[];
    const int t = blockIdx.x;
    const int tid = threadIdx.x;
    for (int i = tid; i < nbuckets; i += blockDim.x) hist[i] = 0;
    __syncthreads();

    const int base = t * TILE_E;
    const int kmax = TILE_E / 256;
    for (int k = 0; k < kmax; ++k) {
        const int e = base + k * 256 + tid;
        if (e < nnz) atomicAdd(&hist[rows[e] >> BUCKET_SHIFT], 1u);
    }
    __syncthreads();
    for (int i = tid; i < nbuckets; i += blockDim.x)
        tileHist[(size_t)i * ntiles + t] = hist[i];
}

// ---------------------------------------------------------------------------
// Generic 2-level scan building blocks (n <= 256*256).
// ---------------------------------------------------------------------------
__global__ void chunksum_kernel(const unsigned* __restrict__ src, int n,
                                unsigned* __restrict__ sums) {
    __shared__ unsigned s[256];
    const int t = threadIdx.x;
    const int i = blockIdx.x * 256 + t;
    s[t] = (i < n) ? src[i] : 0u;
    __syncthreads();
    for (int off = 128; off; off >>= 1) {
        if (t < off) s[t] += s[t + off];
        __syncthreads();
    }
    if (t == 0) sums[blockIdx.x] = s[0];
}

__global__ void scantop_kernel(const unsigned* __restrict__ sums, int nchunks,
                               unsigned* __restrict__ chunk_off,
                               unsigned* __restrict__ offs, int n, int total) {
    __shared__ unsigned s[256];
    const int t = threadIdx.x;
    unsigned x = (t < nchunks) ? sums[t] : 0u;
    s[t] = x;
    __syncthreads();
    for (int off = 1; off < 256; off <<= 1) {
        unsigned v = (t >= off) ? s[t - off] : 0u;
        __syncthreads();
        s[t] += v;
        __syncthreads();
    }
    if (t < nchunks) chunk_off[t] = s[t] - x;   // exclusive
    if (t == 0) offs[n] = (unsigned)total;
}

__global__ void exscan_kernel(const unsigned* __restrict__ src, int n,
                              const unsigned* __restrict__ chunk_off,
                              unsigned* __restrict__ dst) {
    __shared__ unsigned s[256];
    const int t = threadIdx.x;
    const int i = blockIdx.x * 256 + t;
    unsigned x = (i < n) ? src[i] : 0u;
    s[t] = x;
    __syncthreads();
    for (int off = 1; off < 256; off <<= 1) {
        unsigned v = (t >= off) ? s[t - off] : 0u;
        __syncthreads();
        s[t] += v;
        __syncthreads();
    }
    if (i < n) dst[i] = chunk_off[blockIdx.x] + s[t] - x;
}

// ---------------------------------------------------------------------------
// Partition level 1: scatter nnz entries into bucket-major temp order.
// key = (user << 15) | col. Also writes lu8[dst] = user & 255 so the
// csr counting pass reads 2MB instead of 16MB.
// ---------------------------------------------------------------------------
__global__ void partition_kernel(const int* __restrict__ rows,
                                 const int* __restrict__ cols,
                                 const float* __restrict__ vals, int nnz,
                                 int nbuckets, int ntiles,
                                 const unsigned* __restrict__ offsB,
                                 uint2* __restrict__ temp,
                                 unsigned char* __restrict__ lu8) {
    extern __shared__ unsigned smem[];          // hist[nb] then lofs[nb]
    unsigned* hist = smem;
    unsigned* lofs = smem + nbuckets;
    const int t = blockIdx.x;
    const int tid = threadIdx.x;
    for (int i = tid; i < nbuckets; i += blockDim.x) {
        hist[i] = 0;
        lofs[i] = offsB[(size_t)i * ntiles + t];
    }
    __syncthreads();

    const int base = t * TILE_E;
    const int kmax = TILE_E / 256;
    for (int k = 0; k < kmax; ++k) {
        const int e = base + k * 256 + tid;
        if (e < nnz) {
            const int r = rows[e];
            const int b = r >> BUCKET_SHIFT;
            const unsigned lrank = atomicAdd(&hist[b], 1u);
            const unsigned dst = lofs[b] + lrank;
            const unsigned key = ((unsigned)r << 15) | (unsigned)cols[e];
            temp[dst] = make_uint2(key, __float_as_uint(vals[e]));
            lu8[dst] = (unsigned char)(r & (BUCKET_W - 1));
        }
    }
}

// ---------------------------------------------------------------------------
// Partition level 2 (fused per-user counting): bucket-major temp -> exact CSR.
// 1024 threads/WG (16 waves) for intra-bucket parallelism.
// ---------------------------------------------------------------------------
__global__ void __launch_bounds__(1024)
csr_scatter_kernel(const uint2* __restrict__ temp,
                   const unsigned char* __restrict__ lu8,
                   const unsigned* __restrict__ offsB,
                   int* __restrict__ row_start,
                   uint2* __restrict__ pairs,
                   int ntiles, int num_users, int nbB) {
    __shared__ int cnt[BUCKET_W];
    __shared__ int scan_s[BUCKET_W];
    __shared__ int cur[BUCKET_W];
    const int b = blockIdx.x;
    const int tid = threadIdx.x;
    const int ubase = b << BUCKET_SHIFT;
    const int s0 = (int)offsB[(size_t)b * ntiles];
    const int s1 = (int)offsB[(size_t)(b + 1) * ntiles];

    if (tid < BUCKET_W) cnt[tid] = 0;
    __syncthreads();
    for (int s = s0 + tid; s < s1; s += 1024)
        atomicAdd(&cnt[lu8[s]], 1);
    __syncthreads();

    // exclusive scan of cnt[0..255] (first 256 threads; all hit barriers)
    int x = 0;
    if (tid < BUCKET_W) {
        x = cnt[tid];
        scan_s[tid] = x;
    }
    __syncthreads();
    for (int off = 1; off < BUCKET_W; off <<= 1) {
        int v = 0;
        if (tid < BUCKET_W && tid >= off) v = scan_s[tid - off];
        __syncthreads();
        if (tid < BUCKET_W) scan_s[tid] += v;
        __syncthreads();
    }
    if (tid < BUCKET_W) {
        const int start = s0 + scan_s[tid] - x;
        cur[tid] = start;
        if (ubase + tid < num_users) row_start[ubase + tid] = start;
    }
    if (b == nbB - 1 && tid == 0) row_start[num_users] = s1;
    __syncthreads();

    for (int s = s0 + tid; s < s1; s += 1024) {
        const uint2 e = temp[s];
        const int lu = (int)(e.x >> 15) - ubase;
        const int dst = atomicAdd(&cur[lu], 1);
        pairs[dst] = make_uint2(e.x & 0x7fffu, e.y);
    }
}

// ---------------------------------------------------------------------------
// Segment sum, half-wave version: lanes 0-31 process entry s, lanes 32-63
// entry s+1; each lane covers 2 components via one uint (2xbf16) load.
// Per-entry instruction count ~halved vs full-wave ushort version.
// ---------------------------------------------------------------------------
__global__ void gather_kernel(const int* __restrict__ row_start,
                              const uint2* __restrict__ pairs,
                              const unsigned short* __restrict__ Ph,
                              float* __restrict__ user_emb,
                              float* __restrict__ user_deg, int nu) {
    const int lane = threadIdx.x & 63;
    const int half = lane >> 5;         // 0 or 1
    const int hl = lane & 31;           // component pair index (comps 2hl,2hl+1)
    const int u = (blockIdx.x * blockDim.x + threadIdx.x) >> 6;
    if (u >= nu) return;

    const int s0 = row_start[u];
    const int s1 = row_start[u + 1];
    float ax0 = 0.0f, ay0 = 0.0f, ax1 = 0.0f, ay1 = 0.0f, deg = 0.0f;
    int s = s0;
    for (; s + 3 < s1; s += 4) {
        const uint2 prA = pairs[s + half];
        const uint2 prB = pairs[s + 2 + half];
        const float vA = __uint_as_float(prA.y);
        const float vB = __uint_as_float(prB.y);
        const unsigned wA =
            *(const unsigned*)(Ph + (size_t)prA.x * HIDDEN + 2 * hl);
        const unsigned wB =
            *(const unsigned*)(Ph + (size_t)prB.x * HIDDEN + 2 * hl);
        ax0 = fmaf(vA, __uint_as_float(wA << 16), ax0);
        ay0 = fmaf(vA, __uint_as_float(wA & 0xffff0000u), ay0);
        ax1 = fmaf(vB, __uint_as_float(wB << 16), ax1);
        ay1 = fmaf(vB, __uint_as_float(wB & 0xffff0000u), ay1);
        deg += vA + vB;
    }
    for (; s + 1 < s1; s += 2) {
        const uint2 pr = pairs[s + half];
        const float v = __uint_as_float(pr.y);
        const unsigned w =
            *(const unsigned*)(Ph + (size_t)pr.x * HIDDEN + 2 * hl);
        ax0 = fmaf(v, __uint_as_float(w << 16), ax0);
        ay0 = fmaf(v, __uint_as_float(w & 0xffff0000u), ay0);
        deg += v;
    }
    if (s < s1 && half == 0) {          // last odd entry: half 0 only
        const uint2 pr = pairs[s];
        const float v = __uint_as_float(pr.y);
        const unsigned w =
            *(const unsigned*)(Ph + (size_t)pr.x * HIDDEN + 2 * hl);
        ax0 = fmaf(v, __uint_as_float(w << 16), ax0);
        ay0 = fmaf(v, __uint_as_float(w & 0xffff0000u), ay0);
        deg += v;
    }

    float xv = ax0 + ax1;
    float yv = ay0 + ay1;
    xv += __shfl_xor(xv, 32);
    yv += __shfl_xor(yv, 32);
    deg += __shfl_xor(deg, 32);
    if (half == 0) {
        *(float2*)(user_emb + (size_t)u * HIDDEN + 2 * hl) =
            make_float2(xv, yv);
        if (hl == 0) user_deg[u] = deg;
    }
}

// ---------------------------------------------------------------------------
// 16 bf16 x 16 fp32 dot for one lane: q points at 32B (2 x uint4).
// ---------------------------------------------------------------------------
__device__ inline float dot16(const uint4* __restrict__ q,
                              const float* __restrict__ ue) {
    float d = 0.0f;
    #pragma unroll
    for (int h = 0; h < 2; ++h) {
        const uint4 v = q[h];
        const unsigned w0 = v.x, w1 = v.y, w2 = v.z, w3 = v.w;
        d = fmaf(ue[h * 8 + 0], __uint_as_float(w0 << 16), d);
        d = fmaf(ue[h * 8 + 1], __uint_as_float(w0 & 0xffff0000u), d);
        d = fmaf(ue[h * 8 + 2], __uint_as_float(w1 << 16), d);
        d = fmaf(ue[h * 8 + 3], __uint_as_float(w1 & 0xffff0000u), d);
        d = fmaf(ue[h * 8 + 4], __uint_as_float(w2 << 16), d);
        d = fmaf(ue[h * 8 + 5], __uint_as_float(w2 & 0xffff0000u), d);
        d = fmaf(ue[h * 8 + 6], __uint_as_float(w3 << 16), d);
        d = fmaf(ue[h * 8 + 7], __uint_as_float(w3 & 0xffff0000u), d);
    }
    return d;
}

// ---------------------------------------------------------------------------
// Pair loss, 4-lane group per pair (lane = 16 components), partial store.
// ---------------------------------------------------------------------------
template <int S>
__global__ void loss4_kernel(const float* __restrict__ user_emb,
                             const float* __restrict__ user_deg,
                             const unsigned short* __restrict__ Qh,
                             const float* __restrict__ b_u,
                             const float* __restrict__ b_i,
                             const int* __restrict__ rows,
                             const int* __restrict__ cols,
                             const int* __restrict__ pos_idx,
                             const int* __restrict__ neg_item_idx,
                             int num_pos,
                             float* __restrict__ partials, int slot_base) {
    const int tid = blockIdx.x * blockDim.x + threadIdx.x;
    const int g = tid >> 2;            // pair index
    const int l = tid & 3;             // lane-in-group: components [16l,16l+16)
    float acc = 0.0f;

    if (g < num_pos) {
        const int e = pos_idx[g];
        const int u = rows[e];
        const int ii = cols[e];
        const float invdeg = 1.0f / user_deg[u];

        float ue[16];
        {
            const float4* uep =
                (const float4*)(user_emb + (size_t)u * HIDDEN + l * 16);
            #pragma unroll
            for (int k = 0; k < 4; ++k) {
                const float4 t4 = uep[k];
                ue[4 * k + 0] = t4.x * invdeg;
                ue[4 * k + 1] = t4.y * invdeg;
                ue[4 * k + 2] = t4.z * invdeg;
                ue[4 * k + 3] = t4.w * invdeg;
            }
        }

        int jarr[S];
        float part[1 + S];
        part[0] = dot16((const uint4*)(Qh + (size_t)ii * HIDDEN + l * 16), ue);
        #pragma unroll
        for (int s = 0; s < S; ++s) {
            const int j = neg_item_idx[(size_t)g * S + s];
            jarr[s] = j;
            part[1 + s] =
                dot16((const uint4*)(Qh + (size_t)j * HIDDEN + l * 16), ue);
        }

        #pragma unroll
        for (int k = 0; k < 1 + S; ++k) {
            part[k] += __shfl_xor(part[k], 1);
            part[k] += __shfl_xor(part[k], 2);
        }

        if (l == 0) {
            const float bu = b_u[u];
            const float r = bu + b_i[ii] + part[0];
            #pragma unroll
            for (int s = 0; s < S; ++s) {
                const float nr = bu + b_i[jarr[s]] + part[1 + s];
                const float diff = 1.0f - (r - nr);
                acc += 0.5f * diff * diff;
            }
        }
    }

    for (int off = 32; off; off >>= 1) acc += __shfl_down(acc, off);
    __shared__ float s_part[16];
    const int wave = threadIdx.x >> 6;
    const int lane = threadIdx.x & 63;
    if (lane == 0) s_part[wave] = acc;
    __syncthreads();
    if (threadIdx.x == 0) {
        float t = 0.0f;
        const int nw = blockDim.x >> 6;
        for (int w = 0; w < nw; ++w) t += s_part[w];
        partials[slot_base + blockIdx.x] = t;
    }
}

// generic fallback (thread per pair), only used if S != 5
__global__ void loss_generic_kernel(const float* __restrict__ user_emb,
                                    const float* __restrict__ user_deg,
                                    const unsigned short* __restrict__ Qh,
                                    const float* __restrict__ b_u,
                                    const float* __restrict__ b_i,
                                    const int* __restrict__ rows,
                                    const int* __restrict__ cols,
                                    const int* __restrict__ pos_idx,
                                    const int* __restrict__ neg_item_idx,
                                    int num_pos, int S,
                                    float* __restrict__ partials,
                                    int slot_base) {
    const int p = blockIdx.x * blockDim.x + threadIdx.x;
    float acc = 0.0f;
    if (p < num_pos) {
        const int e = pos_idx[p];
        const int u = rows[e];
        const int ii = cols[e];
        const float invdeg = 1.0f / user_deg[u];
        float ue[HIDDEN];
        #pragma unroll
        for (int kk = 0; kk < HIDDEN; ++kk)
            ue[kk] = user_emb[(size_t)u * HIDDEN + kk] * invdeg;
        const float bu = b_u[u];
        float dot = 0.0f;
        #pragma unroll
        for (int kk = 0; kk < HIDDEN; ++kk)
            dot = fmaf(ue[kk], bf2f(Qh[(size_t)ii * HIDDEN + kk]), dot);
        const float rr = bu + b_i[ii] + dot;
        for (int s = 0; s < S; ++s) {
            const int j = neg_item_idx[(size_t)p * S + s];
            float dn = 0.0f;
            #pragma unroll
            for (int kk = 0; kk < HIDDEN; ++kk)
                dn = fmaf(ue[kk], bf2f(Qh[(size_t)j * HIDDEN + kk]), dn);
            const float nr = bu + b_i[j] + dn;
            const float diff = 1.0f - (rr - nr);
            acc += 0.5f * diff * diff;
        }
    }
    for (int off = 32; off; off >>= 1) acc += __shfl_down(acc, off);
    __shared__ float s_part[16];
    const int wave = threadIdx.x >> 6;
    const int lane = threadIdx.x & 63;
    if (lane == 0) s_part[wave] = acc;
    __syncthreads();
    if (threadIdx.x == 0) {
        float t = 0.0f;
        const int nw = blockDim.x >> 6;
        for (int w = 0; w < nw; ++w) t += s_part[w];
        partials[slot_base + blockIdx.x] = t;
    }
}

// ---------------------------------------------------------------------------
// Bias regularizer partials: 0.5*GAMMA*(sum b_u^2 + sum b_i^2)
// ---------------------------------------------------------------------------
__global__ void bias_reg_kernel(const float* __restrict__ b_u, int nu,
                                const float* __restrict__ b_i, int ni,
                                float* __restrict__ partials, int slot_base) {
    const int tid = blockIdx.x * blockDim.x + threadIdx.x;
    const int stride = gridDim.x * blockDim.x;
    const int n = nu + ni;
    float acc = 0.0f;
    for (int x = tid; x < n; x += stride) {
        float v = (x < nu) ? b_u[x] : b_i[x - nu];
        acc += v * v;
    }
    for (int off = 32; off; off >>= 1) acc += __shfl_down(acc, off);
    __shared__ float s_part[16];
    const int wave = threadIdx.x >> 6;
    const int lane = threadIdx.x & 63;
    if (lane == 0) s_part[wave] = acc;
    __syncthreads();
    if (threadIdx.x == 0) {
        float t = 0.0f;
        const int nw = blockDim.x >> 6;
        for (int w = 0; w < nw; ++w) t += s_part[w];
        partials[slot_base + blockIdx.x] = 0.5f * GAMMA * t;
    }
}

// ---------------------------------------------------------------------------
// Deterministic final reduction of all partial slots -> out[0].
// ---------------------------------------------------------------------------
__global__ void final_reduce_kernel(const float* __restrict__ partials, int n,
                                    float* __restrict__ out) {
    __shared__ float s[256];
    float a = 0.0f;
    for (int i = threadIdx.x; i < n; i += 256) a += partials[i];
    s[threadIdx.x] = a;
    __syncthreads();
    for (int off = 128; off; off >>= 1) {
        if (threadIdx.x < off) s[threadIdx.x] += s[threadIdx.x + off];
        __syncthreads();
    }
    if (threadIdx.x == 0) out[0] = s[0];
}

// ---------------------------------------------------------------------------
extern "C" void kernel_launch(void* const* d_in, const int* in_sizes, int n_in,
                              void* d_out, int out_size, void* d_ws, size_t ws_size,
                              hipStream_t stream) {
    const float* features     = (const float*)d_in[0];
    const float* W_enc        = (const float*)d_in[1];
    const float* b_enc        = (const float*)d_in[2];
    const float* W_p          = (const float*)d_in[3];
    const float* W_q          = (const float*)d_in[4];
    const float* b_u          = (const float*)d_in[5];
    const float* b_i          = (const float*)d_in[6];
    const float* vals         = (const float*)d_in[7];
    const int*   rows         = (const int*)d_in[8];
    const int*   cols         = (const int*)d_in[9];
    const int*   pos_idx      = (const int*)d_in[10];
    const int*   neg_item_idx = (const int*)d_in[11];

    const int num_users  = in_sizes[5];                 // 50000
    const int num_movies = in_sizes[6];                 // 20000
    const int in_feats   = in_sizes[0] / num_movies;    // 128
    const int nnz        = in_sizes[7];                 // 2000000
    const int num_pos    = in_sizes[10];                // 200000
    const int S          = in_sizes[11] / num_pos;      // 5

    const int nbB    = (num_users + BUCKET_W - 1) >> BUCKET_SHIFT;  // 196
    const int ntiles = (nnz + TILE_E - 1) / TILE_E;                 // 245
    const int scanNB = nbB * ntiles;                                // 48020
    const int n1b    = (scanNB + 255) / 256;                        // 188

    const int enc_blocks  = (num_movies * 64 + 255) / 256;          // 5000
    const int loss_blocks = (S == 5) ? (int)(((size_t)num_pos * 4 + 255) / 256)
                                     : (num_pos + 255) / 256;
    const int bias_blocks = 128;
    const int slot_pq   = 0;
    const int slot_loss = enc_blocks;
    const int slot_bias = enc_blocks + loss_blocks;
    const int n_slots   = slot_bias + bias_blocks;

    // workspace layout (256B-aligned). Time-shared region U:
    //   H (encode) | temp (partition) | user_emb (gather+loss)
    auto align256 = [](size_t x) { return (x + 255) & ~(size_t)255; };
    char* ws = (char*)d_ws;
    size_t off = 0;
    unsigned short* Ph = (unsigned short*)(ws + off);
    off += align256((size_t)num_movies * HIDDEN * 2);
    unsigned short* Qh = (unsigned short*)(ws + off);
    off += align256((size_t)num_movies * HIDDEN * 2);
    char* U = ws + off;
    const size_t h_bytes   = align256((size_t)num_movies * HIDDEN * 4);
    const size_t emb_bytes = align256((size_t)num_users * HIDDEN * 4);
    const size_t tmp_bytes = align256((size_t)nnz * 8);
    float* H        = (float*)U;
    float* user_emb = (float*)(U + h_bytes);
    uint2* temp     = (uint2*)U;
    off += (h_bytes + emb_bytes > tmp_bytes) ? (h_bytes + emb_bytes) : tmp_bytes;
    float* user_deg = (float*)(ws + off); off += align256((size_t)num_users * 4);
    int*   row_start= (int*)(ws + off);   off += align256((size_t)(num_users + 1) * 4);
    unsigned* tileHistB = (unsigned*)(ws + off); off += align256((size_t)scanNB * 4);
    unsigned* offsB     = (unsigned*)(ws + off); off += align256((size_t)(scanNB + 1) * 4);
    unsigned* sums_b    = (unsigned*)(ws + off); off += align256(256 * 4);
    unsigned* top_b     = (unsigned*)(ws + off); off += align256(256 * 4);
    uint2* pairs        = (uint2*)(ws + off);    off += align256((size_t)nnz * 8);
    unsigned char* lu8  = (unsigned char*)(ws + off); off += align256((size_t)nnz);
    float* partials     = (float*)(ws + off);    off += align256((size_t)n_slots * 4);

    float* out = (float*)d_out;

    // encode
    h_kernel<<<enc_blocks, 256, 0, stream>>>(features, W_enc, b_enc, H,
                                             num_movies, in_feats);
    pq_kernel<<<enc_blocks, 256, 0, stream>>>(H, W_p, W_q, Ph, Qh,
                                              partials, slot_pq, num_movies);

    // nnz bucket histogram + scan -> offsB
    tilehist_kernel<<<ntiles, 256, (size_t)nbB * 4, stream>>>(
        rows, nnz, nbB, ntiles, tileHistB);
    chunksum_kernel<<<n1b, 256, 0, stream>>>(tileHistB, scanNB, sums_b);
    scantop_kernel<<<1, 256, 0, stream>>>(sums_b, n1b, top_b, offsB, scanNB, nnz);
    exscan_kernel<<<n1b, 256, 0, stream>>>(tileHistB, scanNB, top_b, offsB);

    // two-level partition -> exact CSR pairs (+ row_start fused)
    partition_kernel<<<ntiles, 256, (size_t)nbB * 8, stream>>>(
        rows, cols, vals, nnz, nbB, ntiles, offsB, temp, lu8);
    csr_scatter_kernel<<<nbB, 1024, 0, stream>>>(temp, lu8, offsB, row_start,
                                                 pairs, ntiles, num_users, nbB);

    // segment sum (half-wave register gather, bf16 P)
    gather_kernel<<<(num_users * 64 + 255) / 256, 256, 0, stream>>>(
        row_start, pairs, Ph, user_emb, user_deg, num_users);

    // pair loss -> per-block partials
    if (S == 5) {
        loss4_kernel<5><<<loss_blocks, 256, 0, stream>>>(
            user_emb, user_deg, Qh, b_u, b_i, rows, cols, pos_idx,
            neg_item_idx, num_pos, partials, slot_loss);
    } else {
        loss_generic_kernel<<<loss_blocks, 256, 0, stream>>>(
            user_emb, user_deg, Qh, b_u, b_i, rows, cols, pos_idx,
            neg_item_idx, num_pos, S, partials, slot_loss);
    }

    bias_reg_kernel<<<bias_blocks, 256, 0, stream>>>(b_u, num_users,
                                                     b_i, num_movies,
                                                     partials, slot_bias);

    final_reduce_kernel<<<1, 256, 0, stream>>>(partials, n_slots, out);
}

// Round 11
// 216.048 us; speedup vs baseline: 2.2377x; 1.0870x over previous
//
#include <hip/hip_runtime.h>

#define HIDDEN 64
#define BETA 0.01f
#define GAMMA 0.01f

#define BUCKET_SHIFT 7                 // 128 users per bucket
#define BUCKET_W     (1 << BUCKET_SHIFT)
#define TILE_E       8192              // entries per partition tile

__device__ inline unsigned short f2bf(float f) {   // RNE float->bf16
    unsigned x = __float_as_uint(f);
    return (unsigned short)((x + 0x7fffu + ((x >> 16) & 1u)) >> 16);
}
__device__ inline float bf2f(unsigned short b) {
    return __uint_as_float(((unsigned)b) << 16);
}

// ---------------------------------------------------------------------------
// Fused encode: h = feat@W_enc + b_enc (to LDS), then P/Q = h@W_p/W_q (bf16).
// 4 movies per 256-thread block; h row staged in 1KB LDS.
// BETA regularizer partial -> partials[slot_base + blockIdx.x].
// ---------------------------------------------------------------------------
__global__ void encode_kernel(const float* __restrict__ features,
                              const float* __restrict__ W_enc,
                              const float* __restrict__ b_enc,
                              const float* __restrict__ W_p,
                              const float* __restrict__ W_q,
                              unsigned short* __restrict__ Ph,
                              unsigned short* __restrict__ Qh,
                              float* __restrict__ partials, int slot_base,
                              int num_movies, int in_feats) {
    __shared__ float hs[4][HIDDEN];
    const int tid = threadIdx.x;
    const int j = tid & 63;
    const int ml = tid >> 6;
    const int m = blockIdx.x * 4 + ml;

    if (m < num_movies) {
        const float* frow = features + (size_t)m * in_feats;
        float a0 = 0.0f, a1 = 0.0f, a2 = 0.0f, a3 = 0.0f;
        #pragma unroll 8
        for (int f = 0; f < in_feats; f += 4) {
            const float4 fv = *(const float4*)(frow + f);
            a0 = fmaf(fv.x, W_enc[(f + 0) * HIDDEN + j], a0);
            a1 = fmaf(fv.y, W_enc[(f + 1) * HIDDEN + j], a1);
            a2 = fmaf(fv.z, W_enc[(f + 2) * HIDDEN + j], a2);
            a3 = fmaf(fv.w, W_enc[(f + 3) * HIDDEN + j], a3);
        }
        hs[ml][j] = (a0 + a1) + (a2 + a3) + b_enc[j];
    }
    __syncthreads();

    float reg = 0.0f;
    if (m < num_movies) {
        const float* hrow = hs[ml];
        float p0 = 0.0f, p1 = 0.0f, p2 = 0.0f, p3 = 0.0f;
        float q0 = 0.0f, q1 = 0.0f, q2 = 0.0f, q3 = 0.0f;
        #pragma unroll 4
        for (int f = 0; f < HIDDEN; f += 4) {
            const float4 hv = *(const float4*)(hrow + f);
            p0 = fmaf(hv.x, W_p[(f + 0) * HIDDEN + j], p0);
            p1 = fmaf(hv.y, W_p[(f + 1) * HIDDEN + j], p1);
            p2 = fmaf(hv.z, W_p[(f + 2) * HIDDEN + j], p2);
            p3 = fmaf(hv.w, W_p[(f + 3) * HIDDEN + j], p3);
            q0 = fmaf(hv.x, W_q[(f + 0) * HIDDEN + j], q0);
            q1 = fmaf(hv.y, W_q[(f + 1) * HIDDEN + j], q1);
            q2 = fmaf(hv.z, W_q[(f + 2) * HIDDEN + j], q2);
            q3 = fmaf(hv.w, W_q[(f + 3) * HIDDEN + j], q3);
        }
        const float p = (p0 + p1) + (p2 + p3);
        const float q = (q0 + q1) + (q2 + q3);
        Ph[(size_t)m * HIDDEN + j] = f2bf(p);
        Qh[(size_t)m * HIDDEN + j] = f2bf(q);
        reg = p * p + q * q;
    }

    for (int off = 32; off; off >>= 1) reg += __shfl_down(reg, off);
    __shared__ float s_part[4];
    const int lane = tid & 63;
    if (lane == 0) s_part[ml] = reg;
    __syncthreads();
    if (tid == 0) {
        float t = (s_part[0] + s_part[1]) + (s_part[2] + s_part[3]);
        partials[slot_base + blockIdx.x] = 0.5f * BETA * t;
    }
}

// ---------------------------------------------------------------------------
// Per-tile LDS bucket histogram over nnz entries.
// ---------------------------------------------------------------------------
__global__ void tilehist_kernel(const int* __restrict__ rows, int nnz,
                                int nbuckets, int ntiles,
                                unsigned* __restrict__ tileHist) {
    extern __shared__ unsigned hist[];
    const int t = blockIdx.x;
    const int tid = threadIdx.x;
    for (int i = tid; i < nbuckets; i += blockDim.x) hist[i] = 0;
    __syncthreads();

    const int base = t * TILE_E;
    const int kmax = TILE_E / 256;
    for (int k = 0; k < kmax; ++k) {
        const int e = base + k * 256 + tid;
        if (e < nnz) atomicAdd(&hist[rows[e] >> BUCKET_SHIFT], 1u);
    }
    __syncthreads();
    for (int i = tid; i < nbuckets; i += blockDim.x)
        tileHist[(size_t)i * ntiles + t] = hist[i];
}

// ---------------------------------------------------------------------------
// 2-level scan blocks. chunksum/exscan: 256-thread chunks (n1 blocks).
// scantop: single 512-thread block (n1 <= 512).
// ---------------------------------------------------------------------------
__global__ void chunksum_kernel(const unsigned* __restrict__ src, int n,
                                unsigned* __restrict__ sums) {
    __shared__ unsigned s[256];
    const int t = threadIdx.x;
    const int i = blockIdx.x * 256 + t;
    s[t] = (i < n) ? src[i] : 0u;
    __syncthreads();
    for (int off = 128; off; off >>= 1) {
        if (t < off) s[t] += s[t + off];
        __syncthreads();
    }
    if (t == 0) sums[blockIdx.x] = s[0];
}

__global__ void __launch_bounds__(512)
scantop_kernel(const unsigned* __restrict__ sums, int nchunks,
               unsigned* __restrict__ chunk_off,
               unsigned* __restrict__ offs, int n, int total) {
    __shared__ unsigned s[512];
    const int t = threadIdx.x;
    unsigned x = (t < nchunks) ? sums[t] : 0u;
    s[t] = x;
    __syncthreads();
    for (int off = 1; off < 512; off <<= 1) {
        unsigned v = (t >= off) ? s[t - off] : 0u;
        __syncthreads();
        s[t] += v;
        __syncthreads();
    }
    if (t < nchunks) chunk_off[t] = s[t] - x;   // exclusive
    if (t == 0) offs[n] = (unsigned)total;
}

__global__ void exscan_kernel(const unsigned* __restrict__ src, int n,
                              const unsigned* __restrict__ chunk_off,
                              unsigned* __restrict__ dst) {
    __shared__ unsigned s[256];
    const int t = threadIdx.x;
    const int i = blockIdx.x * 256 + t;
    unsigned x = (i < n) ? src[i] : 0u;
    s[t] = x;
    __syncthreads();
    for (int off = 1; off < 256; off <<= 1) {
        unsigned v = (t >= off) ? s[t - off] : 0u;
        __syncthreads();
        s[t] += v;
        __syncthreads();
    }
    if (i < n) dst[i] = chunk_off[blockIdx.x] + s[t] - x;
}

// ---------------------------------------------------------------------------
// Partition level 1: scatter nnz entries into bucket-major temp order.
// key = (user << 15) | col; lu8[dst] = user & 127 for the cheap count pass.
// ---------------------------------------------------------------------------
__global__ void partition_kernel(const int* __restrict__ rows,
                                 const int* __restrict__ cols,
                                 const float* __restrict__ vals, int nnz,
                                 int nbuckets, int ntiles,
                                 const unsigned* __restrict__ offsB,
                                 uint2* __restrict__ temp,
                                 unsigned char* __restrict__ lu8) {
    extern __shared__ unsigned smem[];          // hist[nb] then lofs[nb]
    unsigned* hist = smem;
    unsigned* lofs = smem + nbuckets;
    const int t = blockIdx.x;
    const int tid = threadIdx.x;
    for (int i = tid; i < nbuckets; i += blockDim.x) {
        hist[i] = 0;
        lofs[i] = offsB[(size_t)i * ntiles + t];
    }
    __syncthreads();

    const int base = t * TILE_E;
    const int kmax = TILE_E / 256;
    for (int k = 0; k < kmax; ++k) {
        const int e = base + k * 256 + tid;
        if (e < nnz) {
            const int r = rows[e];
            const int b = r >> BUCKET_SHIFT;
            const unsigned lrank = atomicAdd(&hist[b], 1u);
            const unsigned dst = lofs[b] + lrank;
            const unsigned key = ((unsigned)r << 15) | (unsigned)cols[e];
            temp[dst] = make_uint2(key, __float_as_uint(vals[e]));
            lu8[dst] = (unsigned char)(r & (BUCKET_W - 1));
        }
    }
}

// ---------------------------------------------------------------------------
// Partition level 2 (fused per-user counting): bucket-major temp -> exact CSR.
// 391 WGs x 512 threads (fills all CUs).
// ---------------------------------------------------------------------------
__global__ void __launch_bounds__(512)
csr_scatter_kernel(const uint2* __restrict__ temp,
                   const unsigned char* __restrict__ lu8,
                   const unsigned* __restrict__ offsB,
                   int* __restrict__ row_start,
                   uint2* __restrict__ pairs,
                   int ntiles, int num_users, int nbB) {
    __shared__ int cnt[BUCKET_W];
    __shared__ int scan_s[BUCKET_W];
    __shared__ int cur[BUCKET_W];
    const int b = blockIdx.x;
    const int tid = threadIdx.x;
    const int ubase = b << BUCKET_SHIFT;
    const int s0 = (int)offsB[(size_t)b * ntiles];
    const int s1 = (int)offsB[(size_t)(b + 1) * ntiles];

    if (tid < BUCKET_W) cnt[tid] = 0;
    __syncthreads();
    for (int s = s0 + tid; s < s1; s += 512)
        atomicAdd(&cnt[lu8[s]], 1);
    __syncthreads();

    int x = 0;
    if (tid < BUCKET_W) {
        x = cnt[tid];
        scan_s[tid] = x;
    }
    __syncthreads();
    for (int off = 1; off < BUCKET_W; off <<= 1) {
        int v = 0;
        if (tid < BUCKET_W && tid >= off) v = scan_s[tid - off];
        __syncthreads();
        if (tid < BUCKET_W) scan_s[tid] += v;
        __syncthreads();
    }
    if (tid < BUCKET_W) {
        const int start = s0 + scan_s[tid] - x;
        cur[tid] = start;
        if (ubase + tid < num_users) row_start[ubase + tid] = start;
    }
    if (b == nbB - 1 && tid == 0) row_start[num_users] = s1;
    __syncthreads();

    for (int s = s0 + tid; s < s1; s += 512) {
        const uint2 e = temp[s];
        const int lu = (int)(e.x >> 15) - ubase;
        const int dst = atomicAdd(&cur[lu], 1);
        pairs[dst] = make_uint2(e.x & 0x7fffu, e.y);
    }
}

// ---------------------------------------------------------------------------
// Segment sum, half-wave, unroll 8: lanes 0-31 do even entries, 32-63 odd;
// 4 independent pair->P load chains per half in flight.
// ---------------------------------------------------------------------------
__global__ void gather_kernel(const int* __restrict__ row_start,
                              const uint2* __restrict__ pairs,
                              const unsigned short* __restrict__ Ph,
                              float* __restrict__ user_emb,
                              float* __restrict__ user_deg, int nu) {
    const int lane = threadIdx.x & 63;
    const int half = lane >> 5;         // 0 or 1
    const int hl = lane & 31;           // comps 2hl, 2hl+1
    const int u = (blockIdx.x * blockDim.x + threadIdx.x) >> 6;
    if (u >= nu) return;

    const int s0 = row_start[u];
    const int s1 = row_start[u + 1];
    float ax0 = 0.0f, ay0 = 0.0f, ax1 = 0.0f, ay1 = 0.0f;
    float ax2 = 0.0f, ay2 = 0.0f, ax3 = 0.0f, ay3 = 0.0f;
    float deg = 0.0f;
    int s = s0;
    for (; s + 7 < s1; s += 8) {
        const uint2 p0 = pairs[s + half];
        const uint2 p1 = pairs[s + 2 + half];
        const uint2 p2 = pairs[s + 4 + half];
        const uint2 p3 = pairs[s + 6 + half];
        const unsigned w0 = *(const unsigned*)(Ph + (size_t)p0.x * HIDDEN + 2 * hl);
        const unsigned w1 = *(const unsigned*)(Ph + (size_t)p1.x * HIDDEN + 2 * hl);
        const unsigned w2 = *(const unsigned*)(Ph + (size_t)p2.x * HIDDEN + 2 * hl);
        const unsigned w3 = *(const unsigned*)(Ph + (size_t)p3.x * HIDDEN + 2 * hl);
        const float v0 = __uint_as_float(p0.y);
        const float v1 = __uint_as_float(p1.y);
        const float v2 = __uint_as_float(p2.y);
        const float v3 = __uint_as_float(p3.y);
        ax0 = fmaf(v0, __uint_as_float(w0 << 16), ax0);
        ay0 = fmaf(v0, __uint_as_float(w0 & 0xffff0000u), ay0);
        ax1 = fmaf(v1, __uint_as_float(w1 << 16), ax1);
        ay1 = fmaf(v1, __uint_as_float(w1 & 0xffff0000u), ay1);
        ax2 = fmaf(v2, __uint_as_float(w2 << 16), ax2);
        ay2 = fmaf(v2, __uint_as_float(w2 & 0xffff0000u), ay2);
        ax3 = fmaf(v3, __uint_as_float(w3 << 16), ax3);
        ay3 = fmaf(v3, __uint_as_float(w3 & 0xffff0000u), ay3);
        deg += (v0 + v1) + (v2 + v3);
    }
    for (; s + 1 < s1; s += 2) {
        const uint2 pr = pairs[s + half];
        const float v = __uint_as_float(pr.y);
        const unsigned w = *(const unsigned*)(Ph + (size_t)pr.x * HIDDEN + 2 * hl);
        ax0 = fmaf(v, __uint_as_float(w << 16), ax0);
        ay0 = fmaf(v, __uint_as_float(w & 0xffff0000u), ay0);
        deg += v;
    }
    if (s < s1 && half == 0) {          // last odd entry
        const uint2 pr = pairs[s];
        const float v = __uint_as_float(pr.y);
        const unsigned w = *(const unsigned*)(Ph + (size_t)pr.x * HIDDEN + 2 * hl);
        ax0 = fmaf(v, __uint_as_float(w << 16), ax0);
        ay0 = fmaf(v, __uint_as_float(w & 0xffff0000u), ay0);
        deg += v;
    }

    float xv = (ax0 + ax1) + (ax2 + ax3);
    float yv = (ay0 + ay1) + (ay2 + ay3);
    xv += __shfl_xor(xv, 32);
    yv += __shfl_xor(yv, 32);
    deg += __shfl_xor(deg, 32);
    if (half == 0) {
        *(float2*)(user_emb + (size_t)u * HIDDEN + 2 * hl) =
            make_float2(xv, yv);
        if (hl == 0) user_deg[u] = deg;
    }
}

// ---------------------------------------------------------------------------
// 16 bf16 x 16 fp32 dot for one lane: q points at 32B (2 x uint4).
// ---------------------------------------------------------------------------
__device__ inline float dot16(const uint4* __restrict__ q,
                              const float* __restrict__ ue) {
    float d = 0.0f;
    #pragma unroll
    for (int h = 0; h < 2; ++h) {
        const uint4 v = q[h];
        const unsigned w0 = v.x, w1 = v.y, w2 = v.z, w3 = v.w;
        d = fmaf(ue[h * 8 + 0], __uint_as_float(w0 << 16), d);
        d = fmaf(ue[h * 8 + 1], __uint_as_float(w0 & 0xffff0000u), d);
        d = fmaf(ue[h * 8 + 2], __uint_as_float(w1 << 16), d);
        d = fmaf(ue[h * 8 + 3], __uint_as_float(w1 & 0xffff0000u), d);
        d = fmaf(ue[h * 8 + 4], __uint_as_float(w2 << 16), d);
        d = fmaf(ue[h * 8 + 5], __uint_as_float(w2 & 0xffff0000u), d);
        d = fmaf(ue[h * 8 + 6], __uint_as_float(w3 << 16), d);
        d = fmaf(ue[h * 8 + 7], __uint_as_float(w3 & 0xffff0000u), d);
    }
    return d;
}

// ---------------------------------------------------------------------------
// Pair loss, 4-lane group per pair (lane = 16 components), partial store.
// ---------------------------------------------------------------------------
template <int S>
__global__ void loss4_kernel(const float* __restrict__ user_emb,
                             const float* __restrict__ user_deg,
                             const unsigned short* __restrict__ Qh,
                             const float* __restrict__ b_u,
                             const float* __restrict__ b_i,
                             const int* __restrict__ rows,
                             const int* __restrict__ cols,
                             const int* __restrict__ pos_idx,
                             const int* __restrict__ neg_item_idx,
                             int num_pos,
                             float* __restrict__ partials, int slot_base) {
    const int tid = blockIdx.x * blockDim.x + threadIdx.x;
    const int g = tid >> 2;            // pair index
    const int l = tid & 3;             // lane-in-group: components [16l,16l+16)
    float acc = 0.0f;

    if (g < num_pos) {
        const int e = pos_idx[g];
        const int u = rows[e];
        const int ii = cols[e];
        const float invdeg = 1.0f / user_deg[u];

        float ue[16];
        {
            const float4* uep =
                (const float4*)(user_emb + (size_t)u * HIDDEN + l * 16);
            #pragma unroll
            for (int k = 0; k < 4; ++k) {
                const float4 t4 = uep[k];
                ue[4 * k + 0] = t4.x * invdeg;
                ue[4 * k + 1] = t4.y * invdeg;
                ue[4 * k + 2] = t4.z * invdeg;
                ue[4 * k + 3] = t4.w * invdeg;
            }
        }

        int jarr[S];
        float part[1 + S];
        part[0] = dot16((const uint4*)(Qh + (size_t)ii * HIDDEN + l * 16), ue);
        #pragma unroll
        for (int s = 0; s < S; ++s) {
            const int j = neg_item_idx[(size_t)g * S + s];
            jarr[s] = j;
            part[1 + s] =
                dot16((const uint4*)(Qh + (size_t)j * HIDDEN + l * 16), ue);
        }

        #pragma unroll
        for (int k = 0; k < 1 + S; ++k) {
            part[k] += __shfl_xor(part[k], 1);
            part[k] += __shfl_xor(part[k], 2);
        }

        if (l == 0) {
            const float bu = b_u[u];
            const float r = bu + b_i[ii] + part[0];
            #pragma unroll
            for (int s = 0; s < S; ++s) {
                const float nr = bu + b_i[jarr[s]] + part[1 + s];
                const float diff = 1.0f - (r - nr);
                acc += 0.5f * diff * diff;
            }
        }
    }

    for (int off = 32; off; off >>= 1) acc += __shfl_down(acc, off);
    __shared__ float s_part[16];
    const int wave = threadIdx.x >> 6;
    const int lane = threadIdx.x & 63;
    if (lane == 0) s_part[wave] = acc;
    __syncthreads();
    if (threadIdx.x == 0) {
        float t = 0.0f;
        const int nw = blockDim.x >> 6;
        for (int w = 0; w < nw; ++w) t += s_part[w];
        partials[slot_base + blockIdx.x] = t;
    }
}

// generic fallback (thread per pair), only used if S != 5
__global__ void loss_generic_kernel(const float* __restrict__ user_emb,
                                    const float* __restrict__ user_deg,
                                    const unsigned short* __restrict__ Qh,
                                    const float* __restrict__ b_u,
                                    const float* __restrict__ b_i,
                                    const int* __restrict__ rows,
                                    const int* __restrict__ cols,
                                    const int* __restrict__ pos_idx,
                                    const int* __restrict__ neg_item_idx,
                                    int num_pos, int S,
                                    float* __restrict__ partials,
                                    int slot_base) {
    const int p = blockIdx.x * blockDim.x + threadIdx.x;
    float acc = 0.0f;
    if (p < num_pos) {
        const int e = pos_idx[p];
        const int u = rows[e];
        const int ii = cols[e];
        const float invdeg = 1.0f / user_deg[u];
        float ue[HIDDEN];
        #pragma unroll
        for (int kk = 0; kk < HIDDEN; ++kk)
            ue[kk] = user_emb[(size_t)u * HIDDEN + kk] * invdeg;
        const float bu = b_u[u];
        float dot = 0.0f;
        #pragma unroll
        for (int kk = 0; kk < HIDDEN; ++kk)
            dot = fmaf(ue[kk], bf2f(Qh[(size_t)ii * HIDDEN + kk]), dot);
        const float rr = bu + b_i[ii] + dot;
        for (int s = 0; s < S; ++s) {
            const int j = neg_item_idx[(size_t)p * S + s];
            float dn = 0.0f;
            #pragma unroll
            for (int kk = 0; kk < HIDDEN; ++kk)
                dn = fmaf(ue[kk], bf2f(Qh[(size_t)j * HIDDEN + kk]), dn);
            const float nr = bu + b_i[j] + dn;
            const float diff = 1.0f - (rr - nr);
            acc += 0.5f * diff * diff;
        }
    }
    for (int off = 32; off; off >>= 1) acc += __shfl_down(acc, off);
    __shared__ float s_part[16];
    const int wave = threadIdx.x >> 6;
    const int lane = threadIdx.x & 63;
    if (lane == 0) s_part[wave] = acc;
    __syncthreads();
    if (threadIdx.x == 0) {
        float t = 0.0f;
        const int nw = blockDim.x >> 6;
        for (int w = 0; w < nw; ++w) t += s_part[w];
        partials[slot_base + blockIdx.x] = t;
    }
}

// ---------------------------------------------------------------------------
// Bias regularizer partials: 0.5*GAMMA*(sum b_u^2 + sum b_i^2)
// ---------------------------------------------------------------------------
__global__ void bias_reg_kernel(const float* __restrict__ b_u, int nu,
                                const float* __restrict__ b_i, int ni,
                                float* __restrict__ partials, int slot_base) {
    const int tid = blockIdx.x * blockDim.x + threadIdx.x;
    const int stride = gridDim.x * blockDim.x;
    const int n = nu + ni;
    float acc = 0.0f;
    for (int x = tid; x < n; x += stride) {
        float v = (x < nu) ? b_u[x] : b_i[x - nu];
        acc += v * v;
    }
    for (int off = 32; off; off >>= 1) acc += __shfl_down(acc, off);
    __shared__ float s_part[16];
    const int wave = threadIdx.x >> 6;
    const int lane = threadIdx.x & 63;
    if (lane == 0) s_part[wave] = acc;
    __syncthreads();
    if (threadIdx.x == 0) {
        float t = 0.0f;
        const int nw = blockDim.x >> 6;
        for (int w = 0; w < nw; ++w) t += s_part[w];
        partials[slot_base + blockIdx.x] = 0.5f * GAMMA * t;
    }
}

// ---------------------------------------------------------------------------
// Deterministic final reduction of all partial slots -> out[0].
// ---------------------------------------------------------------------------
__global__ void final_reduce_kernel(const float* __restrict__ partials, int n,
                                    float* __restrict__ out) {
    __shared__ float s[256];
    float a = 0.0f;
    for (int i = threadIdx.x; i < n; i += 256) a += partials[i];
    s[threadIdx.x] = a;
    __syncthreads();
    for (int off = 128; off; off >>= 1) {
        if (threadIdx.x < off) s[threadIdx.x] += s[threadIdx.x + off];
        __syncthreads();
    }
    if (threadIdx.x == 0) out[0] = s[0];
}

// ---------------------------------------------------------------------------
extern "C" void kernel_launch(void* const* d_in, const int* in_sizes, int n_in,
                              void* d_out, int out_size, void* d_ws, size_t ws_size,
                              hipStream_t stream) {
    const float* features     = (const float*)d_in[0];
    const float* W_enc        = (const float*)d_in[1];
    const float* b_enc        = (const float*)d_in[2];
    const float* W_p          = (const float*)d_in[3];
    const float* W_q          = (const float*)d_in[4];
    const float* b_u          = (const float*)d_in[5];
    const float* b_i          = (const float*)d_in[6];
    const float* vals         = (const float*)d_in[7];
    const int*   rows         = (const int*)d_in[8];
    const int*   cols         = (const int*)d_in[9];
    const int*   pos_idx      = (const int*)d_in[10];
    const int*   neg_item_idx = (const int*)d_in[11];

    const int num_users  = in_sizes[5];                 // 50000
    const int num_movies = in_sizes[6];                 // 20000
    const int in_feats   = in_sizes[0] / num_movies;    // 128
    const int nnz        = in_sizes[7];                 // 2000000
    const int num_pos    = in_sizes[10];                // 200000
    const int S          = in_sizes[11] / num_pos;      // 5

    const int nbB    = (num_users + BUCKET_W - 1) >> BUCKET_SHIFT;  // 391
    const int ntiles = (nnz + TILE_E - 1) / TILE_E;                 // 245
    const int scanNB = nbB * ntiles;                                // 95795
    const int n1b    = (scanNB + 255) / 256;                        // 375 <= 512

    const int enc_blocks  = (num_movies + 3) / 4;                   // 5000
    const int loss_blocks = (S == 5) ? (int)(((size_t)num_pos * 4 + 255) / 256)
                                     : (num_pos + 255) / 256;
    const int bias_blocks = 128;
    const int slot_pq   = 0;
    const int slot_loss = enc_blocks;
    const int slot_bias = enc_blocks + loss_blocks;
    const int n_slots   = slot_bias + bias_blocks;

    // workspace layout (256B-aligned). Time-shared region U:
    //   temp (partition) | user_emb (gather+loss) — sequential, never live together
    auto align256 = [](size_t x) { return (x + 255) & ~(size_t)255; };
    char* ws = (char*)d_ws;
    size_t off = 0;
    unsigned short* Ph = (unsigned short*)(ws + off);
    off += align256((size_t)num_movies * HIDDEN * 2);
    unsigned short* Qh = (unsigned short*)(ws + off);
    off += align256((size_t)num_movies * HIDDEN * 2);
    char* U = ws + off;
    const size_t emb_bytes = align256((size_t)num_users * HIDDEN * 4);
    const size_t tmp_bytes = align256((size_t)nnz * 8);
    uint2* temp     = (uint2*)U;
    float* user_emb = (float*)U;
    off += (emb_bytes > tmp_bytes) ? emb_bytes : tmp_bytes;
    float* user_deg = (float*)(ws + off); off += align256((size_t)num_users * 4);
    int*   row_start= (int*)(ws + off);   off += align256((size_t)(num_users + 1) * 4);
    unsigned* tileHistB = (unsigned*)(ws + off); off += align256((size_t)scanNB * 4);
    unsigned* offsB     = (unsigned*)(ws + off); off += align256((size_t)(scanNB + 1) * 4);
    unsigned* sums_b    = (unsigned*)(ws + off); off += align256(512 * 4);
    unsigned* top_b     = (unsigned*)(ws + off); off += align256(512 * 4);
    uint2* pairs        = (uint2*)(ws + off);    off += align256((size_t)nnz * 8);
    unsigned char* lu8  = (unsigned char*)(ws + off); off += align256((size_t)nnz);
    float* partials     = (float*)(ws + off);    off += align256((size_t)n_slots * 4);

    float* out = (float*)d_out;

    // fused encode -> Ph/Qh (bf16) + regularizer partials
    encode_kernel<<<enc_blocks, 256, 0, stream>>>(
        features, W_enc, b_enc, W_p, W_q, Ph, Qh, partials, slot_pq,
        num_movies, in_feats);

    // nnz bucket histogram + scan -> offsB
    tilehist_kernel<<<ntiles, 256, (size_t)nbB * 4, stream>>>(
        rows, nnz, nbB, ntiles, tileHistB);
    chunksum_kernel<<<n1b, 256, 0, stream>>>(tileHistB, scanNB, sums_b);
    scantop_kernel<<<1, 512, 0, stream>>>(sums_b, n1b, top_b, offsB, scanNB, nnz);
    exscan_kernel<<<n1b, 256, 0, stream>>>(tileHistB, scanNB, top_b, offsB);

    // two-level partition -> exact CSR pairs (+ row_start fused)
    partition_kernel<<<ntiles, 256, (size_t)nbB * 8, stream>>>(
        rows, cols, vals, nnz, nbB, ntiles, offsB, temp, lu8);
    csr_scatter_kernel<<<nbB, 512, 0, stream>>>(temp, lu8, offsB, row_start,
                                                pairs, ntiles, num_users, nbB);

    // segment sum (half-wave unroll-8 register gather, bf16 P)
    gather_kernel<<<(num_users * 64 + 255) / 256, 256, 0, stream>>>(
        row_start, pairs, Ph, user_emb, user_deg, num_users);

    // pair loss -> per-block partials
    if (S == 5) {
        loss4_kernel<5><<<loss_blocks, 256, 0, stream>>>(
            user_emb, user_deg, Qh, b_u, b_i, rows, cols, pos_idx,
            neg_item_idx, num_pos, partials, slot_loss);
    } else {
        loss_generic_kernel<<<loss_blocks, 256, 0, stream>>>(
            user_emb, user_deg, Qh, b_u, b_i, rows, cols, pos_idx,
            neg_item_idx, num_pos, S, partials, slot_loss);
    }

    bias_reg_kernel<<<bias_blocks, 256, 0, stream>>>(b_u, num_users,
                                                     b_i, num_movies,
                                                     partials, slot_bias);

    final_reduce_kernel<<<1, 256, 0, stream>>>(partials, n_slots, out);
}

// Round 12
// 190.987 us; speedup vs baseline: 2.5314x; 1.1312x over previous
//
#include <hip/hip_runtime.h>

#define HIDDEN 64
#define BETA 0.01f
#define GAMMA 0.01f

#define BUCKET_SHIFT 7                 // 128 users per bucket
#define BUCKET_W     (1 << BUCKET_SHIFT)
#define TILE_E       8192              // entries per partition tile

__device__ inline unsigned short f2bf(float f) {   // RNE float->bf16
    unsigned x = __float_as_uint(f);
    return (unsigned short)((x + 0x7fffu + ((x >> 16) & 1u)) >> 16);
}
__device__ inline float bf2f(unsigned short b) {
    return __uint_as_float(((unsigned)b) << 16);
}

// ---------------------------------------------------------------------------
// Fused encode, register-blocked: each wave owns 4 movies; W columns loaded
// once and reused x4. Phase 1: h rows -> LDS. Phase 2: P/Q (bf16).
// BETA regularizer partial -> partials[slot_base + blockIdx.x].
// ---------------------------------------------------------------------------
__global__ void __launch_bounds__(256)
encode_kernel(const float* __restrict__ features,
              const float* __restrict__ W_enc,
              const float* __restrict__ b_enc,
              const float* __restrict__ W_p,
              const float* __restrict__ W_q,
              unsigned short* __restrict__ Ph,
              unsigned short* __restrict__ Qh,
              float* __restrict__ partials, int slot_base,
              int num_movies, int in_feats) {
    __shared__ float hs[16][HIDDEN];           // 4 KB
    const int tid = threadIdx.x;
    const int j = tid & 63;
    const int wv = tid >> 6;                   // wave 0..3
    const int m0 = blockIdx.x * 16 + wv * 4;   // this wave's 4 movies

    // clamped row pointers (stores guarded below)
    const int c0 = min(m0 + 0, num_movies - 1);
    const int c1 = min(m0 + 1, num_movies - 1);
    const int c2 = min(m0 + 2, num_movies - 1);
    const int c3 = min(m0 + 3, num_movies - 1);
    const float* fr0 = features + (size_t)c0 * in_feats;
    const float* fr1 = features + (size_t)c1 * in_feats;
    const float* fr2 = features + (size_t)c2 * in_feats;
    const float* fr3 = features + (size_t)c3 * in_feats;

    float h0 = 0.0f, h1 = 0.0f, h2 = 0.0f, h3 = 0.0f;
    #pragma unroll 4
    for (int f = 0; f < in_feats; f += 4) {
        const float w_a = W_enc[(f + 0) * HIDDEN + j];
        const float w_b = W_enc[(f + 1) * HIDDEN + j];
        const float w_c = W_enc[(f + 2) * HIDDEN + j];
        const float w_d = W_enc[(f + 3) * HIDDEN + j];
        const float4 a0 = *(const float4*)(fr0 + f);
        const float4 a1 = *(const float4*)(fr1 + f);
        const float4 a2 = *(const float4*)(fr2 + f);
        const float4 a3 = *(const float4*)(fr3 + f);
        h0 = fmaf(a0.x, w_a, h0); h0 = fmaf(a0.y, w_b, h0);
        h0 = fmaf(a0.z, w_c, h0); h0 = fmaf(a0.w, w_d, h0);
        h1 = fmaf(a1.x, w_a, h1); h1 = fmaf(a1.y, w_b, h1);
        h1 = fmaf(a1.z, w_c, h1); h1 = fmaf(a1.w, w_d, h1);
        h2 = fmaf(a2.x, w_a, h2); h2 = fmaf(a2.y, w_b, h2);
        h2 = fmaf(a2.z, w_c, h2); h2 = fmaf(a2.w, w_d, h2);
        h3 = fmaf(a3.x, w_a, h3); h3 = fmaf(a3.y, w_b, h3);
        h3 = fmaf(a3.z, w_c, h3); h3 = fmaf(a3.w, w_d, h3);
    }
    const float be = b_enc[j];
    hs[wv * 4 + 0][j] = h0 + be;
    hs[wv * 4 + 1][j] = h1 + be;
    hs[wv * 4 + 2][j] = h2 + be;
    hs[wv * 4 + 3][j] = h3 + be;
    __syncthreads();

    float p0 = 0.0f, p1 = 0.0f, p2 = 0.0f, p3 = 0.0f;
    float q0 = 0.0f, q1 = 0.0f, q2 = 0.0f, q3 = 0.0f;
    #pragma unroll 4
    for (int f = 0; f < HIDDEN; f += 4) {
        const float wp0 = W_p[(f + 0) * HIDDEN + j];
        const float wp1 = W_p[(f + 1) * HIDDEN + j];
        const float wp2 = W_p[(f + 2) * HIDDEN + j];
        const float wp3 = W_p[(f + 3) * HIDDEN + j];
        const float wq0 = W_q[(f + 0) * HIDDEN + j];
        const float wq1 = W_q[(f + 1) * HIDDEN + j];
        const float wq2 = W_q[(f + 2) * HIDDEN + j];
        const float wq3 = W_q[(f + 3) * HIDDEN + j];
        const float4 v0 = *(const float4*)(&hs[wv * 4 + 0][f]);
        const float4 v1 = *(const float4*)(&hs[wv * 4 + 1][f]);
        const float4 v2 = *(const float4*)(&hs[wv * 4 + 2][f]);
        const float4 v3 = *(const float4*)(&hs[wv * 4 + 3][f]);
        p0 = fmaf(v0.x, wp0, p0); p0 = fmaf(v0.y, wp1, p0);
        p0 = fmaf(v0.z, wp2, p0); p0 = fmaf(v0.w, wp3, p0);
        q0 = fmaf(v0.x, wq0, q0); q0 = fmaf(v0.y, wq1, q0);
        q0 = fmaf(v0.z, wq2, q0); q0 = fmaf(v0.w, wq3, q0);
        p1 = fmaf(v1.x, wp0, p1); p1 = fmaf(v1.y, wp1, p1);
        p1 = fmaf(v1.z, wp2, p1); p1 = fmaf(v1.w, wp3, p1);
        q1 = fmaf(v1.x, wq0, q1); q1 = fmaf(v1.y, wq1, q1);
        q1 = fmaf(v1.z, wq2, q1); q1 = fmaf(v1.w, wq3, q1);
        p2 = fmaf(v2.x, wp0, p2); p2 = fmaf(v2.y, wp1, p2);
        p2 = fmaf(v2.z, wp2, p2); p2 = fmaf(v2.w, wp3, p2);
        q2 = fmaf(v2.x, wq0, q2); q2 = fmaf(v2.y, wq1, q2);
        q2 = fmaf(v2.z, wq2, q2); q2 = fmaf(v2.w, wq3, q2);
        p3 = fmaf(v3.x, wp0, p3); p3 = fmaf(v3.y, wp1, p3);
        p3 = fmaf(v3.z, wp2, p3); p3 = fmaf(v3.w, wp3, p3);
        q3 = fmaf(v3.x, wq0, q3); q3 = fmaf(v3.y, wq1, q3);
        q3 = fmaf(v3.z, wq2, q3); q3 = fmaf(v3.w, wq3, q3);
    }

    float reg = 0.0f;
    if (m0 + 0 < num_movies) {
        Ph[(size_t)(m0 + 0) * HIDDEN + j] = f2bf(p0);
        Qh[(size_t)(m0 + 0) * HIDDEN + j] = f2bf(q0);
        reg += p0 * p0 + q0 * q0;
    }
    if (m0 + 1 < num_movies) {
        Ph[(size_t)(m0 + 1) * HIDDEN + j] = f2bf(p1);
        Qh[(size_t)(m0 + 1) * HIDDEN + j] = f2bf(q1);
        reg += p1 * p1 + q1 * q1;
    }
    if (m0 + 2 < num_movies) {
        Ph[(size_t)(m0 + 2) * HIDDEN + j] = f2bf(p2);
        Qh[(size_t)(m0 + 2) * HIDDEN + j] = f2bf(q2);
        reg += p2 * p2 + q2 * q2;
    }
    if (m0 + 3 < num_movies) {
        Ph[(size_t)(m0 + 3) * HIDDEN + j] = f2bf(p3);
        Qh[(size_t)(m0 + 3) * HIDDEN + j] = f2bf(q3);
        reg += p3 * p3 + q3 * q3;
    }

    for (int off = 32; off; off >>= 1) reg += __shfl_down(reg, off);
    __shared__ float s_part[4];
    if (j == 0) s_part[wv] = reg;
    __syncthreads();
    if (tid == 0) {
        float t = (s_part[0] + s_part[1]) + (s_part[2] + s_part[3]);
        partials[slot_base + blockIdx.x] = 0.5f * BETA * t;
    }
}

// ---------------------------------------------------------------------------
// Per-tile LDS bucket histogram over nnz entries.
// ---------------------------------------------------------------------------
__global__ void tilehist_kernel(const int* __restrict__ rows, int nnz,
                                int nbuckets, int ntiles,
                                unsigned* __restrict__ tileHist) {
    extern __shared__ unsigned hist[];
    const int t = blockIdx.x;
    const int tid = threadIdx.x;
    for (int i = tid; i < nbuckets; i += blockDim.x) hist[i] = 0;
    __syncthreads();

    const int base = t * TILE_E;
    const int kmax = TILE_E / 256;
    for (int k = 0; k < kmax; ++k) {
        const int e = base + k * 256 + tid;
        if (e < nnz) atomicAdd(&hist[rows[e] >> BUCKET_SHIFT], 1u);
    }
    __syncthreads();
    for (int i = tid; i < nbuckets; i += blockDim.x)
        tileHist[(size_t)i * ntiles + t] = hist[i];
}

// ---------------------------------------------------------------------------
// 2-level scan blocks. chunksum/exscan: 256-thread chunks (n1 blocks).
// scantop: single 512-thread block (n1 <= 512).
// ---------------------------------------------------------------------------
__global__ void chunksum_kernel(const unsigned* __restrict__ src, int n,
                                unsigned* __restrict__ sums) {
    __shared__ unsigned s[256];
    const int t = threadIdx.x;
    const int i = blockIdx.x * 256 + t;
    s[t] = (i < n) ? src[i] : 0u;
    __syncthreads();
    for (int off = 128; off; off >>= 1) {
        if (t < off) s[t] += s[t + off];
        __syncthreads();
    }
    if (t == 0) sums[blockIdx.x] = s[0];
}

__global__ void __launch_bounds__(512)
scantop_kernel(const unsigned* __restrict__ sums, int nchunks,
               unsigned* __restrict__ chunk_off,
               unsigned* __restrict__ offs, int n, int total) {
    __shared__ unsigned s[512];
    const int t = threadIdx.x;
    unsigned x = (t < nchunks) ? sums[t] : 0u;
    s[t] = x;
    __syncthreads();
    for (int off = 1; off < 512; off <<= 1) {
        unsigned v = (t >= off) ? s[t - off] : 0u;
        __syncthreads();
        s[t] += v;
        __syncthreads();
    }
    if (t < nchunks) chunk_off[t] = s[t] - x;   // exclusive
    if (t == 0) offs[n] = (unsigned)total;
}

__global__ void exscan_kernel(const unsigned* __restrict__ src, int n,
                              const unsigned* __restrict__ chunk_off,
                              unsigned* __restrict__ dst) {
    __shared__ unsigned s[256];
    const int t = threadIdx.x;
    const int i = blockIdx.x * 256 + t;
    unsigned x = (i < n) ? src[i] : 0u;
    s[t] = x;
    __syncthreads();
    for (int off = 1; off < 256; off <<= 1) {
        unsigned v = (t >= off) ? s[t - off] : 0u;
        __syncthreads();
        s[t] += v;
        __syncthreads();
    }
    if (i < n) dst[i] = chunk_off[blockIdx.x] + s[t] - x;
}

// ---------------------------------------------------------------------------
// Partition level 1: scatter nnz entries into bucket-major temp order.
// key = (user << 15) | col; lu8[dst] = user & 127 for the cheap count pass.
// ---------------------------------------------------------------------------
__global__ void partition_kernel(const int* __restrict__ rows,
                                 const int* __restrict__ cols,
                                 const float* __restrict__ vals, int nnz,
                                 int nbuckets, int ntiles,
                                 const unsigned* __restrict__ offsB,
                                 uint2* __restrict__ temp,
                                 unsigned char* __restrict__ lu8) {
    extern __shared__ unsigned smem[];          // hist[nb] then lofs[nb]
    unsigned* hist = smem;
    unsigned* lofs = smem + nbuckets;
    const int t = blockIdx.x;
    const int tid = threadIdx.x;
    for (int i = tid; i < nbuckets; i += blockDim.x) {
        hist[i] = 0;
        lofs[i] = offsB[(size_t)i * ntiles + t];
    }
    __syncthreads();

    const int base = t * TILE_E;
    const int kmax = TILE_E / 256;
    for (int k = 0; k < kmax; ++k) {
        const int e = base + k * 256 + tid;
        if (e < nnz) {
            const int r = rows[e];
            const int b = r >> BUCKET_SHIFT;
            const unsigned lrank = atomicAdd(&hist[b], 1u);
            const unsigned dst = lofs[b] + lrank;
            const unsigned key = ((unsigned)r << 15) | (unsigned)cols[e];
            temp[dst] = make_uint2(key, __float_as_uint(vals[e]));
            lu8[dst] = (unsigned char)(r & (BUCKET_W - 1));
        }
    }
}

// ---------------------------------------------------------------------------
// Partition level 2 (fused per-user counting): bucket-major temp -> exact CSR.
// ---------------------------------------------------------------------------
__global__ void __launch_bounds__(512)
csr_scatter_kernel(const uint2* __restrict__ temp,
                   const unsigned char* __restrict__ lu8,
                   const unsigned* __restrict__ offsB,
                   int* __restrict__ row_start,
                   uint2* __restrict__ pairs,
                   int ntiles, int num_users, int nbB) {
    __shared__ int cnt[BUCKET_W];
    __shared__ int scan_s[BUCKET_W];
    __shared__ int cur[BUCKET_W];
    const int b = blockIdx.x;
    const int tid = threadIdx.x;
    const int ubase = b << BUCKET_SHIFT;
    const int s0 = (int)offsB[(size_t)b * ntiles];
    const int s1 = (int)offsB[(size_t)(b + 1) * ntiles];

    if (tid < BUCKET_W) cnt[tid] = 0;
    __syncthreads();
    for (int s = s0 + tid; s < s1; s += 512)
        atomicAdd(&cnt[lu8[s]], 1);
    __syncthreads();

    int x = 0;
    if (tid < BUCKET_W) {
        x = cnt[tid];
        scan_s[tid] = x;
    }
    __syncthreads();
    for (int off = 1; off < BUCKET_W; off <<= 1) {
        int v = 0;
        if (tid < BUCKET_W && tid >= off) v = scan_s[tid - off];
        __syncthreads();
        if (tid < BUCKET_W) scan_s[tid] += v;
        __syncthreads();
    }
    if (tid < BUCKET_W) {
        const int start = s0 + scan_s[tid] - x;
        cur[tid] = start;
        if (ubase + tid < num_users) row_start[ubase + tid] = start;
    }
    if (b == nbB - 1 && tid == 0) row_start[num_users] = s1;
    __syncthreads();

    for (int s = s0 + tid; s < s1; s += 512) {
        const uint2 e = temp[s];
        const int lu = (int)(e.x >> 15) - ubase;
        const int dst = atomicAdd(&cur[lu], 1);
        pairs[dst] = make_uint2(e.x & 0x7fffu, e.y);
    }
}

// ---------------------------------------------------------------------------
// Segment sum, half-wave, unroll 8: lanes 0-31 do even entries, 32-63 odd;
// 4 independent pair->P load chains per half in flight.
// ---------------------------------------------------------------------------
__global__ void gather_kernel(const int* __restrict__ row_start,
                              const uint2* __restrict__ pairs,
                              const unsigned short* __restrict__ Ph,
                              float* __restrict__ user_emb,
                              float* __restrict__ user_deg, int nu) {
    const int lane = threadIdx.x & 63;
    const int half = lane >> 5;         // 0 or 1
    const int hl = lane & 31;           // comps 2hl, 2hl+1
    const int u = (blockIdx.x * blockDim.x + threadIdx.x) >> 6;
    if (u >= nu) return;

    const int s0 = row_start[u];
    const int s1 = row_start[u + 1];
    float ax0 = 0.0f, ay0 = 0.0f, ax1 = 0.0f, ay1 = 0.0f;
    float ax2 = 0.0f, ay2 = 0.0f, ax3 = 0.0f, ay3 = 0.0f;
    float deg = 0.0f;
    int s = s0;
    for (; s + 7 < s1; s += 8) {
        const uint2 p0 = pairs[s + half];
        const uint2 p1 = pairs[s + 2 + half];
        const uint2 p2 = pairs[s + 4 + half];
        const uint2 p3 = pairs[s + 6 + half];
        const unsigned w0 = *(const unsigned*)(Ph + (size_t)p0.x * HIDDEN + 2 * hl);
        const unsigned w1 = *(const unsigned*)(Ph + (size_t)p1.x * HIDDEN + 2 * hl);
        const unsigned w2 = *(const unsigned*)(Ph + (size_t)p2.x * HIDDEN + 2 * hl);
        const unsigned w3 = *(const unsigned*)(Ph + (size_t)p3.x * HIDDEN + 2 * hl);
        const float v0 = __uint_as_float(p0.y);
        const float v1 = __uint_as_float(p1.y);
        const float v2 = __uint_as_float(p2.y);
        const float v3 = __uint_as_float(p3.y);
        ax0 = fmaf(v0, __uint_as_float(w0 << 16), ax0);
        ay0 = fmaf(v0, __uint_as_float(w0 & 0xffff0000u), ay0);
        ax1 = fmaf(v1, __uint_as_float(w1 << 16), ax1);
        ay1 = fmaf(v1, __uint_as_float(w1 & 0xffff0000u), ay1);
        ax2 = fmaf(v2, __uint_as_float(w2 << 16), ax2);
        ay2 = fmaf(v2, __uint_as_float(w2 & 0xffff0000u), ay2);
        ax3 = fmaf(v3, __uint_as_float(w3 << 16), ax3);
        ay3 = fmaf(v3, __uint_as_float(w3 & 0xffff0000u), ay3);
        deg += (v0 + v1) + (v2 + v3);
    }
    for (; s + 1 < s1; s += 2) {
        const uint2 pr = pairs[s + half];
        const float v = __uint_as_float(pr.y);
        const unsigned w = *(const unsigned*)(Ph + (size_t)pr.x * HIDDEN + 2 * hl);
        ax0 = fmaf(v, __uint_as_float(w << 16), ax0);
        ay0 = fmaf(v, __uint_as_float(w & 0xffff0000u), ay0);
        deg += v;
    }
    if (s < s1 && half == 0) {          // last odd entry
        const uint2 pr = pairs[s];
        const float v = __uint_as_float(pr.y);
        const unsigned w = *(const unsigned*)(Ph + (size_t)pr.x * HIDDEN + 2 * hl);
        ax0 = fmaf(v, __uint_as_float(w << 16), ax0);
        ay0 = fmaf(v, __uint_as_float(w & 0xffff0000u), ay0);
        deg += v;
    }

    float xv = (ax0 + ax1) + (ax2 + ax3);
    float yv = (ay0 + ay1) + (ay2 + ay3);
    xv += __shfl_xor(xv, 32);
    yv += __shfl_xor(yv, 32);
    deg += __shfl_xor(deg, 32);
    if (half == 0) {
        *(float2*)(user_emb + (size_t)u * HIDDEN + 2 * hl) =
            make_float2(xv, yv);
        if (hl == 0) user_deg[u] = deg;
    }
}

// ---------------------------------------------------------------------------
// 16 bf16 x 16 fp32 dot for one lane: q points at 32B (2 x uint4).
// ---------------------------------------------------------------------------
__device__ inline float dot16(const uint4* __restrict__ q,
                              const float* __restrict__ ue) {
    float d = 0.0f;
    #pragma unroll
    for (int h = 0; h < 2; ++h) {
        const uint4 v = q[h];
        const unsigned w0 = v.x, w1 = v.y, w2 = v.z, w3 = v.w;
        d = fmaf(ue[h * 8 + 0], __uint_as_float(w0 << 16), d);
        d = fmaf(ue[h * 8 + 1], __uint_as_float(w0 & 0xffff0000u), d);
        d = fmaf(ue[h * 8 + 2], __uint_as_float(w1 << 16), d);
        d = fmaf(ue[h * 8 + 3], __uint_as_float(w1 & 0xffff0000u), d);
        d = fmaf(ue[h * 8 + 4], __uint_as_float(w2 << 16), d);
        d = fmaf(ue[h * 8 + 5], __uint_as_float(w2 & 0xffff0000u), d);
        d = fmaf(ue[h * 8 + 6], __uint_as_float(w3 << 16), d);
        d = fmaf(ue[h * 8 + 7], __uint_as_float(w3 & 0xffff0000u), d);
    }
    return d;
}

// ---------------------------------------------------------------------------
// Pair loss, 4-lane group per pair (lane = 16 components), partial store.
// ---------------------------------------------------------------------------
template <int S>
__global__ void loss4_kernel(const float* __restrict__ user_emb,
                             const float* __restrict__ user_deg,
                             const unsigned short* __restrict__ Qh,
                             const float* __restrict__ b_u,
                             const float* __restrict__ b_i,
                             const int* __restrict__ rows,
                             const int* __restrict__ cols,
                             const int* __restrict__ pos_idx,
                             const int* __restrict__ neg_item_idx,
                             int num_pos,
                             float* __restrict__ partials, int slot_base) {
    const int tid = blockIdx.x * blockDim.x + threadIdx.x;
    const int g = tid >> 2;            // pair index
    const int l = tid & 3;             // lane-in-group: components [16l,16l+16)
    float acc = 0.0f;

    if (g < num_pos) {
        const int e = pos_idx[g];
        const int u = rows[e];
        const int ii = cols[e];
        const float invdeg = 1.0f / user_deg[u];

        float ue[16];
        {
            const float4* uep =
                (const float4*)(user_emb + (size_t)u * HIDDEN + l * 16);
            #pragma unroll
            for (int k = 0; k < 4; ++k) {
                const float4 t4 = uep[k];
                ue[4 * k + 0] = t4.x * invdeg;
                ue[4 * k + 1] = t4.y * invdeg;
                ue[4 * k + 2] = t4.z * invdeg;
                ue[4 * k + 3] = t4.w * invdeg;
            }
        }

        int jarr[S];
        float part[1 + S];
        part[0] = dot16((const uint4*)(Qh + (size_t)ii * HIDDEN + l * 16), ue);
        #pragma unroll
        for (int s = 0; s < S; ++s) {
            const int j = neg_item_idx[(size_t)g * S + s];
            jarr[s] = j;
            part[1 + s] =
                dot16((const uint4*)(Qh + (size_t)j * HIDDEN + l * 16), ue);
        }

        #pragma unroll
        for (int k = 0; k < 1 + S; ++k) {
            part[k] += __shfl_xor(part[k], 1);
            part[k] += __shfl_xor(part[k], 2);
        }

        if (l == 0) {
            const float bu = b_u[u];
            const float r = bu + b_i[ii] + part[0];
            #pragma unroll
            for (int s = 0; s < S; ++s) {
                const float nr = bu + b_i[jarr[s]] + part[1 + s];
                const float diff = 1.0f - (r - nr);
                acc += 0.5f * diff * diff;
            }
        }
    }

    for (int off = 32; off; off >>= 1) acc += __shfl_down(acc, off);
    __shared__ float s_part[16];
    const int wave = threadIdx.x >> 6;
    const int lane = threadIdx.x & 63;
    if (lane == 0) s_part[wave] = acc;
    __syncthreads();
    if (threadIdx.x == 0) {
        float t = 0.0f;
        const int nw = blockDim.x >> 6;
        for (int w = 0; w < nw; ++w) t += s_part[w];
        partials[slot_base + blockIdx.x] = t;
    }
}

// generic fallback (thread per pair), only used if S != 5
__global__ void loss_generic_kernel(const float* __restrict__ user_emb,
                                    const float* __restrict__ user_deg,
                                    const unsigned short* __restrict__ Qh,
                                    const float* __restrict__ b_u,
                                    const float* __restrict__ b_i,
                                    const int* __restrict__ rows,
                                    const int* __restrict__ cols,
                                    const int* __restrict__ pos_idx,
                                    const int* __restrict__ neg_item_idx,
                                    int num_pos, int S,
                                    float* __restrict__ partials,
                                    int slot_base) {
    const int p = blockIdx.x * blockDim.x + threadIdx.x;
    float acc = 0.0f;
    if (p < num_pos) {
        const int e = pos_idx[p];
        const int u = rows[e];
        const int ii = cols[e];
        const float invdeg = 1.0f / user_deg[u];
        float ue[HIDDEN];
        #pragma unroll
        for (int kk = 0; kk < HIDDEN; ++kk)
            ue[kk] = user_emb[(size_t)u * HIDDEN + kk] * invdeg;
        const float bu = b_u[u];
        float dot = 0.0f;
        #pragma unroll
        for (int kk = 0; kk < HIDDEN; ++kk)
            dot = fmaf(ue[kk], bf2f(Qh[(size_t)ii * HIDDEN + kk]), dot);
        const float rr = bu + b_i[ii] + dot;
        for (int s = 0; s < S; ++s) {
            const int j = neg_item_idx[(size_t)p * S + s];
            float dn = 0.0f;
            #pragma unroll
            for (int kk = 0; kk < HIDDEN; ++kk)
                dn = fmaf(ue[kk], bf2f(Qh[(size_t)j * HIDDEN + kk]), dn);
            const float nr = bu + b_i[j] + dn;
            const float diff = 1.0f - (rr - nr);
            acc += 0.5f * diff * diff;
        }
    }
    for (int off = 32; off; off >>= 1) acc += __shfl_down(acc, off);
    __shared__ float s_part[16];
    const int wave = threadIdx.x >> 6;
    const int lane = threadIdx.x & 63;
    if (lane == 0) s_part[wave] = acc;
    __syncthreads();
    if (threadIdx.x == 0) {
        float t = 0.0f;
        const int nw = blockDim.x >> 6;
        for (int w = 0; w < nw; ++w) t += s_part[w];
        partials[slot_base + blockIdx.x] = t;
    }
}

// ---------------------------------------------------------------------------
// Bias regularizer partials: 0.5*GAMMA*(sum b_u^2 + sum b_i^2)
// ---------------------------------------------------------------------------
__global__ void bias_reg_kernel(const float* __restrict__ b_u, int nu,
                                const float* __restrict__ b_i, int ni,
                                float* __restrict__ partials, int slot_base) {
    const int tid = blockIdx.x * blockDim.x + threadIdx.x;
    const int stride = gridDim.x * blockDim.x;
    const int n = nu + ni;
    float acc = 0.0f;
    for (int x = tid; x < n; x += stride) {
        float v = (x < nu) ? b_u[x] : b_i[x - nu];
        acc += v * v;
    }
    for (int off = 32; off; off >>= 1) acc += __shfl_down(acc, off);
    __shared__ float s_part[16];
    const int wave = threadIdx.x >> 6;
    const int lane = threadIdx.x & 63;
    if (lane == 0) s_part[wave] = acc;
    __syncthreads();
    if (threadIdx.x == 0) {
        float t = 0.0f;
        const int nw = blockDim.x >> 6;
        for (int w = 0; w < nw; ++w) t += s_part[w];
        partials[slot_base + blockIdx.x] = 0.5f * GAMMA * t;
    }
}

// ---------------------------------------------------------------------------
// Deterministic final reduction of all partial slots -> out[0].
// ---------------------------------------------------------------------------
__global__ void final_reduce_kernel(const float* __restrict__ partials, int n,
                                    float* __restrict__ out) {
    __shared__ float s[256];
    float a = 0.0f;
    for (int i = threadIdx.x; i < n; i += 256) a += partials[i];
    s[threadIdx.x] = a;
    __syncthreads();
    for (int off = 128; off; off >>= 1) {
        if (threadIdx.x < off) s[threadIdx.x] += s[threadIdx.x + off];
        __syncthreads();
    }
    if (threadIdx.x == 0) out[0] = s[0];
}

// ---------------------------------------------------------------------------
extern "C" void kernel_launch(void* const* d_in, const int* in_sizes, int n_in,
                              void* d_out, int out_size, void* d_ws, size_t ws_size,
                              hipStream_t stream) {
    const float* features     = (const float*)d_in[0];
    const float* W_enc        = (const float*)d_in[1];
    const float* b_enc        = (const float*)d_in[2];
    const float* W_p          = (const float*)d_in[3];
    const float* W_q          = (const float*)d_in[4];
    const float* b_u          = (const float*)d_in[5];
    const float* b_i          = (const float*)d_in[6];
    const float* vals         = (const float*)d_in[7];
    const int*   rows         = (const int*)d_in[8];
    const int*   cols         = (const int*)d_in[9];
    const int*   pos_idx      = (const int*)d_in[10];
    const int*   neg_item_idx = (const int*)d_in[11];

    const int num_users  = in_sizes[5];                 // 50000
    const int num_movies = in_sizes[6];                 // 20000
    const int in_feats   = in_sizes[0] / num_movies;    // 128
    const int nnz        = in_sizes[7];                 // 2000000
    const int num_pos    = in_sizes[10];                // 200000
    const int S          = in_sizes[11] / num_pos;      // 5

    const int nbB    = (num_users + BUCKET_W - 1) >> BUCKET_SHIFT;  // 391
    const int ntiles = (nnz + TILE_E - 1) / TILE_E;                 // 245
    const int scanNB = nbB * ntiles;                                // 95795
    const int n1b    = (scanNB + 255) / 256;                        // 375 <= 512

    const int enc_blocks  = (num_movies + 15) / 16;                 // 1250
    const int loss_blocks = (S == 5) ? (int)(((size_t)num_pos * 4 + 255) / 256)
                                     : (num_pos + 255) / 256;
    const int bias_blocks = 128;
    const int slot_pq   = 0;
    const int slot_loss = enc_blocks;
    const int slot_bias = enc_blocks + loss_blocks;
    const int n_slots   = slot_bias + bias_blocks;

    // workspace layout (256B-aligned). Time-shared region U:
    //   temp (partition) | user_emb (gather+loss) — sequential, never live together
    auto align256 = [](size_t x) { return (x + 255) & ~(size_t)255; };
    char* ws = (char*)d_ws;
    size_t off = 0;
    unsigned short* Ph = (unsigned short*)(ws + off);
    off += align256((size_t)num_movies * HIDDEN * 2);
    unsigned short* Qh = (unsigned short*)(ws + off);
    off += align256((size_t)num_movies * HIDDEN * 2);
    char* U = ws + off;
    const size_t emb_bytes = align256((size_t)num_users * HIDDEN * 4);
    const size_t tmp_bytes = align256((size_t)nnz * 8);
    uint2* temp     = (uint2*)U;
    float* user_emb = (float*)U;
    off += (emb_bytes > tmp_bytes) ? emb_bytes : tmp_bytes;
    float* user_deg = (float*)(ws + off); off += align256((size_t)num_users * 4);
    int*   row_start= (int*)(ws + off);   off += align256((size_t)(num_users + 1) * 4);
    unsigned* tileHistB = (unsigned*)(ws + off); off += align256((size_t)scanNB * 4);
    unsigned* offsB     = (unsigned*)(ws + off); off += align256((size_t)(scanNB + 1) * 4);
    unsigned* sums_b    = (unsigned*)(ws + off); off += align256(512 * 4);
    unsigned* top_b     = (unsigned*)(ws + off); off += align256(512 * 4);
    uint2* pairs        = (uint2*)(ws + off);    off += align256((size_t)nnz * 8);
    unsigned char* lu8  = (unsigned char*)(ws + off); off += align256((size_t)nnz);
    float* partials     = (float*)(ws + off);    off += align256((size_t)n_slots * 4);

    float* out = (float*)d_out;

    // fused register-blocked encode -> Ph/Qh (bf16) + regularizer partials
    encode_kernel<<<enc_blocks, 256, 0, stream>>>(
        features, W_enc, b_enc, W_p, W_q, Ph, Qh, partials, slot_pq,
        num_movies, in_feats);

    // nnz bucket histogram + scan -> offsB
    tilehist_kernel<<<ntiles, 256, (size_t)nbB * 4, stream>>>(
        rows, nnz, nbB, ntiles, tileHistB);
    chunksum_kernel<<<n1b, 256, 0, stream>>>(tileHistB, scanNB, sums_b);
    scantop_kernel<<<1, 512, 0, stream>>>(sums_b, n1b, top_b, offsB, scanNB, nnz);
    exscan_kernel<<<n1b, 256, 0, stream>>>(tileHistB, scanNB, top_b, offsB);

    // two-level partition -> exact CSR pairs (+ row_start fused)
    partition_kernel<<<ntiles, 256, (size_t)nbB * 8, stream>>>(
        rows, cols, vals, nnz, nbB, ntiles, offsB, temp, lu8);
    csr_scatter_kernel<<<nbB, 512, 0, stream>>>(temp, lu8, offsB, row_start,
                                                pairs, ntiles, num_users, nbB);

    // segment sum (half-wave unroll-8 register gather, bf16 P)
    gather_kernel<<<(num_users * 64 + 255) / 256, 256, 0, stream>>>(
        row_start, pairs, Ph, user_emb, user_deg, num_users);

    // pair loss -> per-block partials
    if (S == 5) {
        loss4_kernel<5><<<loss_blocks, 256, 0, stream>>>(
            user_emb, user_deg, Qh, b_u, b_i, rows, cols, pos_idx,
            neg_item_idx, num_pos, partials, slot_loss);
    } else {
        loss_generic_kernel<<<loss_blocks, 256, 0, stream>>>(
            user_emb, user_deg, Qh, b_u, b_i, rows, cols, pos_idx,
            neg_item_idx, num_pos, S, partials, slot_loss);
    }

    bias_reg_kernel<<<bias_blocks, 256, 0, stream>>>(b_u, num_users,
                                                     b_i, num_movies,
                                                     partials, slot_bias);

    final_reduce_kernel<<<1, 256, 0, stream>>>(partials, n_slots, out);
}

// Round 13
// 187.699 us; speedup vs baseline: 2.5757x; 1.0175x over previous
//
#include <hip/hip_runtime.h>

#define HIDDEN 64
#define BETA 0.01f
#define GAMMA 0.01f

#define BUCKET_SHIFT 8                 // 256 users per bucket
#define BUCKET_W     (1 << BUCKET_SHIFT)
#define TILE_E       8192              // entries per partition tile

__device__ inline unsigned short f2bf(float f) {   // RNE float->bf16
    unsigned x = __float_as_uint(f);
    return (unsigned short)((x + 0x7fffu + ((x >> 16) & 1u)) >> 16);
}
__device__ inline float bf2f(unsigned short b) {
    return __uint_as_float(((unsigned)b) << 16);
}

// ---------------------------------------------------------------------------
// Fused encode, register-blocked: each wave owns 4 movies; W columns loaded
// once and reused x4. Phase 1: h rows -> LDS. Phase 2: P/Q (bf16).
// ---------------------------------------------------------------------------
__global__ void __launch_bounds__(256)
encode_kernel(const float* __restrict__ features,
              const float* __restrict__ W_enc,
              const float* __restrict__ b_enc,
              const float* __restrict__ W_p,
              const float* __restrict__ W_q,
              unsigned short* __restrict__ Ph,
              unsigned short* __restrict__ Qh,
              float* __restrict__ partials, int slot_base,
              int num_movies, int in_feats) {
    __shared__ float hs[16][HIDDEN];           // 4 KB
    const int tid = threadIdx.x;
    const int j = tid & 63;
    const int wv = tid >> 6;                   // wave 0..3
    const int m0 = blockIdx.x * 16 + wv * 4;   // this wave's 4 movies

    const int c0 = min(m0 + 0, num_movies - 1);
    const int c1 = min(m0 + 1, num_movies - 1);
    const int c2 = min(m0 + 2, num_movies - 1);
    const int c3 = min(m0 + 3, num_movies - 1);
    const float* fr0 = features + (size_t)c0 * in_feats;
    const float* fr1 = features + (size_t)c1 * in_feats;
    const float* fr2 = features + (size_t)c2 * in_feats;
    const float* fr3 = features + (size_t)c3 * in_feats;

    float h0 = 0.0f, h1 = 0.0f, h2 = 0.0f, h3 = 0.0f;
    #pragma unroll 4
    for (int f = 0; f < in_feats; f += 4) {
        const float w_a = W_enc[(f + 0) * HIDDEN + j];
        const float w_b = W_enc[(f + 1) * HIDDEN + j];
        const float w_c = W_enc[(f + 2) * HIDDEN + j];
        const float w_d = W_enc[(f + 3) * HIDDEN + j];
        const float4 a0 = *(const float4*)(fr0 + f);
        const float4 a1 = *(const float4*)(fr1 + f);
        const float4 a2 = *(const float4*)(fr2 + f);
        const float4 a3 = *(const float4*)(fr3 + f);
        h0 = fmaf(a0.x, w_a, h0); h0 = fmaf(a0.y, w_b, h0);
        h0 = fmaf(a0.z, w_c, h0); h0 = fmaf(a0.w, w_d, h0);
        h1 = fmaf(a1.x, w_a, h1); h1 = fmaf(a1.y, w_b, h1);
        h1 = fmaf(a1.z, w_c, h1); h1 = fmaf(a1.w, w_d, h1);
        h2 = fmaf(a2.x, w_a, h2); h2 = fmaf(a2.y, w_b, h2);
        h2 = fmaf(a2.z, w_c, h2); h2 = fmaf(a2.w, w_d, h2);
        h3 = fmaf(a3.x, w_a, h3); h3 = fmaf(a3.y, w_b, h3);
        h3 = fmaf(a3.z, w_c, h3); h3 = fmaf(a3.w, w_d, h3);
    }
    const float be = b_enc[j];
    hs[wv * 4 + 0][j] = h0 + be;
    hs[wv * 4 + 1][j] = h1 + be;
    hs[wv * 4 + 2][j] = h2 + be;
    hs[wv * 4 + 3][j] = h3 + be;
    __syncthreads();

    float p0 = 0.0f, p1 = 0.0f, p2 = 0.0f, p3 = 0.0f;
    float q0 = 0.0f, q1 = 0.0f, q2 = 0.0f, q3 = 0.0f;
    #pragma unroll 4
    for (int f = 0; f < HIDDEN; f += 4) {
        const float wp0 = W_p[(f + 0) * HIDDEN + j];
        const float wp1 = W_p[(f + 1) * HIDDEN + j];
        const float wp2 = W_p[(f + 2) * HIDDEN + j];
        const float wp3 = W_p[(f + 3) * HIDDEN + j];
        const float wq0 = W_q[(f + 0) * HIDDEN + j];
        const float wq1 = W_q[(f + 1) * HIDDEN + j];
        const float wq2 = W_q[(f + 2) * HIDDEN + j];
        const float wq3 = W_q[(f + 3) * HIDDEN + j];
        const float4 v0 = *(const float4*)(&hs[wv * 4 + 0][f]);
        const float4 v1 = *(const float4*)(&hs[wv * 4 + 1][f]);
        const float4 v2 = *(const float4*)(&hs[wv * 4 + 2][f]);
        const float4 v3 = *(const float4*)(&hs[wv * 4 + 3][f]);
        p0 = fmaf(v0.x, wp0, p0); p0 = fmaf(v0.y, wp1, p0);
        p0 = fmaf(v0.z, wp2, p0); p0 = fmaf(v0.w, wp3, p0);
        q0 = fmaf(v0.x, wq0, q0); q0 = fmaf(v0.y, wq1, q0);
        q0 = fmaf(v0.z, wq2, q0); q0 = fmaf(v0.w, wq3, q0);
        p1 = fmaf(v1.x, wp0, p1); p1 = fmaf(v1.y, wp1, p1);
        p1 = fmaf(v1.z, wp2, p1); p1 = fmaf(v1.w, wp3, p1);
        q1 = fmaf(v1.x, wq0, q1); q1 = fmaf(v1.y, wq1, q1);
        q1 = fmaf(v1.z, wq2, q1); q1 = fmaf(v1.w, wq3, q1);
        p2 = fmaf(v2.x, wp0, p2); p2 = fmaf(v2.y, wp1, p2);
        p2 = fmaf(v2.z, wp2, p2); p2 = fmaf(v2.w, wp3, p2);
        q2 = fmaf(v2.x, wq0, q2); q2 = fmaf(v2.y, wq1, q2);
        q2 = fmaf(v2.z, wq2, q2); q2 = fmaf(v2.w, wq3, q2);
        p3 = fmaf(v3.x, wp0, p3); p3 = fmaf(v3.y, wp1, p3);
        p3 = fmaf(v3.z, wp2, p3); p3 = fmaf(v3.w, wp3, p3);
        q3 = fmaf(v3.x, wq0, q3); q3 = fmaf(v3.y, wq1, q3);
        q3 = fmaf(v3.z, wq2, q3); q3 = fmaf(v3.w, wq3, q3);
    }

    float reg = 0.0f;
    if (m0 + 0 < num_movies) {
        Ph[(size_t)(m0 + 0) * HIDDEN + j] = f2bf(p0);
        Qh[(size_t)(m0 + 0) * HIDDEN + j] = f2bf(q0);
        reg += p0 * p0 + q0 * q0;
    }
    if (m0 + 1 < num_movies) {
        Ph[(size_t)(m0 + 1) * HIDDEN + j] = f2bf(p1);
        Qh[(size_t)(m0 + 1) * HIDDEN + j] = f2bf(q1);
        reg += p1 * p1 + q1 * q1;
    }
    if (m0 + 2 < num_movies) {
        Ph[(size_t)(m0 + 2) * HIDDEN + j] = f2bf(p2);
        Qh[(size_t)(m0 + 2) * HIDDEN + j] = f2bf(q2);
        reg += p2 * p2 + q2 * q2;
    }
    if (m0 + 3 < num_movies) {
        Ph[(size_t)(m0 + 3) * HIDDEN + j] = f2bf(p3);
        Qh[(size_t)(m0 + 3) * HIDDEN + j] = f2bf(q3);
        reg += p3 * p3 + q3 * q3;
    }

    for (int off = 32; off; off >>= 1) reg += __shfl_down(reg, off);
    __shared__ float s_part[4];
    if (j == 0) s_part[wv] = reg;
    __syncthreads();
    if (tid == 0) {
        float t = (s_part[0] + s_part[1]) + (s_part[2] + s_part[3]);
        partials[slot_base + blockIdx.x] = 0.5f * BETA * t;
    }
}

// ---------------------------------------------------------------------------
// Per-tile LDS bucket histogram over nnz entries (nontemporal row reads).
// ---------------------------------------------------------------------------
__global__ void tilehist_kernel(const int* __restrict__ rows, int nnz,
                                int nbuckets, int ntiles,
                                unsigned* __restrict__ tileHist) {
    extern __shared__ unsigned hist[];
    const int t = blockIdx.x;
    const int tid = threadIdx.x;
    for (int i = tid; i < nbuckets; i += blockDim.x) hist[i] = 0;
    __syncthreads();

    const int base = t * TILE_E;
    const int kmax = TILE_E / 256;
    for (int k = 0; k < kmax; ++k) {
        const int e = base + k * 256 + tid;
        if (e < nnz) {
            const int r = __builtin_nontemporal_load(rows + e);
            atomicAdd(&hist[r >> BUCKET_SHIFT], 1u);
        }
    }
    __syncthreads();
    for (int i = tid; i < nbuckets; i += blockDim.x)
        tileHist[(size_t)i * ntiles + t] = hist[i];
}

// ---------------------------------------------------------------------------
// 2-level scan blocks.
// ---------------------------------------------------------------------------
__global__ void chunksum_kernel(const unsigned* __restrict__ src, int n,
                                unsigned* __restrict__ sums) {
    __shared__ unsigned s[256];
    const int t = threadIdx.x;
    const int i = blockIdx.x * 256 + t;
    s[t] = (i < n) ? src[i] : 0u;
    __syncthreads();
    for (int off = 128; off; off >>= 1) {
        if (t < off) s[t] += s[t + off];
        __syncthreads();
    }
    if (t == 0) sums[blockIdx.x] = s[0];
}

__global__ void __launch_bounds__(512)
scantop_kernel(const unsigned* __restrict__ sums, int nchunks,
               unsigned* __restrict__ chunk_off,
               unsigned* __restrict__ offs, int n, int total) {
    __shared__ unsigned s[512];
    const int t = threadIdx.x;
    unsigned x = (t < nchunks) ? sums[t] : 0u;
    s[t] = x;
    __syncthreads();
    for (int off = 1; off < 512; off <<= 1) {
        unsigned v = (t >= off) ? s[t - off] : 0u;
        __syncthreads();
        s[t] += v;
        __syncthreads();
    }
    if (t < nchunks) chunk_off[t] = s[t] - x;   // exclusive
    if (t == 0) offs[n] = (unsigned)total;
}

__global__ void exscan_kernel(const unsigned* __restrict__ src, int n,
                              const unsigned* __restrict__ chunk_off,
                              unsigned* __restrict__ dst) {
    __shared__ unsigned s[256];
    const int t = threadIdx.x;
    const int i = blockIdx.x * 256 + t;
    unsigned x = (i < n) ? src[i] : 0u;
    s[t] = x;
    __syncthreads();
    for (int off = 1; off < 256; off <<= 1) {
        unsigned v = (t >= off) ? s[t - off] : 0u;
        __syncthreads();
        s[t] += v;
        __syncthreads();
    }
    if (i < n) dst[i] = chunk_off[blockIdx.x] + s[t] - x;
}

// ---------------------------------------------------------------------------
// Partition level 1: scatter nnz entries into bucket-major temp order.
// key = (user << 15) | col. Streaming inputs read nontemporally so L2 can
// keep the partial write lines resident until full.
// ---------------------------------------------------------------------------
__global__ void partition_kernel(const int* __restrict__ rows,
                                 const int* __restrict__ cols,
                                 const float* __restrict__ vals, int nnz,
                                 int nbuckets, int ntiles,
                                 const unsigned* __restrict__ offsB,
                                 uint2* __restrict__ temp) {
    extern __shared__ unsigned smem[];          // hist[nb] then lofs[nb]
    unsigned* hist = smem;
    unsigned* lofs = smem + nbuckets;
    const int t = blockIdx.x;
    const int tid = threadIdx.x;
    for (int i = tid; i < nbuckets; i += blockDim.x) {
        hist[i] = 0;
        lofs[i] = offsB[(size_t)i * ntiles + t];
    }
    __syncthreads();

    const int base = t * TILE_E;
    const int kmax = TILE_E / 256;
    for (int k = 0; k < kmax; ++k) {
        const int e = base + k * 256 + tid;
        if (e < nnz) {
            const int r = __builtin_nontemporal_load(rows + e);
            const int c = __builtin_nontemporal_load(cols + e);
            const float v = __builtin_nontemporal_load(vals + e);
            const int b = r >> BUCKET_SHIFT;
            const unsigned lrank = atomicAdd(&hist[b], 1u);
            const unsigned dst = lofs[b] + lrank;
            const unsigned key = ((unsigned)r << 15) | (unsigned)c;
            temp[dst] = make_uint2(key, __float_as_uint(v));
        }
    }
}

// ---------------------------------------------------------------------------
// Partition level 2 (fused per-user counting): bucket-major temp -> exact CSR.
// temp read nontemporally (one-touch stream); 1024 threads/WG.
// ---------------------------------------------------------------------------
__global__ void __launch_bounds__(1024)
csr_scatter_kernel(const uint2* __restrict__ temp,
                   const unsigned* __restrict__ offsB,
                   int* __restrict__ row_start,
                   uint2* __restrict__ pairs,
                   int ntiles, int num_users, int nbB) {
    __shared__ int cnt[BUCKET_W];
    __shared__ int scan_s[BUCKET_W];
    __shared__ int cur[BUCKET_W];
    const int b = blockIdx.x;
    const int tid = threadIdx.x;
    const int ubase = b << BUCKET_SHIFT;
    const int s0 = (int)offsB[(size_t)b * ntiles];
    const int s1 = (int)offsB[(size_t)(b + 1) * ntiles];

    if (tid < BUCKET_W) cnt[tid] = 0;
    __syncthreads();
    const unsigned* tx = (const unsigned*)temp;   // temp[s].x at tx[2s]
    for (int s = s0 + tid; s < s1; s += 1024) {
        const unsigned key = __builtin_nontemporal_load(tx + 2 * (size_t)s);
        atomicAdd(&cnt[(int)(key >> 15) - ubase], 1);
    }
    __syncthreads();

    int x = 0;
    if (tid < BUCKET_W) {
        x = cnt[tid];
        scan_s[tid] = x;
    }
    __syncthreads();
    for (int off = 1; off < BUCKET_W; off <<= 1) {
        int v = 0;
        if (tid < BUCKET_W && tid >= off) v = scan_s[tid - off];
        __syncthreads();
        if (tid < BUCKET_W) scan_s[tid] += v;
        __syncthreads();
    }
    if (tid < BUCKET_W) {
        const int start = s0 + scan_s[tid] - x;
        cur[tid] = start;
        if (ubase + tid < num_users) row_start[ubase + tid] = start;
    }
    if (b == nbB - 1 && tid == 0) row_start[num_users] = s1;
    __syncthreads();

    for (int s = s0 + tid; s < s1; s += 1024) {
        const unsigned long long ev = __builtin_nontemporal_load(
            (const unsigned long long*)temp + s);
        const unsigned ex = (unsigned)ev;
        const unsigned ey = (unsigned)(ev >> 32);
        const int lu = (int)(ex >> 15) - ubase;
        const int dst = atomicAdd(&cur[lu], 1);
        pairs[dst] = make_uint2(ex & 0x7fffu, ey);
    }
}

// ---------------------------------------------------------------------------
// Segment sum, half-wave, unroll 8: lanes 0-31 do even entries, 32-63 odd;
// 4 independent pair->P load chains per half in flight.
// ---------------------------------------------------------------------------
__global__ void gather_kernel(const int* __restrict__ row_start,
                              const uint2* __restrict__ pairs,
                              const unsigned short* __restrict__ Ph,
                              float* __restrict__ user_emb,
                              float* __restrict__ user_deg, int nu) {
    const int lane = threadIdx.x & 63;
    const int half = lane >> 5;         // 0 or 1
    const int hl = lane & 31;           // comps 2hl, 2hl+1
    const int u = (blockIdx.x * blockDim.x + threadIdx.x) >> 6;
    if (u >= nu) return;

    const int s0 = row_start[u];
    const int s1 = row_start[u + 1];
    float ax0 = 0.0f, ay0 = 0.0f, ax1 = 0.0f, ay1 = 0.0f;
    float ax2 = 0.0f, ay2 = 0.0f, ax3 = 0.0f, ay3 = 0.0f;
    float deg = 0.0f;
    int s = s0;
    for (; s + 7 < s1; s += 8) {
        const uint2 p0 = pairs[s + half];
        const uint2 p1 = pairs[s + 2 + half];
        const uint2 p2 = pairs[s + 4 + half];
        const uint2 p3 = pairs[s + 6 + half];
        const unsigned w0 = *(const unsigned*)(Ph + (size_t)p0.x * HIDDEN + 2 * hl);
        const unsigned w1 = *(const unsigned*)(Ph + (size_t)p1.x * HIDDEN + 2 * hl);
        const unsigned w2 = *(const unsigned*)(Ph + (size_t)p2.x * HIDDEN + 2 * hl);
        const unsigned w3 = *(const unsigned*)(Ph + (size_t)p3.x * HIDDEN + 2 * hl);
        const float v0 = __uint_as_float(p0.y);
        const float v1 = __uint_as_float(p1.y);
        const float v2 = __uint_as_float(p2.y);
        const float v3 = __uint_as_float(p3.y);
        ax0 = fmaf(v0, __uint_as_float(w0 << 16), ax0);
        ay0 = fmaf(v0, __uint_as_float(w0 & 0xffff0000u), ay0);
        ax1 = fmaf(v1, __uint_as_float(w1 << 16), ax1);
        ay1 = fmaf(v1, __uint_as_float(w1 & 0xffff0000u), ay1);
        ax2 = fmaf(v2, __uint_as_float(w2 << 16), ax2);
        ay2 = fmaf(v2, __uint_as_float(w2 & 0xffff0000u), ay2);
        ax3 = fmaf(v3, __uint_as_float(w3 << 16), ax3);
        ay3 = fmaf(v3, __uint_as_float(w3 & 0xffff0000u), ay3);
        deg += (v0 + v1) + (v2 + v3);
    }
    for (; s + 1 < s1; s += 2) {
        const uint2 pr = pairs[s + half];
        const float v = __uint_as_float(pr.y);
        const unsigned w = *(const unsigned*)(Ph + (size_t)pr.x * HIDDEN + 2 * hl);
        ax0 = fmaf(v, __uint_as_float(w << 16), ax0);
        ay0 = fmaf(v, __uint_as_float(w & 0xffff0000u), ay0);
        deg += v;
    }
    if (s < s1 && half == 0) {          // last odd entry
        const uint2 pr = pairs[s];
        const float v = __uint_as_float(pr.y);
        const unsigned w = *(const unsigned*)(Ph + (size_t)pr.x * HIDDEN + 2 * hl);
        ax0 = fmaf(v, __uint_as_float(w << 16), ax0);
        ay0 = fmaf(v, __uint_as_float(w & 0xffff0000u), ay0);
        deg += v;
    }

    float xv = (ax0 + ax1) + (ax2 + ax3);
    float yv = (ay0 + ay1) + (ay2 + ay3);
    xv += __shfl_xor(xv, 32);
    yv += __shfl_xor(yv, 32);
    deg += __shfl_xor(deg, 32);
    if (half == 0) {
        *(float2*)(user_emb + (size_t)u * HIDDEN + 2 * hl) =
            make_float2(xv, yv);
        if (hl == 0) user_deg[u] = deg;
    }
}

// ---------------------------------------------------------------------------
// 16 bf16 x 16 fp32 dot for one lane: q points at 32B (2 x uint4).
// ---------------------------------------------------------------------------
__device__ inline float dot16(const uint4* __restrict__ q,
                              const float* __restrict__ ue) {
    float d = 0.0f;
    #pragma unroll
    for (int h = 0; h < 2; ++h) {
        const uint4 v = q[h];
        const unsigned w0 = v.x, w1 = v.y, w2 = v.z, w3 = v.w;
        d = fmaf(ue[h * 8 + 0], __uint_as_float(w0 << 16), d);
        d = fmaf(ue[h * 8 + 1], __uint_as_float(w0 & 0xffff0000u), d);
        d = fmaf(ue[h * 8 + 2], __uint_as_float(w1 << 16), d);
        d = fmaf(ue[h * 8 + 3], __uint_as_float(w1 & 0xffff0000u), d);
        d = fmaf(ue[h * 8 + 4], __uint_as_float(w2 << 16), d);
        d = fmaf(ue[h * 8 + 5], __uint_as_float(w2 & 0xffff0000u), d);
        d = fmaf(ue[h * 8 + 6], __uint_as_float(w3 << 16), d);
        d = fmaf(ue[h * 8 + 7], __uint_as_float(w3 & 0xffff0000u), d);
    }
    return d;
}

// ---------------------------------------------------------------------------
// Pair loss, 4-lane group per pair (lane = 16 components), partial store.
// ---------------------------------------------------------------------------
template <int S>
__global__ void loss4_kernel(const float* __restrict__ user_emb,
                             const float* __restrict__ user_deg,
                             const unsigned short* __restrict__ Qh,
                             const float* __restrict__ b_u,
                             const float* __restrict__ b_i,
                             const int* __restrict__ rows,
                             const int* __restrict__ cols,
                             const int* __restrict__ pos_idx,
                             const int* __restrict__ neg_item_idx,
                             int num_pos,
                             float* __restrict__ partials, int slot_base) {
    const int tid = blockIdx.x * blockDim.x + threadIdx.x;
    const int g = tid >> 2;            // pair index
    const int l = tid & 3;             // lane-in-group: components [16l,16l+16)
    float acc = 0.0f;

    if (g < num_pos) {
        const int e = pos_idx[g];
        const int u = rows[e];
        const int ii = cols[e];
        const float invdeg = 1.0f / user_deg[u];

        float ue[16];
        {
            const float4* uep =
                (const float4*)(user_emb + (size_t)u * HIDDEN + l * 16);
            #pragma unroll
            for (int k = 0; k < 4; ++k) {
                const float4 t4 = uep[k];
                ue[4 * k + 0] = t4.x * invdeg;
                ue[4 * k + 1] = t4.y * invdeg;
                ue[4 * k + 2] = t4.z * invdeg;
                ue[4 * k + 3] = t4.w * invdeg;
            }
        }

        int jarr[S];
        float part[1 + S];
        part[0] = dot16((const uint4*)(Qh + (size_t)ii * HIDDEN + l * 16), ue);
        #pragma unroll
        for (int s = 0; s < S; ++s) {
            const int j = neg_item_idx[(size_t)g * S + s];
            jarr[s] = j;
            part[1 + s] =
                dot16((const uint4*)(Qh + (size_t)j * HIDDEN + l * 16), ue);
        }

        #pragma unroll
        for (int k = 0; k < 1 + S; ++k) {
            part[k] += __shfl_xor(part[k], 1);
            part[k] += __shfl_xor(part[k], 2);
        }

        if (l == 0) {
            const float bu = b_u[u];
            const float r = bu + b_i[ii] + part[0];
            #pragma unroll
            for (int s = 0; s < S; ++s) {
                const float nr = bu + b_i[jarr[s]] + part[1 + s];
                const float diff = 1.0f - (r - nr);
                acc += 0.5f * diff * diff;
            }
        }
    }

    for (int off = 32; off; off >>= 1) acc += __shfl_down(acc, off);
    __shared__ float s_part[16];
    const int wave = threadIdx.x >> 6;
    const int lane = threadIdx.x & 63;
    if (lane == 0) s_part[wave] = acc;
    __syncthreads();
    if (threadIdx.x == 0) {
        float t = 0.0f;
        const int nw = blockDim.x >> 6;
        for (int w = 0; w < nw; ++w) t += s_part[w];
        partials[slot_base + blockIdx.x] = t;
    }
}

// generic fallback (thread per pair), only used if S != 5
__global__ void loss_generic_kernel(const float* __restrict__ user_emb,
                                    const float* __restrict__ user_deg,
                                    const unsigned short* __restrict__ Qh,
                                    const float* __restrict__ b_u,
                                    const float* __restrict__ b_i,
                                    const int* __restrict__ rows,
                                    const int* __restrict__ cols,
                                    const int* __restrict__ pos_idx,
                                    const int* __restrict__ neg_item_idx,
                                    int num_pos, int S,
                                    float* __restrict__ partials,
                                    int slot_base) {
    const int p = blockIdx.x * blockDim.x + threadIdx.x;
    float acc = 0.0f;
    if (p < num_pos) {
        const int e = pos_idx[p];
        const int u = rows[e];
        const int ii = cols[e];
        const float invdeg = 1.0f / user_deg[u];
        float ue[HIDDEN];
        #pragma unroll
        for (int kk = 0; kk < HIDDEN; ++kk)
            ue[kk] = user_emb[(size_t)u * HIDDEN + kk] * invdeg;
        const float bu = b_u[u];
        float dot = 0.0f;
        #pragma unroll
        for (int kk = 0; kk < HIDDEN; ++kk)
            dot = fmaf(ue[kk], bf2f(Qh[(size_t)ii * HIDDEN + kk]), dot);
        const float rr = bu + b_i[ii] + dot;
        for (int s = 0; s < S; ++s) {
            const int j = neg_item_idx[(size_t)p * S + s];
            float dn = 0.0f;
            #pragma unroll
            for (int kk = 0; kk < HIDDEN; ++kk)
                dn = fmaf(ue[kk], bf2f(Qh[(size_t)j * HIDDEN + kk]), dn);
            const float nr = bu + b_i[j] + dn;
            const float diff = 1.0f - (rr - nr);
            acc += 0.5f * diff * diff;
        }
    }
    for (int off = 32; off; off >>= 1) acc += __shfl_down(acc, off);
    __shared__ float s_part[16];
    const int wave = threadIdx.x >> 6;
    const int lane = threadIdx.x & 63;
    if (lane == 0) s_part[wave] = acc;
    __syncthreads();
    if (threadIdx.x == 0) {
        float t = 0.0f;
        const int nw = blockDim.x >> 6;
        for (int w = 0; w < nw; ++w) t += s_part[w];
        partials[slot_base + blockIdx.x] = t;
    }
}

// ---------------------------------------------------------------------------
// Bias regularizer partials: 0.5*GAMMA*(sum b_u^2 + sum b_i^2)
// ---------------------------------------------------------------------------
__global__ void bias_reg_kernel(const float* __restrict__ b_u, int nu,
                                const float* __restrict__ b_i, int ni,
                                float* __restrict__ partials, int slot_base) {
    const int tid = blockIdx.x * blockDim.x + threadIdx.x;
    const int stride = gridDim.x * blockDim.x;
    const int n = nu + ni;
    float acc = 0.0f;
    for (int x = tid; x < n; x += stride) {
        float v = (x < nu) ? b_u[x] : b_i[x - nu];
        acc += v * v;
    }
    for (int off = 32; off; off >>= 1) acc += __shfl_down(acc, off);
    __shared__ float s_part[16];
    const int wave = threadIdx.x >> 6;
    const int lane = threadIdx.x & 63;
    if (lane == 0) s_part[wave] = acc;
    __syncthreads();
    if (threadIdx.x == 0) {
        float t = 0.0f;
        const int nw = blockDim.x >> 6;
        for (int w = 0; w < nw; ++w) t += s_part[w];
        partials[slot_base + blockIdx.x] = 0.5f * GAMMA * t;
    }
}

// ---------------------------------------------------------------------------
// Deterministic final reduction of all partial slots -> out[0].
// ---------------------------------------------------------------------------
__global__ void final_reduce_kernel(const float* __restrict__ partials, int n,
                                    float* __restrict__ out) {
    __shared__ float s[256];
    float a = 0.0f;
    for (int i = threadIdx.x; i < n; i += 256) a += partials[i];
    s[threadIdx.x] = a;
    __syncthreads();
    for (int off = 128; off; off >>= 1) {
        if (threadIdx.x < off) s[threadIdx.x] += s[threadIdx.x + off];
        __syncthreads();
    }
    if (threadIdx.x == 0) out[0] = s[0];
}

// ---------------------------------------------------------------------------
extern "C" void kernel_launch(void* const* d_in, const int* in_sizes, int n_in,
                              void* d_out, int out_size, void* d_ws, size_t ws_size,
                              hipStream_t stream) {
    const float* features     = (const float*)d_in[0];
    const float* W_enc        = (const float*)d_in[1];
    const float* b_enc        = (const float*)d_in[2];
    const float* W_p          = (const float*)d_in[3];
    const float* W_q          = (const float*)d_in[4];
    const float* b_u          = (const float*)d_in[5];
    const float* b_i          = (const float*)d_in[6];
    const float* vals         = (const float*)d_in[7];
    const int*   rows         = (const int*)d_in[8];
    const int*   cols         = (const int*)d_in[9];
    const int*   pos_idx      = (const int*)d_in[10];
    const int*   neg_item_idx = (const int*)d_in[11];

    const int num_users  = in_sizes[5];                 // 50000
    const int num_movies = in_sizes[6];                 // 20000
    const int in_feats   = in_sizes[0] / num_movies;    // 128
    const int nnz        = in_sizes[7];                 // 2000000
    const int num_pos    = in_sizes[10];                // 200000
    const int S          = in_sizes[11] / num_pos;      // 5

    const int nbB    = (num_users + BUCKET_W - 1) >> BUCKET_SHIFT;  // 196
    const int ntiles = (nnz + TILE_E - 1) / TILE_E;                 // 245
    const int scanNB = nbB * ntiles;                                // 48020
    const int n1b    = (scanNB + 255) / 256;                        // 188 <= 512

    const int enc_blocks  = (num_movies + 15) / 16;                 // 1250
    const int loss_blocks = (S == 5) ? (int)(((size_t)num_pos * 4 + 255) / 256)
                                     : (num_pos + 255) / 256;
    const int bias_blocks = 128;
    const int slot_pq   = 0;
    const int slot_loss = enc_blocks;
    const int slot_bias = enc_blocks + loss_blocks;
    const int n_slots   = slot_bias + bias_blocks;

    // workspace layout (256B-aligned). Time-shared region U:
    //   temp (partition) | user_emb (gather+loss) — sequential, never live together
    auto align256 = [](size_t x) { return (x + 255) & ~(size_t)255; };
    char* ws = (char*)d_ws;
    size_t off = 0;
    unsigned short* Ph = (unsigned short*)(ws + off);
    off += align256((size_t)num_movies * HIDDEN * 2);
    unsigned short* Qh = (unsigned short*)(ws + off);
    off += align256((size_t)num_movies * HIDDEN * 2);
    char* U = ws + off;
    const size_t emb_bytes = align256((size_t)num_users * HIDDEN * 4);
    const size_t tmp_bytes = align256((size_t)nnz * 8);
    uint2* temp     = (uint2*)U;
    float* user_emb = (float*)U;
    off += (emb_bytes > tmp_bytes) ? emb_bytes : tmp_bytes;
    float* user_deg = (float*)(ws + off); off += align256((size_t)num_users * 4);
    int*   row_start= (int*)(ws + off);   off += align256((size_t)(num_users + 1) * 4);
    unsigned* tileHistB = (unsigned*)(ws + off); off += align256((size_t)scanNB * 4);
    unsigned* offsB     = (unsigned*)(ws + off); off += align256((size_t)(scanNB + 1) * 4);
    unsigned* sums_b    = (unsigned*)(ws + off); off += align256(512 * 4);
    unsigned* top_b     = (unsigned*)(ws + off); off += align256(512 * 4);
    uint2* pairs        = (uint2*)(ws + off);    off += align256((size_t)nnz * 8);
    float* partials     = (float*)(ws + off);    off += align256((size_t)n_slots * 4);

    float* out = (float*)d_out;

    // fused register-blocked encode -> Ph/Qh (bf16) + regularizer partials
    encode_kernel<<<enc_blocks, 256, 0, stream>>>(
        features, W_enc, b_enc, W_p, W_q, Ph, Qh, partials, slot_pq,
        num_movies, in_feats);

    // nnz bucket histogram + scan -> offsB
    tilehist_kernel<<<ntiles, 256, (size_t)nbB * 4, stream>>>(
        rows, nnz, nbB, ntiles, tileHistB);
    chunksum_kernel<<<n1b, 256, 0, stream>>>(tileHistB, scanNB, sums_b);
    scantop_kernel<<<1, 512, 0, stream>>>(sums_b, n1b, top_b, offsB, scanNB, nnz);
    exscan_kernel<<<n1b, 256, 0, stream>>>(tileHistB, scanNB, top_b, offsB);

    // two-level partition -> exact CSR pairs (+ row_start fused)
    partition_kernel<<<ntiles, 256, (size_t)nbB * 8, stream>>>(
        rows, cols, vals, nnz, nbB, ntiles, offsB, temp);
    csr_scatter_kernel<<<nbB, 1024, 0, stream>>>(temp, offsB, row_start,
                                                 pairs, ntiles, num_users, nbB);

    // segment sum (half-wave unroll-8 register gather, bf16 P)
    gather_kernel<<<(num_users * 64 + 255) / 256, 256, 0, stream>>>(
        row_start, pairs, Ph, user_emb, user_deg, num_users);

    // pair loss -> per-block partials
    if (S == 5) {
        loss4_kernel<5><<<loss_blocks, 256, 0, stream>>>(
            user_emb, user_deg, Qh, b_u, b_i, rows, cols, pos_idx,
            neg_item_idx, num_pos, partials, slot_loss);
    } else {
        loss_generic_kernel<<<loss_blocks, 256, 0, stream>>>(
            user_emb, user_deg, Qh, b_u, b_i, rows, cols, pos_idx,
            neg_item_idx, num_pos, S, partials, slot_loss);
    }

    bias_reg_kernel<<<bias_blocks, 256, 0, stream>>>(b_u, num_users,
                                                     b_i, num_movies,
                                                     partials, slot_bias);

    final_reduce_kernel<<<1, 256, 0, stream>>>(partials, n_slots, out);
}

// Round 14
// 180.700 us; speedup vs baseline: 2.6755x; 1.0387x over previous
//
#include <hip/hip_runtime.h>

#define HIDDEN 64
#define BETA 0.01f
#define GAMMA 0.01f

#define BUCKET_SHIFT 8                 // 256 users per bucket
#define BUCKET_W     (1 << BUCKET_SHIFT)
#define TILE_E       8192              // entries per partition tile

__device__ inline unsigned short f2bf(float f) {   // RNE float->bf16
    unsigned x = __float_as_uint(f);
    return (unsigned short)((x + 0x7fffu + ((x >> 16) & 1u)) >> 16);
}
__device__ inline float bf2f(unsigned short b) {
    return __uint_as_float(((unsigned)b) << 16);
}
__device__ inline float bflo(unsigned w) { return __uint_as_float(w << 16); }
__device__ inline float bfhi(unsigned w) {
    return __uint_as_float(w & 0xffff0000u);
}

// ---------------------------------------------------------------------------
// Fused encode, register-blocked: each wave owns 4 movies; W columns loaded
// once and reused x4. Phase 1: h rows -> LDS. Phase 2: P/Q (bf16).
// ---------------------------------------------------------------------------
__global__ void __launch_bounds__(256)
encode_kernel(const float* __restrict__ features,
              const float* __restrict__ W_enc,
              const float* __restrict__ b_enc,
              const float* __restrict__ W_p,
              const float* __restrict__ W_q,
              unsigned short* __restrict__ Ph,
              unsigned short* __restrict__ Qh,
              float* __restrict__ partials, int slot_base,
              int num_movies, int in_feats) {
    __shared__ float hs[16][HIDDEN];           // 4 KB
    const int tid = threadIdx.x;
    const int j = tid & 63;
    const int wv = tid >> 6;                   // wave 0..3
    const int m0 = blockIdx.x * 16 + wv * 4;   // this wave's 4 movies

    const int c0 = min(m0 + 0, num_movies - 1);
    const int c1 = min(m0 + 1, num_movies - 1);
    const int c2 = min(m0 + 2, num_movies - 1);
    const int c3 = min(m0 + 3, num_movies - 1);
    const float* fr0 = features + (size_t)c0 * in_feats;
    const float* fr1 = features + (size_t)c1 * in_feats;
    const float* fr2 = features + (size_t)c2 * in_feats;
    const float* fr3 = features + (size_t)c3 * in_feats;

    float h0 = 0.0f, h1 = 0.0f, h2 = 0.0f, h3 = 0.0f;
    #pragma unroll 4
    for (int f = 0; f < in_feats; f += 4) {
        const float w_a = W_enc[(f + 0) * HIDDEN + j];
        const float w_b = W_enc[(f + 1) * HIDDEN + j];
        const float w_c = W_enc[(f + 2) * HIDDEN + j];
        const float w_d = W_enc[(f + 3) * HIDDEN + j];
        const float4 a0 = *(const float4*)(fr0 + f);
        const float4 a1 = *(const float4*)(fr1 + f);
        const float4 a2 = *(const float4*)(fr2 + f);
        const float4 a3 = *(const float4*)(fr3 + f);
        h0 = fmaf(a0.x, w_a, h0); h0 = fmaf(a0.y, w_b, h0);
        h0 = fmaf(a0.z, w_c, h0); h0 = fmaf(a0.w, w_d, h0);
        h1 = fmaf(a1.x, w_a, h1); h1 = fmaf(a1.y, w_b, h1);
        h1 = fmaf(a1.z, w_c, h1); h1 = fmaf(a1.w, w_d, h1);
        h2 = fmaf(a2.x, w_a, h2); h2 = fmaf(a2.y, w_b, h2);
        h2 = fmaf(a2.z, w_c, h2); h2 = fmaf(a2.w, w_d, h2);
        h3 = fmaf(a3.x, w_a, h3); h3 = fmaf(a3.y, w_b, h3);
        h3 = fmaf(a3.z, w_c, h3); h3 = fmaf(a3.w, w_d, h3);
    }
    const float be = b_enc[j];
    hs[wv * 4 + 0][j] = h0 + be;
    hs[wv * 4 + 1][j] = h1 + be;
    hs[wv * 4 + 2][j] = h2 + be;
    hs[wv * 4 + 3][j] = h3 + be;
    __syncthreads();

    float p0 = 0.0f, p1 = 0.0f, p2 = 0.0f, p3 = 0.0f;
    float q0 = 0.0f, q1 = 0.0f, q2 = 0.0f, q3 = 0.0f;
    #pragma unroll 4
    for (int f = 0; f < HIDDEN; f += 4) {
        const float wp0 = W_p[(f + 0) * HIDDEN + j];
        const float wp1 = W_p[(f + 1) * HIDDEN + j];
        const float wp2 = W_p[(f + 2) * HIDDEN + j];
        const float wp3 = W_p[(f + 3) * HIDDEN + j];
        const float wq0 = W_q[(f + 0) * HIDDEN + j];
        const float wq1 = W_q[(f + 1) * HIDDEN + j];
        const float wq2 = W_q[(f + 2) * HIDDEN + j];
        const float wq3 = W_q[(f + 3) * HIDDEN + j];
        const float4 v0 = *(const float4*)(&hs[wv * 4 + 0][f]);
        const float4 v1 = *(const float4*)(&hs[wv * 4 + 1][f]);
        const float4 v2 = *(const float4*)(&hs[wv * 4 + 2][f]);
        const float4 v3 = *(const float4*)(&hs[wv * 4 + 3][f]);
        p0 = fmaf(v0.x, wp0, p0); p0 = fmaf(v0.y, wp1, p0);
        p0 = fmaf(v0.z, wp2, p0); p0 = fmaf(v0.w, wp3, p0);
        q0 = fmaf(v0.x, wq0, q0); q0 = fmaf(v0.y, wq1, q0);
        q0 = fmaf(v0.z, wq2, q0); q0 = fmaf(v0.w, wq3, q0);
        p1 = fmaf(v1.x, wp0, p1); p1 = fmaf(v1.y, wp1, p1);
        p1 = fmaf(v1.z, wp2, p1); p1 = fmaf(v1.w, wp3, p1);
        q1 = fmaf(v1.x, wq0, q1); q1 = fmaf(v1.y, wq1, q1);
        q1 = fmaf(v1.z, wq2, q1); q1 = fmaf(v1.w, wq3, q1);
        p2 = fmaf(v2.x, wp0, p2); p2 = fmaf(v2.y, wp1, p2);
        p2 = fmaf(v2.z, wp2, p2); p2 = fmaf(v2.w, wp3, p2);
        q2 = fmaf(v2.x, wq0, q2); q2 = fmaf(v2.y, wq1, q2);
        q2 = fmaf(v2.z, wq2, q2); q2 = fmaf(v2.w, wq3, q2);
        p3 = fmaf(v3.x, wp0, p3); p3 = fmaf(v3.y, wp1, p3);
        p3 = fmaf(v3.z, wp2, p3); p3 = fmaf(v3.w, wp3, p3);
        q3 = fmaf(v3.x, wq0, q3); q3 = fmaf(v3.y, wq1, q3);
        q3 = fmaf(v3.z, wq2, q3); q3 = fmaf(v3.w, wq3, q3);
    }

    float reg = 0.0f;
    if (m0 + 0 < num_movies) {
        Ph[(size_t)(m0 + 0) * HIDDEN + j] = f2bf(p0);
        Qh[(size_t)(m0 + 0) * HIDDEN + j] = f2bf(q0);
        reg += p0 * p0 + q0 * q0;
    }
    if (m0 + 1 < num_movies) {
        Ph[(size_t)(m0 + 1) * HIDDEN + j] = f2bf(p1);
        Qh[(size_t)(m0 + 1) * HIDDEN + j] = f2bf(q1);
        reg += p1 * p1 + q1 * q1;
    }
    if (m0 + 2 < num_movies) {
        Ph[(size_t)(m0 + 2) * HIDDEN + j] = f2bf(p2);
        Qh[(size_t)(m0 + 2) * HIDDEN + j] = f2bf(q2);
        reg += p2 * p2 + q2 * q2;
    }
    if (m0 + 3 < num_movies) {
        Ph[(size_t)(m0 + 3) * HIDDEN + j] = f2bf(p3);
        Qh[(size_t)(m0 + 3) * HIDDEN + j] = f2bf(q3);
        reg += p3 * p3 + q3 * q3;
    }

    for (int off = 32; off; off >>= 1) reg += __shfl_down(reg, off);
    __shared__ float s_part[4];
    if (j == 0) s_part[wv] = reg;
    __syncthreads();
    if (tid == 0) {
        float t = (s_part[0] + s_part[1]) + (s_part[2] + s_part[3]);
        partials[slot_base + blockIdx.x] = 0.5f * BETA * t;
    }
}

// ---------------------------------------------------------------------------
// Per-tile LDS bucket histogram over nnz entries (nontemporal row reads).
// ---------------------------------------------------------------------------
__global__ void tilehist_kernel(const int* __restrict__ rows, int nnz,
                                int nbuckets, int ntiles,
                                unsigned* __restrict__ tileHist) {
    extern __shared__ unsigned hist[];
    const int t = blockIdx.x;
    const int tid = threadIdx.x;
    for (int i = tid; i < nbuckets; i += blockDim.x) hist[i] = 0;
    __syncthreads();

    const int base = t * TILE_E;
    const int kmax = TILE_E / 256;
    for (int k = 0; k < kmax; ++k) {
        const int e = base + k * 256 + tid;
        if (e < nnz) {
            const int r = __builtin_nontemporal_load(rows + e);
            atomicAdd(&hist[r >> BUCKET_SHIFT], 1u);
        }
    }
    __syncthreads();
    for (int i = tid; i < nbuckets; i += blockDim.x)
        tileHist[(size_t)i * ntiles + t] = hist[i];
}

// ---------------------------------------------------------------------------
// 2-level scan blocks.
// ---------------------------------------------------------------------------
__global__ void chunksum_kernel(const unsigned* __restrict__ src, int n,
                                unsigned* __restrict__ sums) {
    __shared__ unsigned s[256];
    const int t = threadIdx.x;
    const int i = blockIdx.x * 256 + t;
    s[t] = (i < n) ? src[i] : 0u;
    __syncthreads();
    for (int off = 128; off; off >>= 1) {
        if (t < off) s[t] += s[t + off];
        __syncthreads();
    }
    if (t == 0) sums[blockIdx.x] = s[0];
}

__global__ void __launch_bounds__(512)
scantop_kernel(const unsigned* __restrict__ sums, int nchunks,
               unsigned* __restrict__ chunk_off,
               unsigned* __restrict__ offs, int n, int total) {
    __shared__ unsigned s[512];
    const int t = threadIdx.x;
    unsigned x = (t < nchunks) ? sums[t] : 0u;
    s[t] = x;
    __syncthreads();
    for (int off = 1; off < 512; off <<= 1) {
        unsigned v = (t >= off) ? s[t - off] : 0u;
        __syncthreads();
        s[t] += v;
        __syncthreads();
    }
    if (t < nchunks) chunk_off[t] = s[t] - x;   // exclusive
    if (t == 0) offs[n] = (unsigned)total;
}

__global__ void exscan_kernel(const unsigned* __restrict__ src, int n,
                              const unsigned* __restrict__ chunk_off,
                              unsigned* __restrict__ dst) {
    __shared__ unsigned s[256];
    const int t = threadIdx.x;
    const int i = blockIdx.x * 256 + t;
    unsigned x = (i < n) ? src[i] : 0u;
    s[t] = x;
    __syncthreads();
    for (int off = 1; off < 256; off <<= 1) {
        unsigned v = (t >= off) ? s[t - off] : 0u;
        __syncthreads();
        s[t] += v;
        __syncthreads();
    }
    if (i < n) dst[i] = chunk_off[blockIdx.x] + s[t] - x;
}

// ---------------------------------------------------------------------------
// Partition level 1: scatter nnz entries into bucket-major temp order.
// key = (user << 15) | col. Streaming inputs read nontemporally so L2 can
// keep the partial write lines resident until full.
// ---------------------------------------------------------------------------
__global__ void partition_kernel(const int* __restrict__ rows,
                                 const int* __restrict__ cols,
                                 const float* __restrict__ vals, int nnz,
                                 int nbuckets, int ntiles,
                                 const unsigned* __restrict__ offsB,
                                 uint2* __restrict__ temp) {
    extern __shared__ unsigned smem[];          // hist[nb] then lofs[nb]
    unsigned* hist = smem;
    unsigned* lofs = smem + nbuckets;
    const int t = blockIdx.x;
    const int tid = threadIdx.x;
    for (int i = tid; i < nbuckets; i += blockDim.x) {
        hist[i] = 0;
        lofs[i] = offsB[(size_t)i * ntiles + t];
    }
    __syncthreads();

    const int base = t * TILE_E;
    const int kmax = TILE_E / 256;
    for (int k = 0; k < kmax; ++k) {
        const int e = base + k * 256 + tid;
        if (e < nnz) {
            const int r = __builtin_nontemporal_load(rows + e);
            const int c = __builtin_nontemporal_load(cols + e);
            const float v = __builtin_nontemporal_load(vals + e);
            const int b = r >> BUCKET_SHIFT;
            const unsigned lrank = atomicAdd(&hist[b], 1u);
            const unsigned dst = lofs[b] + lrank;
            const unsigned key = ((unsigned)r << 15) | (unsigned)c;
            temp[dst] = make_uint2(key, __float_as_uint(v));
        }
    }
}

// ---------------------------------------------------------------------------
// Partition level 2 (fused per-user counting): bucket-major temp -> exact CSR.
// ---------------------------------------------------------------------------
__global__ void __launch_bounds__(1024)
csr_scatter_kernel(const uint2* __restrict__ temp,
                   const unsigned* __restrict__ offsB,
                   int* __restrict__ row_start,
                   uint2* __restrict__ pairs,
                   int ntiles, int num_users, int nbB) {
    __shared__ int cnt[BUCKET_W];
    __shared__ int scan_s[BUCKET_W];
    __shared__ int cur[BUCKET_W];
    const int b = blockIdx.x;
    const int tid = threadIdx.x;
    const int ubase = b << BUCKET_SHIFT;
    const int s0 = (int)offsB[(size_t)b * ntiles];
    const int s1 = (int)offsB[(size_t)(b + 1) * ntiles];

    if (tid < BUCKET_W) cnt[tid] = 0;
    __syncthreads();
    const unsigned* tx = (const unsigned*)temp;   // temp[s].x at tx[2s]
    for (int s = s0 + tid; s < s1; s += 1024) {
        const unsigned key = __builtin_nontemporal_load(tx + 2 * (size_t)s);
        atomicAdd(&cnt[(int)(key >> 15) - ubase], 1);
    }
    __syncthreads();

    int x = 0;
    if (tid < BUCKET_W) {
        x = cnt[tid];
        scan_s[tid] = x;
    }
    __syncthreads();
    for (int off = 1; off < BUCKET_W; off <<= 1) {
        int v = 0;
        if (tid < BUCKET_W && tid >= off) v = scan_s[tid - off];
        __syncthreads();
        if (tid < BUCKET_W) scan_s[tid] += v;
        __syncthreads();
    }
    if (tid < BUCKET_W) {
        const int start = s0 + scan_s[tid] - x;
        cur[tid] = start;
        if (ubase + tid < num_users) row_start[ubase + tid] = start;
    }
    if (b == nbB - 1 && tid == 0) row_start[num_users] = s1;
    __syncthreads();

    for (int s = s0 + tid; s < s1; s += 1024) {
        const unsigned long long ev = __builtin_nontemporal_load(
            (const unsigned long long*)temp + s);
        const unsigned ex = (unsigned)ev;
        const unsigned ey = (unsigned)(ev >> 32);
        const int lu = (int)(ex >> 15) - ubase;
        const int dst = atomicAdd(&cur[lu], 1);
        pairs[dst] = make_uint2(ex & 0x7fffu, ey);
    }
}

// ---------------------------------------------------------------------------
// Segment sum, quarter-wave: 16 lanes per entry (lane covers 4 comps via one
// uint2 load), 4 entries per wave instruction, 2 independent chains.
// ---------------------------------------------------------------------------
__global__ void gather_kernel(const int* __restrict__ row_start,
                              const uint2* __restrict__ pairs,
                              const unsigned short* __restrict__ Ph,
                              float* __restrict__ user_emb,
                              float* __restrict__ user_deg, int nu) {
    const int lane = threadIdx.x & 63;
    const int q  = lane >> 4;           // quarter 0..3 (entry slot)
    const int ql = lane & 15;           // comps 4ql .. 4ql+3
    const int u = (blockIdx.x * blockDim.x + threadIdx.x) >> 6;
    if (u >= nu) return;

    const int s0 = row_start[u];
    const int s1 = row_start[u + 1];
    float a0 = 0.0f, a1 = 0.0f, a2 = 0.0f, a3 = 0.0f, degA = 0.0f;
    float b0 = 0.0f, b1 = 0.0f, b2 = 0.0f, b3 = 0.0f, degB = 0.0f;
    int s = s0;
    for (; s + 7 < s1; s += 8) {
        const uint2 pA = pairs[s + q];
        const uint2 pB = pairs[s + 4 + q];
        const uint2 wA = *(const uint2*)(Ph + (size_t)pA.x * HIDDEN + 4 * ql);
        const uint2 wB = *(const uint2*)(Ph + (size_t)pB.x * HIDDEN + 4 * ql);
        const float vA = __uint_as_float(pA.y);
        const float vB = __uint_as_float(pB.y);
        a0 = fmaf(vA, bflo(wA.x), a0);
        a1 = fmaf(vA, bfhi(wA.x), a1);
        a2 = fmaf(vA, bflo(wA.y), a2);
        a3 = fmaf(vA, bfhi(wA.y), a3);
        b0 = fmaf(vB, bflo(wB.x), b0);
        b1 = fmaf(vB, bfhi(wB.x), b1);
        b2 = fmaf(vB, bflo(wB.y), b2);
        b3 = fmaf(vB, bfhi(wB.y), b3);
        degA += vA;
        degB += vB;
    }
    for (; s + 3 < s1; s += 4) {
        const uint2 pA = pairs[s + q];
        const uint2 wA = *(const uint2*)(Ph + (size_t)pA.x * HIDDEN + 4 * ql);
        const float vA = __uint_as_float(pA.y);
        a0 = fmaf(vA, bflo(wA.x), a0);
        a1 = fmaf(vA, bfhi(wA.x), a1);
        a2 = fmaf(vA, bflo(wA.y), a2);
        a3 = fmaf(vA, bfhi(wA.y), a3);
        degA += vA;
    }
    if (s + q < s1) {                   // remainder 0..3 entries
        const uint2 pA = pairs[s + q];
        const uint2 wA = *(const uint2*)(Ph + (size_t)pA.x * HIDDEN + 4 * ql);
        const float vA = __uint_as_float(pA.y);
        a0 = fmaf(vA, bflo(wA.x), a0);
        a1 = fmaf(vA, bfhi(wA.x), a1);
        a2 = fmaf(vA, bflo(wA.y), a2);
        a3 = fmaf(vA, bfhi(wA.y), a3);
        degA += vA;
    }

    float x0 = a0 + b0, x1 = a1 + b1, x2 = a2 + b2, x3 = a3 + b3;
    float deg = degA + degB;
    x0 += __shfl_xor(x0, 16); x0 += __shfl_xor(x0, 32);
    x1 += __shfl_xor(x1, 16); x1 += __shfl_xor(x1, 32);
    x2 += __shfl_xor(x2, 16); x2 += __shfl_xor(x2, 32);
    x3 += __shfl_xor(x3, 16); x3 += __shfl_xor(x3, 32);
    deg += __shfl_xor(deg, 16); deg += __shfl_xor(deg, 32);
    if (q == 0) {
        *(float4*)(user_emb + (size_t)u * HIDDEN + 4 * ql) =
            make_float4(x0, x1, x2, x3);
        if (ql == 0) user_deg[u] = deg;
    }
}

// ---------------------------------------------------------------------------
// 16 bf16 x 16 fp32 dot for one lane: q points at 32B (2 x uint4).
// ---------------------------------------------------------------------------
__device__ inline float dot16(const uint4* __restrict__ q,
                              const float* __restrict__ ue) {
    float d = 0.0f;
    #pragma unroll
    for (int h = 0; h < 2; ++h) {
        const uint4 v = q[h];
        const unsigned w0 = v.x, w1 = v.y, w2 = v.z, w3 = v.w;
        d = fmaf(ue[h * 8 + 0], bflo(w0), d);
        d = fmaf(ue[h * 8 + 1], bfhi(w0), d);
        d = fmaf(ue[h * 8 + 2], bflo(w1), d);
        d = fmaf(ue[h * 8 + 3], bfhi(w1), d);
        d = fmaf(ue[h * 8 + 4], bflo(w2), d);
        d = fmaf(ue[h * 8 + 5], bfhi(w2), d);
        d = fmaf(ue[h * 8 + 6], bflo(w3), d);
        d = fmaf(ue[h * 8 + 7], bfhi(w3), d);
    }
    return d;
}

// ---------------------------------------------------------------------------
// Pair loss, 4-lane group per pair (lane = 16 components), partial store.
// ---------------------------------------------------------------------------
template <int S>
__global__ void loss4_kernel(const float* __restrict__ user_emb,
                             const float* __restrict__ user_deg,
                             const unsigned short* __restrict__ Qh,
                             const float* __restrict__ b_u,
                             const float* __restrict__ b_i,
                             const int* __restrict__ rows,
                             const int* __restrict__ cols,
                             const int* __restrict__ pos_idx,
                             const int* __restrict__ neg_item_idx,
                             int num_pos,
                             float* __restrict__ partials, int slot_base) {
    const int tid = blockIdx.x * blockDim.x + threadIdx.x;
    const int g = tid >> 2;            // pair index
    const int l = tid & 3;             // lane-in-group: components [16l,16l+16)
    float acc = 0.0f;

    if (g < num_pos) {
        const int e = pos_idx[g];
        const int u = rows[e];
        const int ii = cols[e];
        const float invdeg = 1.0f / user_deg[u];

        float ue[16];
        {
            const float4* uep =
                (const float4*)(user_emb + (size_t)u * HIDDEN + l * 16);
            #pragma unroll
            for (int k = 0; k < 4; ++k) {
                const float4 t4 = uep[k];
                ue[4 * k + 0] = t4.x * invdeg;
                ue[4 * k + 1] = t4.y * invdeg;
                ue[4 * k + 2] = t4.z * invdeg;
                ue[4 * k + 3] = t4.w * invdeg;
            }
        }

        int jarr[S];
        float part[1 + S];
        part[0] = dot16((const uint4*)(Qh + (size_t)ii * HIDDEN + l * 16), ue);
        #pragma unroll
        for (int s = 0; s < S; ++s) {
            const int j = neg_item_idx[(size_t)g * S + s];
            jarr[s] = j;
            part[1 + s] =
                dot16((const uint4*)(Qh + (size_t)j * HIDDEN + l * 16), ue);
        }

        #pragma unroll
        for (int k = 0; k < 1 + S; ++k) {
            part[k] += __shfl_xor(part[k], 1);
            part[k] += __shfl_xor(part[k], 2);
        }

        if (l == 0) {
            const float bu = b_u[u];
            const float r = bu + b_i[ii] + part[0];
            #pragma unroll
            for (int s = 0; s < S; ++s) {
                const float nr = bu + b_i[jarr[s]] + part[1 + s];
                const float diff = 1.0f - (r - nr);
                acc += 0.5f * diff * diff;
            }
        }
    }

    for (int off = 32; off; off >>= 1) acc += __shfl_down(acc, off);
    __shared__ float s_part[16];
    const int wave = threadIdx.x >> 6;
    const int lane = threadIdx.x & 63;
    if (lane == 0) s_part[wave] = acc;
    __syncthreads();
    if (threadIdx.x == 0) {
        float t = 0.0f;
        const int nw = blockDim.x >> 6;
        for (int w = 0; w < nw; ++w) t += s_part[w];
        partials[slot_base + blockIdx.x] = t;
    }
}

// generic fallback (thread per pair), only used if S != 5
__global__ void loss_generic_kernel(const float* __restrict__ user_emb,
                                    const float* __restrict__ user_deg,
                                    const unsigned short* __restrict__ Qh,
                                    const float* __restrict__ b_u,
                                    const float* __restrict__ b_i,
                                    const int* __restrict__ rows,
                                    const int* __restrict__ cols,
                                    const int* __restrict__ pos_idx,
                                    const int* __restrict__ neg_item_idx,
                                    int num_pos, int S,
                                    float* __restrict__ partials,
                                    int slot_base) {
    const int p = blockIdx.x * blockDim.x + threadIdx.x;
    float acc = 0.0f;
    if (p < num_pos) {
        const int e = pos_idx[p];
        const int u = rows[e];
        const int ii = cols[e];
        const float invdeg = 1.0f / user_deg[u];
        float ue[HIDDEN];
        #pragma unroll
        for (int kk = 0; kk < HIDDEN; ++kk)
            ue[kk] = user_emb[(size_t)u * HIDDEN + kk] * invdeg;
        const float bu = b_u[u];
        float dot = 0.0f;
        #pragma unroll
        for (int kk = 0; kk < HIDDEN; ++kk)
            dot = fmaf(ue[kk], bf2f(Qh[(size_t)ii * HIDDEN + kk]), dot);
        const float rr = bu + b_i[ii] + dot;
        for (int s = 0; s < S; ++s) {
            const int j = neg_item_idx[(size_t)p * S + s];
            float dn = 0.0f;
            #pragma unroll
            for (int kk = 0; kk < HIDDEN; ++kk)
                dn = fmaf(ue[kk], bf2f(Qh[(size_t)j * HIDDEN + kk]), dn);
            const float nr = bu + b_i[j] + dn;
            const float diff = 1.0f - (rr - nr);
            acc += 0.5f * diff * diff;
        }
    }
    for (int off = 32; off; off >>= 1) acc += __shfl_down(acc, off);
    __shared__ float s_part[16];
    const int wave = threadIdx.x >> 6;
    const int lane = threadIdx.x & 63;
    if (lane == 0) s_part[wave] = acc;
    __syncthreads();
    if (threadIdx.x == 0) {
        float t = 0.0f;
        const int nw = blockDim.x >> 6;
        for (int w = 0; w < nw; ++w) t += s_part[w];
        partials[slot_base + blockIdx.x] = t;
    }
}

// ---------------------------------------------------------------------------
// Final reduction: sum partial slots + GAMMA bias regularizer -> out[0].
// Single 1024-thread block, deterministic.
// ---------------------------------------------------------------------------
__global__ void __launch_bounds__(1024)
final_reduce_kernel(const float* __restrict__ partials, int n,
                    const float* __restrict__ b_u, int nu,
                    const float* __restrict__ b_i, int ni,
                    float* __restrict__ out) {
    __shared__ float s[1024];
    const int t = threadIdx.x;
    float a = 0.0f;
    for (int i = t; i < n; i += 1024) a += partials[i];
    float r = 0.0f;
    for (int i = t; i < nu; i += 1024) {
        const float v = b_u[i];
        r = fmaf(v, v, r);
    }
    for (int i = t; i < ni; i += 1024) {
        const float v = b_i[i];
        r = fmaf(v, v, r);
    }
    s[t] = a + 0.5f * GAMMA * r;
    __syncthreads();
    for (int off = 512; off; off >>= 1) {
        if (t < off) s[t] += s[t + off];
        __syncthreads();
    }
    if (t == 0) out[0] = s[0];
}

// ---------------------------------------------------------------------------
extern "C" void kernel_launch(void* const* d_in, const int* in_sizes, int n_in,
                              void* d_out, int out_size, void* d_ws, size_t ws_size,
                              hipStream_t stream) {
    const float* features     = (const float*)d_in[0];
    const float* W_enc        = (const float*)d_in[1];
    const float* b_enc        = (const float*)d_in[2];
    const float* W_p          = (const float*)d_in[3];
    const float* W_q          = (const float*)d_in[4];
    const float* b_u          = (const float*)d_in[5];
    const float* b_i          = (const float*)d_in[6];
    const float* vals         = (const float*)d_in[7];
    const int*   rows         = (const int*)d_in[8];
    const int*   cols         = (const int*)d_in[9];
    const int*   pos_idx      = (const int*)d_in[10];
    const int*   neg_item_idx = (const int*)d_in[11];

    const int num_users  = in_sizes[5];                 // 50000
    const int num_movies = in_sizes[6];                 // 20000
    const int in_feats   = in_sizes[0] / num_movies;    // 128
    const int nnz        = in_sizes[7];                 // 2000000
    const int num_pos    = in_sizes[10];                // 200000
    const int S          = in_sizes[11] / num_pos;      // 5

    const int nbB    = (num_users + BUCKET_W - 1) >> BUCKET_SHIFT;  // 196
    const int ntiles = (nnz + TILE_E - 1) / TILE_E;                 // 245
    const int scanNB = nbB * ntiles;                                // 48020
    const int n1b    = (scanNB + 255) / 256;                        // 188 <= 512

    const int enc_blocks  = (num_movies + 15) / 16;                 // 1250
    const int loss_blocks = (S == 5) ? (int)(((size_t)num_pos * 4 + 255) / 256)
                                     : (num_pos + 255) / 256;
    const int slot_pq   = 0;
    const int slot_loss = enc_blocks;
    const int n_slots   = enc_blocks + loss_blocks;

    // workspace layout (256B-aligned). Time-shared region U:
    //   temp (partition) | user_emb (gather+loss) — never live together
    auto align256 = [](size_t x) { return (x + 255) & ~(size_t)255; };
    char* ws = (char*)d_ws;
    size_t off = 0;
    unsigned short* Ph = (unsigned short*)(ws + off);
    off += align256((size_t)num_movies * HIDDEN * 2);
    unsigned short* Qh = (unsigned short*)(ws + off);
    off += align256((size_t)num_movies * HIDDEN * 2);
    char* U = ws + off;
    const size_t emb_bytes = align256((size_t)num_users * HIDDEN * 4);
    const size_t tmp_bytes = align256((size_t)nnz * 8);
    uint2* temp     = (uint2*)U;
    float* user_emb = (float*)U;
    off += (emb_bytes > tmp_bytes) ? emb_bytes : tmp_bytes;
    float* user_deg = (float*)(ws + off); off += align256((size_t)num_users * 4);
    int*   row_start= (int*)(ws + off);   off += align256((size_t)(num_users + 1) * 4);
    unsigned* tileHistB = (unsigned*)(ws + off); off += align256((size_t)scanNB * 4);
    unsigned* offsB     = (unsigned*)(ws + off); off += align256((size_t)(scanNB + 1) * 4);
    unsigned* sums_b    = (unsigned*)(ws + off); off += align256(512 * 4);
    unsigned* top_b     = (unsigned*)(ws + off); off += align256(512 * 4);
    uint2* pairs        = (uint2*)(ws + off);    off += align256((size_t)nnz * 8);
    float* partials     = (float*)(ws + off);    off += align256((size_t)n_slots * 4);

    float* out = (float*)d_out;

    // fused register-blocked encode -> Ph/Qh (bf16) + regularizer partials
    encode_kernel<<<enc_blocks, 256, 0, stream>>>(
        features, W_enc, b_enc, W_p, W_q, Ph, Qh, partials, slot_pq,
        num_movies, in_feats);

    // nnz bucket histogram + scan -> offsB
    tilehist_kernel<<<ntiles, 256, (size_t)nbB * 4, stream>>>(
        rows, nnz, nbB, ntiles, tileHistB);
    chunksum_kernel<<<n1b, 256, 0, stream>>>(tileHistB, scanNB, sums_b);
    scantop_kernel<<<1, 512, 0, stream>>>(sums_b, n1b, top_b, offsB, scanNB, nnz);
    exscan_kernel<<<n1b, 256, 0, stream>>>(tileHistB, scanNB, top_b, offsB);

    // two-level partition -> exact CSR pairs (+ row_start fused)
    partition_kernel<<<ntiles, 256, (size_t)nbB * 8, stream>>>(
        rows, cols, vals, nnz, nbB, ntiles, offsB, temp);
    csr_scatter_kernel<<<nbB, 1024, 0, stream>>>(temp, offsB, row_start,
                                                 pairs, ntiles, num_users, nbB);

    // segment sum (quarter-wave register gather, bf16 P)
    gather_kernel<<<(num_users * 64 + 255) / 256, 256, 0, stream>>>(
        row_start, pairs, Ph, user_emb, user_deg, num_users);

    // pair loss -> per-block partials
    if (S == 5) {
        loss4_kernel<5><<<loss_blocks, 256, 0, stream>>>(
            user_emb, user_deg, Qh, b_u, b_i, rows, cols, pos_idx,
            neg_item_idx, num_pos, partials, slot_loss);
    } else {
        loss_generic_kernel<<<loss_blocks, 256, 0, stream>>>(
            user_emb, user_deg, Qh, b_u, b_i, rows, cols, pos_idx,
            neg_item_idx, num_pos, S, partials, slot_loss);
    }

    // final: partial slots + GAMMA bias regularizer
    final_reduce_kernel<<<1, 1024, 0, stream>>>(partials, n_slots,
                                                b_u, num_users,
                                                b_i, num_movies, out);
}